// Round 1
// baseline (938.577 us; speedup 1.0000x reference)
//
#include <hip/hip_runtime.h>
#include <cfloat>
#include <cstdint>

// Problem constants (fixed by setup_inputs)
#define B_   8
#define N_   1024
#define H_   128
#define K_   20
#define EPS_ 1e-6f

// ---------------------------------------------------------------------------
// kNN: for each (b,n) find the 20 nearest points (by squared distance,
// self included at dist 0). Order irrelevant downstream (mean over k).
// ---------------------------------------------------------------------------
__global__ __launch_bounds__(256) void knn_kernel(const float* __restrict__ x,
                                                  int* __restrict__ idx) {
    int bn = blockIdx.x;               // b*1024 + n
    int b = bn >> 10, n = bn & 1023;
    const float* xb = x + (size_t)b * N_ * 3;
    float cx = xb[n * 3 + 0], cy = xb[n * 3 + 1], cz = xb[n * 3 + 2];

    __shared__ float dist[N_];
    int t = threadIdx.x;
    for (int j = t; j < N_; j += 256) {
        float dx = xb[j * 3 + 0] - cx;
        float dy = xb[j * 3 + 1] - cy;
        float dz = xb[j * 3 + 2] - cz;
        dist[j] = dx * dx + dy * dy + dz * dz;
    }
    __syncthreads();

    __shared__ float rv[4];
    __shared__ int   ri[4];
    for (int s = 0; s < K_; ++s) {
        float best = FLT_MAX; int bi = -1;
        for (int j = t; j < N_; j += 256) {
            float dv = dist[j];
            if (dv < best || (dv == best && j < bi)) { best = dv; bi = j; }
        }
        // wave (64-lane) reduce
        for (int off = 32; off; off >>= 1) {
            float ov = __shfl_down(best, off);
            int   oi = __shfl_down(bi, off);
            if (ov < best || (ov == best && oi < bi)) { best = ov; bi = oi; }
        }
        if ((t & 63) == 0) { rv[t >> 6] = best; ri[t >> 6] = bi; }
        __syncthreads();
        if (t == 0) {
            float bv = rv[0]; int bix = ri[0];
            for (int w = 1; w < 4; ++w)
                if (rv[w] < bv || (rv[w] == bv && ri[w] < bix)) { bv = rv[w]; bix = ri[w]; }
            idx[(size_t)bn * K_ + s] = bix;
            dist[bix] = FLT_MAX;
        }
        __syncthreads();
    }
}

// ---------------------------------------------------------------------------
// conv_pos: build per-neighbor features (edge, center, cross), apply two
// 3->H linears, VN leaky-relu (slope 0.2), mean over k. Fused; never
// materializes the (B,H,3,N,k) tensor.
// Output h1: (B, H, 3, N)
// ---------------------------------------------------------------------------
__global__ __launch_bounds__(128) void convpos_kernel(const float* __restrict__ x,
                                                      const int* __restrict__ idx,
                                                      const float* __restrict__ Wf,
                                                      const float* __restrict__ Wd,
                                                      float* __restrict__ h1) {
    int bn = blockIdx.x;
    int b = bn >> 10, n = bn & 1023;
    const float* xb = x + (size_t)b * N_ * 3;

    __shared__ float nb[K_][3];
    __shared__ float ctr[3];
    int t = threadIdx.x;
    if (t < K_) {
        int j = idx[(size_t)bn * K_ + t];
        nb[t][0] = xb[j * 3 + 0];
        nb[t][1] = xb[j * 3 + 1];
        nb[t][2] = xb[j * 3 + 2];
    }
    if (t == K_) {
        ctr[0] = xb[n * 3 + 0]; ctr[1] = xb[n * 3 + 1]; ctr[2] = xb[n * 3 + 2];
    }
    __syncthreads();

    float cx = ctr[0], cy = ctr[1], cz = ctr[2];
    float wf0 = Wf[t * 3 + 0], wf1 = Wf[t * 3 + 1], wf2 = Wf[t * 3 + 2];
    float wd0 = Wd[t * 3 + 0], wd1 = Wd[t * 3 + 1], wd2 = Wd[t * 3 + 2];

    float ax = 0.f, ay = 0.f, az = 0.f;
    #pragma unroll 4
    for (int kk = 0; kk < K_; ++kk) {
        float nx = nb[kk][0], ny = nb[kk][1], nz = nb[kk][2];
        float ex = nx - cx, ey = ny - cy, ez = nz - cz;
        // cross(neigh, center)
        float rx = ny * cz - nz * cy;
        float ry = nz * cx - nx * cz;
        float rz = nx * cy - ny * cx;
        float fx = wf0 * ex + wf1 * cx + wf2 * rx;
        float fy = wf0 * ey + wf1 * cy + wf2 * ry;
        float fz = wf0 * ez + wf1 * cz + wf2 * rz;
        float gx = wd0 * ex + wd1 * cx + wd2 * rx;
        float gy = wd0 * ey + wd1 * cy + wd2 * ry;
        float gz = wd0 * ez + wd1 * cz + wd2 * rz;
        float dot = fx * gx + fy * gy + fz * gz;
        float dsq = gx * gx + gy * gy + gz * gz + EPS_;
        float coef = dot / dsq;
        float qx, qy, qz;
        if (dot >= 0.f) { qx = fx; qy = fy; qz = fz; }
        else            { qx = fx - coef * gx; qy = fy - coef * gy; qz = fz - coef * gz; }
        ax += 0.2f * fx + 0.8f * qx;
        ay += 0.2f * fy + 0.8f * qy;
        az += 0.2f * fz + 0.8f * qz;
    }
    const float inv = 1.0f / (float)K_;
    size_t base = (((size_t)b * H_ + t) * 3) * N_ + n;
    h1[base]            = ax * inv;
    h1[base + N_]       = ay * inv;
    h1[base + 2 * N_]   = az * inv;
}

// ---------------------------------------------------------------------------
// Tiled fp32 GEMM over (B,C,3,N)-layout tensors:
// out[b,o,v,n] = sum_c W[o,c] * in[b,c,v,n]  (+ add[b,o,v,n] if add != null)
// Treated as 24 slabs (b,v): out_slab(OxN) = W(OxC) * in_slab(CxN),
// row stride 3N. Tile 64x64, BK=16, 256 threads, 4x4 acc per thread.
// ---------------------------------------------------------------------------
#define BM 64
#define BN 64
#define BK 16
__global__ __launch_bounds__(256) void gemm_kernel(const float* __restrict__ W,
                                                   const float* __restrict__ in,
                                                   const float* __restrict__ add,
                                                   float* __restrict__ out,
                                                   int O, int C) {
    int slab = blockIdx.z;            // b*3 + v
    int b = slab / 3, v = slab % 3;
    const float* inS  = in  + ((size_t)b * C * 3 + v) * N_;
    float*       outS = out + ((size_t)b * O * 3 + v) * N_;
    const float* addS = add ? add + ((size_t)b * O * 3 + v) * N_ : nullptr;
    int n0 = blockIdx.x * BN;
    int m0 = blockIdx.y * BM;

    __shared__ float As[BK][BM];   // W tile, transposed
    __shared__ float Bs[BK][BN];

    int t  = threadIdx.x;
    int tx = t & 15, ty = t >> 4;
    float acc[4][4] = {};

    int wm = t >> 2;                 // 0..63
    int wk = (t & 3) * 4;            // 0,4,8,12
    int br = t >> 4;                 // 0..15
    int bc = (t & 15) * 4;           // 0..60

    for (int k0 = 0; k0 < C; k0 += BK) {
        float4 wv = *(const float4*)(W + (size_t)(m0 + wm) * C + k0 + wk);
        As[wk + 0][wm] = wv.x;
        As[wk + 1][wm] = wv.y;
        As[wk + 2][wm] = wv.z;
        As[wk + 3][wm] = wv.w;
        float4 bv = *(const float4*)(inS + (size_t)(k0 + br) * 3 * N_ + n0 + bc);
        *(float4*)&Bs[br][bc] = bv;
        __syncthreads();
        #pragma unroll
        for (int kk = 0; kk < BK; ++kk) {
            float4 a = *(const float4*)&As[kk][ty * 4];
            float4 bq = *(const float4*)&Bs[kk][tx * 4];
            float av[4] = {a.x, a.y, a.z, a.w};
            float bw[4] = {bq.x, bq.y, bq.z, bq.w};
            #pragma unroll
            for (int i = 0; i < 4; ++i)
                #pragma unroll
                for (int j = 0; j < 4; ++j)
                    acc[i][j] += av[i] * bw[j];
        }
        __syncthreads();
    }

    #pragma unroll
    for (int i = 0; i < 4; ++i) {
        size_t row = (size_t)(m0 + ty * 4 + i);
        size_t o_off = row * 3 * N_ + n0 + tx * 4;
        float4 r = make_float4(acc[i][0], acc[i][1], acc[i][2], acc[i][3]);
        if (addS) {
            float4 a = *(const float4*)(addS + o_off);
            r.x += a.x; r.y += a.y; r.z += a.z; r.w += a.w;
        }
        *(float4*)(outS + o_off) = r;
    }
}

// ---------------------------------------------------------------------------
// VN leaky-relu elementwise over (B,C,3,N): p projected against direction d.
// One thread per (b,c,n); v-axis (3) handled in-thread.
// ---------------------------------------------------------------------------
__global__ __launch_bounds__(256) void lrelu_kernel(const float* __restrict__ p,
                                                    const float* __restrict__ d,
                                                    float* __restrict__ out,
                                                    float slope, int total) {
    int i = blockIdx.x * 256 + threadIdx.x;
    if (i >= total) return;
    int n = i & 1023;
    size_t bc = (size_t)(i >> 10);
    size_t base = bc * 3 * N_ + n;
    float p0 = p[base], p1 = p[base + N_], p2 = p[base + 2 * N_];
    float d0 = d[base], d1 = d[base + N_], d2 = d[base + 2 * N_];
    float dot = p0 * d0 + p1 * d1 + p2 * d2;
    float dsq = d0 * d0 + d1 * d1 + d2 * d2 + EPS_;
    float coef = dot / dsq;
    float q0, q1, q2;
    if (dot >= 0.f) { q0 = p0; q1 = p1; q2 = p2; }
    else            { q0 = p0 - coef * d0; q1 = p1 - coef * d1; q2 = p2 - coef * d2; }
    float om = 1.0f - slope;
    out[base]          = slope * p0 + om * q0;
    out[base + N_]     = slope * p1 + om * q1;
    out[base + 2 * N_] = slope * p2 + om * q2;
}

// ---------------------------------------------------------------------------
// Mean over N: h (B,H,3,N) -> P (B,H,3). One block per (b,h,v).
// ---------------------------------------------------------------------------
__global__ __launch_bounds__(256) void pool_kernel(const float* __restrict__ h,
                                                   float* __restrict__ P) {
    size_t base = (size_t)blockIdx.x * N_;
    int t = threadIdx.x;
    float s = h[base + t] + h[base + t + 256] + h[base + t + 512] + h[base + t + 768];
    for (int off = 32; off; off >>= 1) s += __shfl_down(s, off);
    __shared__ float red[4];
    if ((t & 63) == 0) red[t >> 6] = s;
    __syncthreads();
    if (t == 0) P[blockIdx.x] = (red[0] + red[1] + red[2] + red[3]) * (1.0f / (float)N_);
}

// ---------------------------------------------------------------------------
// Concat: Hd[b, 0:128] = h ; Hd[b, 128:256] = broadcast(P) over n.
// ---------------------------------------------------------------------------
__global__ __launch_bounds__(256) void concat_kernel(const float* __restrict__ h,
                                                     const float* __restrict__ P,
                                                     float* __restrict__ Hd) {
    size_t i = (size_t)blockIdx.x * 256 + threadIdx.x;
    if (i >= (size_t)B_ * 256 * 3 * N_) return;
    int n = (int)(i & 1023);
    size_t r = i >> 10;
    int v = (int)(r % 3); r /= 3;
    int c = (int)(r % 256);
    int b = (int)(r / 256);
    float val;
    if (c < H_) val = h[(((size_t)b * H_ + c) * 3 + v) * N_ + n];
    else        val = P[((size_t)b * H_ + (c - H_)) * 3 + v];
    Hd[i] = val;
}

// ---------------------------------------------------------------------------
// Final: hid (B,H,3) -> act = vn_lrelu(hid, Wd*hid, 0.2) -> out = Wc*act
// One block per b, thread per output channel.
// ---------------------------------------------------------------------------
__global__ __launch_bounds__(128) void final_kernel(const float* __restrict__ P,
                                                    const float* __restrict__ Wd,
                                                    const float* __restrict__ Wc,
                                                    float* __restrict__ out) {
    int b = blockIdx.x;
    int t = threadIdx.x;   // output channel
    __shared__ float hid[H_][3];
    __shared__ float act[H_][3];
    const float* Pb = P + (size_t)b * H_ * 3;
    hid[t][0] = Pb[t * 3 + 0];
    hid[t][1] = Pb[t * 3 + 1];
    hid[t][2] = Pb[t * 3 + 2];
    __syncthreads();

    float d0 = 0.f, d1 = 0.f, d2 = 0.f;
    const float* wd = Wd + (size_t)t * H_;
    for (int c = 0; c < H_; ++c) {
        float w = wd[c];
        d0 += w * hid[c][0]; d1 += w * hid[c][1]; d2 += w * hid[c][2];
    }
    float p0 = hid[t][0], p1 = hid[t][1], p2 = hid[t][2];
    float dot = p0 * d0 + p1 * d1 + p2 * d2;
    float dsq = d0 * d0 + d1 * d1 + d2 * d2 + EPS_;
    float coef = dot / dsq;
    float q0, q1, q2;
    if (dot >= 0.f) { q0 = p0; q1 = p1; q2 = p2; }
    else            { q0 = p0 - coef * d0; q1 = p1 - coef * d1; q2 = p2 - coef * d2; }
    act[t][0] = 0.2f * p0 + 0.8f * q0;
    act[t][1] = 0.2f * p1 + 0.8f * q1;
    act[t][2] = 0.2f * p2 + 0.8f * q2;
    __syncthreads();

    float o0 = 0.f, o1 = 0.f, o2 = 0.f;
    const float* wc = Wc + (size_t)t * H_;
    for (int c = 0; c < H_; ++c) {
        float w = wc[c];
        o0 += w * act[c][0]; o1 += w * act[c][1]; o2 += w * act[c][2];
    }
    size_t ob = ((size_t)b * H_ + t) * 3;
    out[ob + 0] = o0; out[ob + 1] = o1; out[ob + 2] = o2;
}

// ---------------------------------------------------------------------------
extern "C" void kernel_launch(void* const* d_in, const int* in_sizes, int n_in,
                              void* d_out, int out_size, void* d_ws, size_t ws_size,
                              hipStream_t stream) {
    const float* x   = (const float*)d_in[0];
    const float* Wf  = (const float*)d_in[1];   // (H,3)
    const float* Wdp = (const float*)d_in[2];   // (H,3)
    const float* Wfc = (const float*)d_in[3];   // (2H,H)
    const float* Wd0 = (const float*)d_in[4];   // (4,2H,2H)
    const float* W0  = (const float*)d_in[5];   // (4,H,2H)
    const float* Wd1 = (const float*)d_in[6];   // (4,H,H)
    const float* W1  = (const float*)d_in[7];   // (4,H,H)
    const float* Wsc = (const float*)d_in[8];   // (4,H,2H)
    const float* Wda = (const float*)d_in[9];   // (H,H)
    const float* Wc  = (const float*)d_in[10];  // (LAT,H)
    float* out = (float*)d_out;

    // workspace carve-up
    char* ws = (char*)d_ws;
    size_t off = 0;
    auto alloc = [&](size_t bytes) {
        void* p = ws + off;
        off = (off + bytes + 255) & ~(size_t)255;
        return p;
    };
    const size_t sz128 = (size_t)B_ * H_ * 3 * N_ * sizeof(float);       // 12.6 MB
    const size_t sz256 = (size_t)B_ * 2 * H_ * 3 * N_ * sizeof(float);   // 25.2 MB
    int*   idx = (int*)  alloc((size_t)B_ * N_ * K_ * sizeof(int));
    float* Hd  = (float*)alloc(sz256);
    float* T0  = (float*)alloc(sz256);
    float* T1  = (float*)alloc(sz128);
    float* T2  = (float*)alloc(sz128);
    float* T3  = (float*)alloc(sz128);
    float* P   = (float*)alloc((size_t)B_ * H_ * 3 * sizeof(float));
    (void)ws_size; (void)in_sizes; (void)n_in; (void)out_size;

    auto gemm = [&](const float* W, int O, int C, const float* in,
                    const float* add, float* o_) {
        dim3 grid(N_ / BN, O / BM, B_ * 3);
        hipLaunchKernelGGL(gemm_kernel, grid, dim3(256), 0, stream, W, in, add, o_, O, C);
    };

    // 1. kNN
    hipLaunchKernelGGL(knn_kernel, dim3(B_ * N_), dim3(256), 0, stream, x, idx);
    // 2. conv_pos fused (features + 2 linears + vn_lrelu + mean over k) -> T1
    hipLaunchKernelGGL(convpos_kernel, dim3(B_ * N_), dim3(128), 0, stream, x, idx, Wf, Wdp, T1);
    // 3. fc_pos -> Hd (B,256,3,N)
    gemm(Wfc, 256, 128, T1, nullptr, Hd);

    // 4. Resnet blocks
    for (int i = 0; i < 4; ++i) {
        gemm(Wd0 + (size_t)i * 256 * 256, 256, 256, Hd, nullptr, T0);
        hipLaunchKernelGGL(lrelu_kernel, dim3((B_ * 256 * N_) / 256), dim3(256), 0, stream,
                           Hd, T0, T0, 0.0f, B_ * 256 * N_);                 // a0 in T0
        gemm(W0 + (size_t)i * 128 * 256, 128, 256, T0, nullptr, T1);         // net
        gemm(Wd1 + (size_t)i * 128 * 128, 128, 128, T1, nullptr, T2);
        hipLaunchKernelGGL(lrelu_kernel, dim3((B_ * 128 * N_) / 256), dim3(256), 0, stream,
                           T1, T2, T2, 0.0f, B_ * 128 * N_);                 // a1 in T2
        gemm(W1 + (size_t)i * 128 * 128, 128, 128, T2, nullptr, T3);         // dx
        gemm(Wsc + (size_t)i * 128 * 256, 128, 256, Hd, T3, T1);             // h = Ws*Hd + dx
        hipLaunchKernelGGL(pool_kernel, dim3(B_ * H_ * 3), dim3(256), 0, stream, T1, P);
        if (i < 3) {
            hipLaunchKernelGGL(concat_kernel, dim3((B_ * 256 * 3 * N_) / 256), dim3(256),
                               0, stream, T1, P, Hd);
        }
    }

    // 5. final tiny stage
    hipLaunchKernelGGL(final_kernel, dim3(B_), dim3(128), 0, stream, P, Wda, Wc, out);
}

// Round 4
// 719.810 us; speedup vs baseline: 1.3039x; 1.3039x over previous
//
#include <hip/hip_runtime.h>
#include <cfloat>
#include <cstdint>

#define B_   8
#define N_   1024
#define H_   128
#define K_   20
#define EPS_ 1e-6f
#define R_   (B_ * 3 * N_)   // 24576 activation rows (b, v, n)

typedef __attribute__((ext_vector_type(8))) short bf8_t;   // 8 bf16 = 4 VGPRs
typedef __attribute__((ext_vector_type(4))) float f4_t;

__device__ inline ushort f2bf(float f) {
    uint u = __float_as_uint(f);
    u += 0x7FFFu + ((u >> 16) & 1u);      // RNE
    return (ushort)(u >> 16);
}
__device__ inline void split_bf(float w, ushort& hi, ushort& lo) {
    hi = f2bf(w);
    lo = f2bf(w - __uint_as_float((uint)hi << 16));
}

// ---------------------------------------------------------------------------
// kNN via 4-pass 8-bit radix select (exact k-th smallest; set semantics).
// ---------------------------------------------------------------------------
__global__ __launch_bounds__(256) void knn_radix(const float* __restrict__ x,
                                                 int* __restrict__ idx) {
    int bn = blockIdx.x;
    int b = bn >> 10, n = bn & 1023;
    const float* xb = x + (size_t)b * N_ * 3;
    __shared__ uint du[N_];
    __shared__ uint hist[256];
    __shared__ uint wsum[4];
    __shared__ uint sel_bin, sel_before, s_lo, s_hi;
    int t = threadIdx.x;

    float cx = xb[n * 3 + 0], cy = xb[n * 3 + 1], cz = xb[n * 3 + 2];
    for (int j = t; j < N_; j += 256) {
        float dx = xb[j * 3 + 0] - cx;
        float dy = xb[j * 3 + 1] - cy;
        float dz = xb[j * 3 + 2] - cz;
        du[j] = __float_as_uint(dx * dx + dy * dy + dz * dz);
    }
    if (t == 0) { s_lo = 0; s_hi = 0; }

    uint rem = K_;
    uint prefix = 0;
    for (int s = 24; s >= 0; s -= 8) {
        hist[t] = 0;
        __syncthreads();
        for (int j = t; j < N_; j += 256) {
            uint u = du[j];
            if ((s == 24) || ((u >> (s + 8)) == prefix))
                atomicAdd(&hist[(u >> s) & 255u], 1u);
        }
        __syncthreads();
        uint v = hist[t];
        for (int o = 1; o < 64; o <<= 1) {
            uint pv = __shfl_up(v, o);
            if ((t & 63) >= o) v += pv;
        }
        if ((t & 63) == 63) wsum[t >> 6] = v;
        __syncthreads();
        uint addv = 0;
        for (int w = 0; w < (t >> 6); ++w) addv += wsum[w];
        v += addv;
        uint excl = v - hist[t];
        if (v >= rem && excl < rem) { sel_bin = (uint)t; sel_before = excl; }
        __syncthreads();
        prefix = (prefix << 8) | sel_bin;
        rem -= sel_before;
        __syncthreads();
    }
    uint T = prefix;
    uint nlt = K_ - rem;
    int* op = idx + (size_t)bn * K_;
    for (int j = t; j < N_; j += 256) {
        uint u = du[j];
        if (u < T) {
            uint p_ = atomicAdd(&s_lo, 1u);
            op[p_] = j;
        } else if (u == T) {
            uint p_ = atomicAdd(&s_hi, 1u);
            if (p_ < rem) op[nlt + p_] = j;
        }
    }
}

// ---------------------------------------------------------------------------
// conv_pos fused -> h1 fp32, layout (B,3,N,128) channel-contiguous.
// ---------------------------------------------------------------------------
__global__ __launch_bounds__(128) void convpos_kernel(const float* __restrict__ x,
                                                      const int* __restrict__ idx,
                                                      const float* __restrict__ Wf,
                                                      const float* __restrict__ Wd,
                                                      float* __restrict__ h1) {
    int bn = blockIdx.x;
    int b = bn >> 10, n = bn & 1023;
    const float* xb = x + (size_t)b * N_ * 3;

    __shared__ float nb[K_][3];
    __shared__ float ctr[3];
    int t = threadIdx.x;
    if (t < K_) {
        int j = idx[(size_t)bn * K_ + t];
        nb[t][0] = xb[j * 3 + 0];
        nb[t][1] = xb[j * 3 + 1];
        nb[t][2] = xb[j * 3 + 2];
    }
    if (t == K_) {
        ctr[0] = xb[n * 3 + 0]; ctr[1] = xb[n * 3 + 1]; ctr[2] = xb[n * 3 + 2];
    }
    __syncthreads();

    float cx = ctr[0], cy = ctr[1], cz = ctr[2];
    float wf0 = Wf[t * 3 + 0], wf1 = Wf[t * 3 + 1], wf2 = Wf[t * 3 + 2];
    float wd0 = Wd[t * 3 + 0], wd1 = Wd[t * 3 + 1], wd2 = Wd[t * 3 + 2];

    float ax = 0.f, ay = 0.f, az = 0.f;
    #pragma unroll 4
    for (int kk = 0; kk < K_; ++kk) {
        float nx = nb[kk][0], ny = nb[kk][1], nz = nb[kk][2];
        float ex = nx - cx, ey = ny - cy, ez = nz - cz;
        float rx = ny * cz - nz * cy;
        float ry = nz * cx - nx * cz;
        float rz = nx * cy - ny * cx;
        float fx = wf0 * ex + wf1 * cx + wf2 * rx;
        float fy = wf0 * ey + wf1 * cy + wf2 * ry;
        float fz = wf0 * ez + wf1 * cz + wf2 * rz;
        float gx = wd0 * ex + wd1 * cx + wd2 * rx;
        float gy = wd0 * ey + wd1 * cy + wd2 * ry;
        float gz = wd0 * ez + wd1 * cz + wd2 * rz;
        float dot = fx * gx + fy * gy + fz * gz;
        float dsq = gx * gx + gy * gy + gz * gz + EPS_;
        float coef = dot / dsq;
        float qx, qy, qz;
        if (dot >= 0.f) { qx = fx; qy = fy; qz = fz; }
        else            { qx = fx - coef * gx; qy = fy - coef * gy; qz = fz - coef * gz; }
        ax += 0.2f * fx + 0.8f * qx;
        ay += 0.2f * fy + 0.8f * qy;
        az += 0.2f * fz + 0.8f * qz;
    }
    const float inv = 1.0f / (float)K_;
    size_t r0 = ((size_t)b * 3) * N_ + n;
    h1[(r0 + 0 * N_) * H_ + t] = ax * inv;
    h1[(r0 + 1 * N_) * H_ + t] = ay * inv;
    h1[(r0 + 2 * N_) * H_ + t] = az * inv;
}

// ---------------------------------------------------------------------------
// Split-operand bf16 MFMA GEMM with fp32 I/O:
//   out[r][o] = sum_c W[o][c] * act[r][c]
// Both operands are split to (hi,lo) bf16 during LDS staging; the product
// uses 3 MFMAs (Ah*Bh + Ah*Bl + Al*Bh) -> ~fp32 accuracy end to end.
// lda = weight row stride (may exceed C for left-half GEMMs).
// Epilogue: optional fp32 add (addF) and per-(slab,o) broadcast add (rowAdd).
// ---------------------------------------------------------------------------
template<int WM, int WN, bool HAS_ADD, bool HAS_ROWADD>
__global__ __launch_bounds__(256) void gemm_mfma(const float* __restrict__ W,
                                                 const float* __restrict__ act,
                                                 const float* __restrict__ addF,
                                                 const float* __restrict__ rowAdd,
                                                 float* __restrict__ outF,
                                                 int O, int C, int lda) {
    constexpr int BM = 2 * WM, BN = 2 * WN, LDK = 40;   // BK = 32, 80B rows
    __shared__ __align__(16) ushort Ah[BM * LDK];
    __shared__ __align__(16) ushort Al[BM * LDK];
    __shared__ __align__(16) ushort Bh[BN * LDK];
    __shared__ __align__(16) ushort Bl[BN * LDK];

    const int t = threadIdx.x;
    const int lane = t & 63, wave = t >> 6;
    const int wm = wave >> 1, wn = wave & 1;
    const int l16 = lane & 15, quad = lane >> 4;
    const int m0 = blockIdx.y * BM;
    const long r0 = (long)blockIdx.z * N_ + blockIdx.x * BN;

    f4_t acc[WM / 16][WN / 16];
    #pragma unroll
    for (int i = 0; i < WM / 16; ++i)
        #pragma unroll
        for (int j = 0; j < WN / 16; ++j)
            #pragma unroll
            for (int e = 0; e < 4; ++e) acc[i][j][e] = 0.f;

    for (int k0 = 0; k0 < C; k0 += 32) {
        #pragma unroll
        for (int c = t; c < BM * 8; c += 256) {          // A: BM x 32 floats
            int row = c >> 3, ko = (c & 7) * 4;
            float4 w4 = *(const float4*)(W + (size_t)(m0 + row) * lda + k0 + ko);
            ushort h0, l0, h1_, l1, h2, l2, h3, l3;
            split_bf(w4.x, h0, l0); split_bf(w4.y, h1_, l1);
            split_bf(w4.z, h2, l2); split_bf(w4.w, h3, l3);
            uint2 ph, pl;
            ph.x = (uint)h0 | ((uint)h1_ << 16); ph.y = (uint)h2 | ((uint)h3 << 16);
            pl.x = (uint)l0 | ((uint)l1 << 16);  pl.y = (uint)l2 | ((uint)l3 << 16);
            *(uint2*)(Ah + row * LDK + ko) = ph;
            *(uint2*)(Al + row * LDK + ko) = pl;
        }
        #pragma unroll
        for (int c = t; c < BN * 8; c += 256) {          // B: BN x 32 floats
            int row = c >> 3, ko = (c & 7) * 4;
            float4 a4 = *(const float4*)(act + (size_t)(r0 + row) * C + k0 + ko);
            ushort h0, l0, h1_, l1, h2, l2, h3, l3;
            split_bf(a4.x, h0, l0); split_bf(a4.y, h1_, l1);
            split_bf(a4.z, h2, l2); split_bf(a4.w, h3, l3);
            uint2 ph, pl;
            ph.x = (uint)h0 | ((uint)h1_ << 16); ph.y = (uint)h2 | ((uint)h3 << 16);
            pl.x = (uint)l0 | ((uint)l1 << 16);  pl.y = (uint)l2 | ((uint)l3 << 16);
            *(uint2*)(Bh + row * LDK + ko) = ph;
            *(uint2*)(Bl + row * LDK + ko) = pl;
        }
        __syncthreads();
        bf8_t ah[WM / 16], al[WM / 16], bh[WN / 16], bl[WN / 16];
        #pragma unroll
        for (int i = 0; i < WM / 16; ++i) {
            ah[i] = *(const bf8_t*)(Ah + (wm * WM + i * 16 + l16) * LDK + quad * 8);
            al[i] = *(const bf8_t*)(Al + (wm * WM + i * 16 + l16) * LDK + quad * 8);
        }
        #pragma unroll
        for (int j = 0; j < WN / 16; ++j) {
            bh[j] = *(const bf8_t*)(Bh + (wn * WN + j * 16 + l16) * LDK + quad * 8);
            bl[j] = *(const bf8_t*)(Bl + (wn * WN + j * 16 + l16) * LDK + quad * 8);
        }
        #pragma unroll
        for (int i = 0; i < WM / 16; ++i)
            #pragma unroll
            for (int j = 0; j < WN / 16; ++j) {
                acc[i][j] = __builtin_amdgcn_mfma_f32_16x16x32_bf16(
                    ah[i], bh[j], acc[i][j], 0, 0, 0);
                acc[i][j] = __builtin_amdgcn_mfma_f32_16x16x32_bf16(
                    ah[i], bl[j], acc[i][j], 0, 0, 0);
                acc[i][j] = __builtin_amdgcn_mfma_f32_16x16x32_bf16(
                    al[i], bh[j], acc[i][j], 0, 0, 0);
            }
        __syncthreads();
    }

    #pragma unroll
    for (int i = 0; i < WM / 16; ++i) {
        int o = m0 + wm * WM + i * 16 + quad * 4;
        float4 ra;
        if (HAS_ROWADD)
            ra = *(const float4*)(rowAdd + (size_t)blockIdx.z * O + o);
        #pragma unroll
        for (int j = 0; j < WN / 16; ++j) {
            long row = r0 + wn * WN + j * 16 + l16;
            size_t off = (size_t)row * O + o;
            f4_t v = acc[i][j];
            if (HAS_ROWADD) { v[0] += ra.x; v[1] += ra.y; v[2] += ra.z; v[3] += ra.w; }
            if (HAS_ADD) {
                float4 a4 = *(const float4*)(addF + off);
                v[0] += a4.x; v[1] += a4.y; v[2] += a4.z; v[3] += a4.w;
            }
            *(float4*)(outF + off) = make_float4(v[0], v[1], v[2], v[3]);
        }
    }
}

// ---------------------------------------------------------------------------
// Exact pooled-half injection (fp32 original weights):
// addD0[s][o] = Wd0_right[o]·P_slab ; addWs[s][o] = Ws_right[o]·P_slab
// ---------------------------------------------------------------------------
__global__ __launch_bounds__(256) void rowadd_kernel(const float* __restrict__ Wd0i,
                                                     const float* __restrict__ Wsi,
                                                     const float* __restrict__ P,
                                                     float* __restrict__ addD0,
                                                     float* __restrict__ addWs) {
    int s = blockIdx.x;               // b*3 + v
    int b = s / 3, v = s % 3;
    __shared__ float Pl[128];
    int t = threadIdx.x;
    if (t < 128) Pl[t] = P[(size_t)(b * 128 + t) * 3 + v];
    __syncthreads();
    float sum = 0.f;
    const float* wr = Wd0i + (size_t)t * 256 + 128;
    #pragma unroll 8
    for (int c = 0; c < 128; ++c) sum += wr[c] * Pl[c];
    addD0[(size_t)s * 256 + t] = sum;
    if (t < 128) {
        const float* wr2 = Wsi + (size_t)t * 256 + 128;
        float s2 = 0.f;
        #pragma unroll 8
        for (int c = 0; c < 128; ++c) s2 += wr2[c] * Pl[c];
        addWs[(size_t)s * 128 + t] = s2;
    }
}

// ---------------------------------------------------------------------------
// VN relu, fp32, (B,3,N,C) layout, float4 over channels; in-place-safe
// (out may alias d: each thread writes exactly what it read).
// ---------------------------------------------------------------------------
__global__ __launch_bounds__(256) void vnrelu4(const float* __restrict__ p,
                                               const float* __restrict__ d,
                                               float* __restrict__ out,
                                               int C, int total4) {
    int i = blockIdx.x * 256 + threadIdx.x;
    if (i >= total4) return;
    int cq = C >> 2;
    int c4 = i % cq, bn = i / cq;
    int b = bn >> 10, n = bn & 1023;
    size_t vs = (size_t)N_ * C;
    size_t base = ((size_t)b * 3 * N_ + n) * C + (c4 << 2);

    f4_t p0 = *(const f4_t*)(p + base);
    f4_t p1 = *(const f4_t*)(p + base + vs);
    f4_t p2 = *(const f4_t*)(p + base + 2 * vs);
    f4_t d0 = *(const f4_t*)(d + base);
    f4_t d1 = *(const f4_t*)(d + base + vs);
    f4_t d2 = *(const f4_t*)(d + base + 2 * vs);
    f4_t o0, o1, o2;
    #pragma unroll
    for (int e = 0; e < 4; ++e) {
        float P0 = p0[e], P1 = p1[e], P2 = p2[e];
        float D0 = d0[e], D1 = d1[e], D2 = d2[e];
        float dot = P0 * D0 + P1 * D1 + P2 * D2;
        float dsq = D0 * D0 + D1 * D1 + D2 * D2 + EPS_;
        float cf = dot / dsq;
        if (dot >= 0.f) { o0[e] = P0; o1[e] = P1; o2[e] = P2; }
        else { o0[e] = P0 - cf * D0; o1[e] = P1 - cf * D1; o2[e] = P2 - cf * D2; }
    }
    *(f4_t*)(out + base) = o0;
    *(f4_t*)(out + base + vs) = o1;
    *(f4_t*)(out + base + 2 * vs) = o2;
}

// ---------------------------------------------------------------------------
// VN relu (slope 0) for trunk blocks 1..3: p = [hF (c<128) | P broadcast],
// d = d0F (256 ch), out 256 ch (may alias d).
// ---------------------------------------------------------------------------
__global__ __launch_bounds__(256) void vnrelu_cat4(const float* __restrict__ hF,
                                                   const float* __restrict__ P,
                                                   const float* __restrict__ d,
                                                   float* __restrict__ out) {
    int i = blockIdx.x * 256 + threadIdx.x;   // total = B*N*64
    int c4 = i & 63, bn = i >> 6;
    int b = bn >> 10, n = bn & 1023;
    size_t vs = (size_t)N_ * 256;
    size_t rowb = ((size_t)b * 3 * N_ + n);
    size_t base = rowb * 256 + (c4 << 2);

    f4_t p0, p1, p2;
    if (c4 < 32) {
        size_t hbase = rowb * 128 + (c4 << 2);
        size_t hvs = (size_t)N_ * 128;
        p0 = *(const f4_t*)(hF + hbase);
        p1 = *(const f4_t*)(hF + hbase + hvs);
        p2 = *(const f4_t*)(hF + hbase + 2 * hvs);
    } else {
        int c = (c4 << 2) - 128;
        #pragma unroll
        for (int e = 0; e < 4; ++e) {
            const float* Pc = P + (size_t)(b * 128 + c + e) * 3;
            p0[e] = Pc[0]; p1[e] = Pc[1]; p2[e] = Pc[2];
        }
    }
    f4_t d0 = *(const f4_t*)(d + base);
    f4_t d1 = *(const f4_t*)(d + base + vs);
    f4_t d2 = *(const f4_t*)(d + base + 2 * vs);
    f4_t o0, o1, o2;
    #pragma unroll
    for (int e = 0; e < 4; ++e) {
        float P0 = p0[e], P1 = p1[e], P2 = p2[e];
        float D0 = d0[e], D1 = d1[e], D2 = d2[e];
        float dot = P0 * D0 + P1 * D1 + P2 * D2;
        float dsq = D0 * D0 + D1 * D1 + D2 * D2 + EPS_;
        float cf = dot / dsq;
        if (dot >= 0.f) { o0[e] = P0; o1[e] = P1; o2[e] = P2; }
        else { o0[e] = P0 - cf * D0; o1[e] = P1 - cf * D1; o2[e] = P2 - cf * D2; }
    }
    *(f4_t*)(out + base) = o0;
    *(f4_t*)(out + base + vs) = o1;
    *(f4_t*)(out + base + 2 * vs) = o2;
}

// ---------------------------------------------------------------------------
// Pool over N (2 stages), hF fp32 (B,3,N,128) -> P fp32 (B,128,3)
// ---------------------------------------------------------------------------
__global__ __launch_bounds__(128) void pool1_kernel(const float* __restrict__ h,
                                                    float* __restrict__ Pp) {
    int s = blockIdx.x >> 3, ch = blockIdx.x & 7;
    int c = threadIdx.x;
    const float* hp = h + ((size_t)s * N_ + ch * 128) * H_ + c;
    float sum = 0.f;
    #pragma unroll 8
    for (int n = 0; n < 128; ++n) sum += hp[(size_t)n * H_];
    Pp[(size_t)blockIdx.x * H_ + c] = sum;
}
__global__ __launch_bounds__(128) void pool2_kernel(const float* __restrict__ Pp,
                                                    float* __restrict__ P) {
    int s = blockIdx.x;
    int b = s / 3, v = s % 3;
    int c = threadIdx.x;
    float sum = 0.f;
    #pragma unroll
    for (int ch = 0; ch < 8; ++ch) sum += Pp[((size_t)s * 8 + ch) * H_ + c];
    P[((size_t)b * H_ + c) * 3 + v] = sum * (1.0f / (float)N_);
}

// ---------------------------------------------------------------------------
// Final stage (fp32, exact)
// ---------------------------------------------------------------------------
__global__ __launch_bounds__(128) void final_kernel(const float* __restrict__ P,
                                                    const float* __restrict__ Wd,
                                                    const float* __restrict__ Wc,
                                                    float* __restrict__ out) {
    int b = blockIdx.x;
    int t = threadIdx.x;
    __shared__ float hid[H_][3];
    __shared__ float act[H_][3];
    const float* Pb = P + (size_t)b * H_ * 3;
    hid[t][0] = Pb[t * 3 + 0];
    hid[t][1] = Pb[t * 3 + 1];
    hid[t][2] = Pb[t * 3 + 2];
    __syncthreads();

    float d0 = 0.f, d1 = 0.f, d2 = 0.f;
    const float* wd = Wd + (size_t)t * H_;
    for (int c = 0; c < H_; ++c) {
        float w = wd[c];
        d0 += w * hid[c][0]; d1 += w * hid[c][1]; d2 += w * hid[c][2];
    }
    float p0 = hid[t][0], p1 = hid[t][1], p2 = hid[t][2];
    float dot = p0 * d0 + p1 * d1 + p2 * d2;
    float dsq = d0 * d0 + d1 * d1 + d2 * d2 + EPS_;
    float cf = dot / dsq;
    float q0, q1, q2;
    if (dot >= 0.f) { q0 = p0; q1 = p1; q2 = p2; }
    else            { q0 = p0 - cf * d0; q1 = p1 - cf * d1; q2 = p2 - cf * d2; }
    act[t][0] = 0.2f * p0 + 0.8f * q0;
    act[t][1] = 0.2f * p1 + 0.8f * q1;
    act[t][2] = 0.2f * p2 + 0.8f * q2;
    __syncthreads();

    float o0 = 0.f, o1 = 0.f, o2 = 0.f;
    const float* wc = Wc + (size_t)t * H_;
    for (int c = 0; c < H_; ++c) {
        float w = wc[c];
        o0 += w * act[c][0]; o1 += w * act[c][1]; o2 += w * act[c][2];
    }
    size_t ob = ((size_t)b * H_ + t) * 3;
    out[ob + 0] = o0; out[ob + 1] = o1; out[ob + 2] = o2;
}

// ---------------------------------------------------------------------------
extern "C" void kernel_launch(void* const* d_in, const int* in_sizes, int n_in,
                              void* d_out, int out_size, void* d_ws, size_t ws_size,
                              hipStream_t stream) {
    const float* x   = (const float*)d_in[0];
    const float* Wf  = (const float*)d_in[1];
    const float* Wdp = (const float*)d_in[2];
    const float* Wfc = (const float*)d_in[3];
    const float* Wd0 = (const float*)d_in[4];
    const float* W0  = (const float*)d_in[5];
    const float* Wd1 = (const float*)d_in[6];
    const float* W1  = (const float*)d_in[7];
    const float* Wsc = (const float*)d_in[8];
    const float* Wda = (const float*)d_in[9];
    const float* Wc  = (const float*)d_in[10];
    float* out = (float*)d_out;
    (void)in_sizes; (void)n_in; (void)out_size; (void)ws_size;

    char* ws = (char*)d_ws;
    size_t off = 0;
    auto alloc = [&](size_t bytes) {
        void* p = ws + off;
        off = (off + bytes + 255) & ~(size_t)255;
        return p;
    };
    const size_t e128 = (size_t)R_ * 128;   // elems
    const size_t e256 = (size_t)R_ * 256;
    int*   idx   = (int*)  alloc((size_t)B_ * N_ * K_ * sizeof(int));
    float* h1    = (float*)alloc(e128 * 4);
    float* HdF   = (float*)alloc(e256 * 4);
    float* d0F   = (float*)alloc(e256 * 4);   // also a0 (in-place)
    float* netF  = (float*)alloc(e128 * 4);
    float* d1F   = (float*)alloc(e128 * 4);   // also a1 (in-place)
    float* dx    = (float*)alloc(e128 * 4);
    float* hF[2] = { (float*)alloc(e128 * 4), (float*)alloc(e128 * 4) };
    float* addD0 = (float*)alloc(24 * 256 * 4);
    float* addWs = (float*)alloc(24 * 128 * 4);
    float* Pp    = (float*)alloc((size_t)24 * 8 * 128 * 4);
    float* P     = (float*)alloc((size_t)B_ * 128 * 3 * 4);

    hipLaunchKernelGGL(knn_radix, dim3(B_ * N_), dim3(256), 0, stream, x, idx);
    hipLaunchKernelGGL(convpos_kernel, dim3(B_ * N_), dim3(128), 0, stream,
                       x, idx, Wf, Wdp, h1);

    // fc_pos: (256,128) x h1 -> HdF
    gemm_mfma<64, 64, false, false><<<dim3(8, 2, 24), 256, 0, stream>>>(
        Wfc, h1, nullptr, nullptr, HdF, 256, 128, 128);

    for (int i = 0; i < 4; ++i) {
        int cur = i & 1, prv = cur ^ 1;
        if (i == 0) {
            gemm_mfma<64, 64, false, false><<<dim3(8, 2, 24), 256, 0, stream>>>(
                Wd0, HdF, nullptr, nullptr, d0F, 256, 256, 256);
            hipLaunchKernelGGL(vnrelu4, dim3(B_ * N_ * 64 / 256), dim3(256), 0, stream,
                               HdF, d0F, d0F, 256, B_ * N_ * 64);
        } else {
            hipLaunchKernelGGL(rowadd_kernel, dim3(24), dim3(256), 0, stream,
                               Wd0 + (size_t)i * 65536, Wsc + (size_t)i * 32768,
                               P, addD0, addWs);
            gemm_mfma<64, 64, false, true><<<dim3(8, 2, 24), 256, 0, stream>>>(
                Wd0 + (size_t)i * 65536, hF[prv], nullptr, addD0, d0F, 256, 128, 256);
            hipLaunchKernelGGL(vnrelu_cat4, dim3(B_ * N_ * 64 / 256), dim3(256), 0, stream,
                               hF[prv], P, d0F, d0F);
        }
        // net = W0 * a0  (128,256)
        gemm_mfma<64, 32, false, false><<<dim3(16, 1, 24), 256, 0, stream>>>(
            W0 + (size_t)i * 32768, d0F, nullptr, nullptr, netF, 128, 256, 256);
        // d1 = Wd1 * net  (128,128)
        gemm_mfma<64, 32, false, false><<<dim3(16, 1, 24), 256, 0, stream>>>(
            Wd1 + (size_t)i * 16384, netF, nullptr, nullptr, d1F, 128, 128, 128);
        hipLaunchKernelGGL(vnrelu4, dim3(B_ * N_ * 32 / 256), dim3(256), 0, stream,
                           netF, d1F, d1F, 128, B_ * N_ * 32);
        // dx = W1 * a1
        gemm_mfma<64, 32, false, false><<<dim3(16, 1, 24), 256, 0, stream>>>(
            W1 + (size_t)i * 16384, d1F, nullptr, nullptr, dx, 128, 128, 128);
        // h = Ws * hidden + dx
        if (i == 0) {
            gemm_mfma<64, 32, true, false><<<dim3(16, 1, 24), 256, 0, stream>>>(
                Wsc, HdF, dx, nullptr, hF[cur], 128, 256, 256);
        } else {
            gemm_mfma<64, 32, true, true><<<dim3(16, 1, 24), 256, 0, stream>>>(
                Wsc + (size_t)i * 32768, hF[prv], dx, addWs, hF[cur], 128, 128, 256);
        }
        hipLaunchKernelGGL(pool1_kernel, dim3(24 * 8), dim3(128), 0, stream, hF[cur], Pp);
        hipLaunchKernelGGL(pool2_kernel, dim3(24), dim3(128), 0, stream, Pp, P);
    }

    hipLaunchKernelGGL(final_kernel, dim3(B_), dim3(128), 0, stream, P, Wda, Wc, out);
}

// Round 5
// 605.649 us; speedup vs baseline: 1.5497x; 1.1885x over previous
//
#include <hip/hip_runtime.h>
#include <cfloat>
#include <cstdint>

#define B_   8
#define N_   1024
#define H_   128
#define K_   20
#define EPS_ 1e-6f
#define R_   (B_ * 3 * N_)   // 24576 activation rows (b, v, n)

typedef __attribute__((ext_vector_type(8))) short bf8_t;   // 8 bf16 = 4 VGPRs
typedef __attribute__((ext_vector_type(4))) float f4_t;

__device__ inline ushort f2bf(float f) {
    uint u = __float_as_uint(f);
    u += 0x7FFFu + ((u >> 16) & 1u);      // RNE
    return (ushort)(u >> 16);
}
__device__ inline float bf2f(ushort u) { return __uint_as_float((uint)u << 16); }
__device__ inline void split_bf(float w, ushort& hi, ushort& lo) {
    hi = f2bf(w);
    lo = f2bf(w - bf2f(hi));
}
// load 4 channels from hi/lo planes -> fp32
__device__ inline f4_t ld4s(const ushort* __restrict__ hi,
                            const ushort* __restrict__ lo, size_t off) {
    ushort4 h = *(const ushort4*)(hi + off);
    ushort4 l = *(const ushort4*)(lo + off);
    f4_t r;
    r[0] = bf2f(h.x) + bf2f(l.x); r[1] = bf2f(h.y) + bf2f(l.y);
    r[2] = bf2f(h.z) + bf2f(l.z); r[3] = bf2f(h.w) + bf2f(l.w);
    return r;
}
__device__ inline void st4s(ushort* __restrict__ hi, ushort* __restrict__ lo,
                            size_t off, f4_t v) {
    ushort4 h, l;
    split_bf(v[0], h.x, l.x); split_bf(v[1], h.y, l.y);
    split_bf(v[2], h.z, l.z); split_bf(v[3], h.w, l.w);
    *(ushort4*)(hi + off) = h;
    *(ushort4*)(lo + off) = l;
}

// ---------------------------------------------------------------------------
// All-weights fp32 -> hi/lo bf16 split (one kernel). Layout offsets (elems):
// Fc 0 | D0 32768 | W0 294912 | D1 425984 | W1 491520 | Ws 557056 | end 688128
// ---------------------------------------------------------------------------
#define OFF_FC 0
#define OFF_D0 32768
#define OFF_W0 294912
#define OFF_D1 425984
#define OFF_W1 491520
#define OFF_WS 557056
#define W_TOT  688128
__global__ __launch_bounds__(256) void cvt_all(const float* __restrict__ Wfc,
                                               const float* __restrict__ Wd0,
                                               const float* __restrict__ W0,
                                               const float* __restrict__ Wd1,
                                               const float* __restrict__ W1,
                                               const float* __restrict__ Wsc,
                                               ushort* __restrict__ hi,
                                               ushort* __restrict__ lo) {
    int i = blockIdx.x * 256 + threadIdx.x;
    if (i >= W_TOT) return;
    const float* src; int off;
    if (i < OFF_W0)      { if (i < OFF_D0) { src = Wfc; off = OFF_FC; }
                           else            { src = Wd0; off = OFF_D0; } }
    else if (i < OFF_W1) { if (i < OFF_D1) { src = W0;  off = OFF_W0; }
                           else            { src = Wd1; off = OFF_D1; } }
    else                 { if (i < OFF_WS) { src = W1;  off = OFF_W1; }
                           else            { src = Wsc; off = OFF_WS; } }
    ushort h, l;
    split_bf(src[i - off], h, l);
    hi[i] = h; lo[i] = l;
}

// ---------------------------------------------------------------------------
// kNN via 4-pass 8-bit radix select; per-wave privatized histograms.
// ---------------------------------------------------------------------------
__global__ __launch_bounds__(256) void knn_radix(const float* __restrict__ x,
                                                 int* __restrict__ idx) {
    int bn = blockIdx.x;
    int b = bn >> 10, n = bn & 1023;
    const float* xb = x + (size_t)b * N_ * 3;
    __shared__ uint du[N_];
    __shared__ uint hist4[4][256];
    __shared__ uint wsum[4];
    __shared__ uint sel_bin, sel_before, s_lo, s_hi;
    int t = threadIdx.x, wv = t >> 6;

    float cx = xb[n * 3 + 0], cy = xb[n * 3 + 1], cz = xb[n * 3 + 2];
    for (int j = t; j < N_; j += 256) {
        float dx = xb[j * 3 + 0] - cx;
        float dy = xb[j * 3 + 1] - cy;
        float dz = xb[j * 3 + 2] - cz;
        du[j] = __float_as_uint(dx * dx + dy * dy + dz * dz);
    }
    if (t == 0) { s_lo = 0; s_hi = 0; }

    uint rem = K_;
    uint prefix = 0;
    for (int s = 24; s >= 0; s -= 8) {
        hist4[0][t] = 0; hist4[1][t] = 0; hist4[2][t] = 0; hist4[3][t] = 0;
        __syncthreads();
        for (int j = t; j < N_; j += 256) {
            uint u = du[j];
            if ((s == 24) || ((u >> (s + 8)) == prefix))
                atomicAdd(&hist4[wv][(u >> s) & 255u], 1u);
        }
        __syncthreads();
        uint tot = hist4[0][t] + hist4[1][t] + hist4[2][t] + hist4[3][t];
        uint v = tot;
        for (int o = 1; o < 64; o <<= 1) {
            uint pv = __shfl_up(v, o);
            if ((t & 63) >= o) v += pv;
        }
        if ((t & 63) == 63) wsum[t >> 6] = v;
        __syncthreads();
        uint addv = 0;
        for (int w = 0; w < (t >> 6); ++w) addv += wsum[w];
        v += addv;
        uint excl = v - tot;
        if (v >= rem && excl < rem) { sel_bin = (uint)t; sel_before = excl; }
        __syncthreads();
        prefix = (prefix << 8) | sel_bin;
        rem -= sel_before;
        __syncthreads();
    }
    uint T = prefix;
    uint nlt = K_ - rem;
    int* op = idx + (size_t)bn * K_;
    for (int j = t; j < N_; j += 256) {
        uint u = du[j];
        if (u < T) {
            uint p_ = atomicAdd(&s_lo, 1u);
            op[p_] = j;
        } else if (u == T) {
            uint p_ = atomicAdd(&s_hi, 1u);
            if (p_ < rem) op[nlt + p_] = j;
        }
    }
}

// ---------------------------------------------------------------------------
// conv_pos fused -> h1 hi/lo planes, layout (B,3,N,128) channel-contiguous.
// ---------------------------------------------------------------------------
__global__ __launch_bounds__(128) void convpos_kernel(const float* __restrict__ x,
                                                      const int* __restrict__ idx,
                                                      const float* __restrict__ Wf,
                                                      const float* __restrict__ Wd,
                                                      ushort* __restrict__ h1h,
                                                      ushort* __restrict__ h1l) {
    int bn = blockIdx.x;
    int b = bn >> 10, n = bn & 1023;
    const float* xb = x + (size_t)b * N_ * 3;

    __shared__ float nb[K_][3];
    __shared__ float ctr[3];
    int t = threadIdx.x;
    if (t < K_) {
        int j = idx[(size_t)bn * K_ + t];
        nb[t][0] = xb[j * 3 + 0];
        nb[t][1] = xb[j * 3 + 1];
        nb[t][2] = xb[j * 3 + 2];
    }
    if (t == K_) {
        ctr[0] = xb[n * 3 + 0]; ctr[1] = xb[n * 3 + 1]; ctr[2] = xb[n * 3 + 2];
    }
    __syncthreads();

    float cx = ctr[0], cy = ctr[1], cz = ctr[2];
    float wf0 = Wf[t * 3 + 0], wf1 = Wf[t * 3 + 1], wf2 = Wf[t * 3 + 2];
    float wd0 = Wd[t * 3 + 0], wd1 = Wd[t * 3 + 1], wd2 = Wd[t * 3 + 2];

    float ax = 0.f, ay = 0.f, az = 0.f;
    #pragma unroll 4
    for (int kk = 0; kk < K_; ++kk) {
        float nx = nb[kk][0], ny = nb[kk][1], nz = nb[kk][2];
        float ex = nx - cx, ey = ny - cy, ez = nz - cz;
        float rx = ny * cz - nz * cy;
        float ry = nz * cx - nx * cz;
        float rz = nx * cy - ny * cx;
        float fx = wf0 * ex + wf1 * cx + wf2 * rx;
        float fy = wf0 * ey + wf1 * cy + wf2 * ry;
        float fz = wf0 * ez + wf1 * cz + wf2 * rz;
        float gx = wd0 * ex + wd1 * cx + wd2 * rx;
        float gy = wd0 * ey + wd1 * cy + wd2 * ry;
        float gz = wd0 * ez + wd1 * cz + wd2 * rz;
        float dot = fx * gx + fy * gy + fz * gz;
        float dsq = gx * gx + gy * gy + gz * gz + EPS_;
        float coef = dot / dsq;
        float qx, qy, qz;
        if (dot >= 0.f) { qx = fx; qy = fy; qz = fz; }
        else            { qx = fx - coef * gx; qy = fy - coef * gy; qz = fz - coef * gz; }
        ax += 0.2f * fx + 0.8f * qx;
        ay += 0.2f * fy + 0.8f * qy;
        az += 0.2f * fz + 0.8f * qz;
    }
    const float inv = 1.0f / (float)K_;
    size_t r0 = ((size_t)b * 3) * N_ + n;
    ushort hh, ll;
    split_bf(ax * inv, hh, ll);
    h1h[(r0) * H_ + t] = hh;            h1l[(r0) * H_ + t] = ll;
    split_bf(ay * inv, hh, ll);
    h1h[(r0 + N_) * H_ + t] = hh;       h1l[(r0 + N_) * H_ + t] = ll;
    split_bf(az * inv, hh, ll);
    h1h[(r0 + 2 * N_) * H_ + t] = hh;   h1l[(r0 + 2 * N_) * H_ + t] = ll;
}

// ---------------------------------------------------------------------------
// Pre-split MFMA GEMM: out[r][o] = sum_c W[o][c]*act[r][c], both operands as
// hi/lo bf16 plane pairs. 3 MFMAs per frag pair (Ah*Bh + Ah*Bl + Al*Bh).
// LDS: LDK=32, 16B chunks XOR-swizzled (chunk ^= row&3) -> uniform banking.
// Epilogue: optional fp32 adds; writes hi/lo planes and/or fp32.
// ---------------------------------------------------------------------------
template<int WM, int WN, bool HAS_ADD, bool HAS_ROWADD, bool OUT_SPLIT, bool OUT_F32>
__global__ __launch_bounds__(256) void gemm_mfma(const ushort* __restrict__ Whi,
                                                 const ushort* __restrict__ Wlo,
                                                 const ushort* __restrict__ Bhi_g,
                                                 const ushort* __restrict__ Blo_g,
                                                 const float* __restrict__ addF,
                                                 const float* __restrict__ rowAdd,
                                                 ushort* __restrict__ outHi,
                                                 ushort* __restrict__ outLo,
                                                 float* __restrict__ outF,
                                                 int O, int C, int lda) {
    constexpr int BM = 2 * WM, BN = 2 * WN;   // BK = 32
    __shared__ __align__(16) ushort Ah[BM * 32];
    __shared__ __align__(16) ushort Al[BM * 32];
    __shared__ __align__(16) ushort Bh[BN * 32];
    __shared__ __align__(16) ushort Bl[BN * 32];

    const int t = threadIdx.x;
    const int lane = t & 63, wave = t >> 6;
    const int wm = wave >> 1, wn = wave & 1;
    const int l16 = lane & 15, quad = lane >> 4;
    const int sw = (quad ^ (l16 & 3)) * 8;    // swizzled chunk offset for reads
    const int m0 = blockIdx.y * BM;
    const long r0 = (long)blockIdx.z * N_ + blockIdx.x * BN;

    f4_t acc[WM / 16][WN / 16];
    #pragma unroll
    for (int i = 0; i < WM / 16; ++i)
        #pragma unroll
        for (int j = 0; j < WN / 16; ++j)
            #pragma unroll
            for (int e = 0; e < 4; ++e) acc[i][j][e] = 0.f;

    for (int k0 = 0; k0 < C; k0 += 32) {
        #pragma unroll
        for (int c = t; c < BM * 4; c += 256) {          // A: BM rows x 4 chunks
            int row = c >> 2, ch = c & 3;
            size_t g = (size_t)(m0 + row) * lda + k0 + ch * 8;
            int ld = row * 32 + ((ch ^ (row & 3)) * 8);
            *(uint4*)(Ah + ld) = *(const uint4*)(Whi + g);
            *(uint4*)(Al + ld) = *(const uint4*)(Wlo + g);
        }
        #pragma unroll
        for (int c = t; c < BN * 4; c += 256) {          // B: BN rows x 4 chunks
            int row = c >> 2, ch = c & 3;
            size_t g = (size_t)(r0 + row) * C + k0 + ch * 8;
            int ld = row * 32 + ((ch ^ (row & 3)) * 8);
            *(uint4*)(Bh + ld) = *(const uint4*)(Bhi_g + g);
            *(uint4*)(Bl + ld) = *(const uint4*)(Blo_g + g);
        }
        __syncthreads();
        bf8_t ah[WM / 16], al[WM / 16], bh[WN / 16], bl[WN / 16];
        #pragma unroll
        for (int i = 0; i < WM / 16; ++i) {
            int ar = wm * WM + i * 16 + l16;
            ah[i] = *(const bf8_t*)(Ah + ar * 32 + sw);
            al[i] = *(const bf8_t*)(Al + ar * 32 + sw);
        }
        #pragma unroll
        for (int j = 0; j < WN / 16; ++j) {
            int br = wn * WN + j * 16 + l16;
            bh[j] = *(const bf8_t*)(Bh + br * 32 + sw);
            bl[j] = *(const bf8_t*)(Bl + br * 32 + sw);
        }
        #pragma unroll
        for (int i = 0; i < WM / 16; ++i)
            #pragma unroll
            for (int j = 0; j < WN / 16; ++j) {
                acc[i][j] = __builtin_amdgcn_mfma_f32_16x16x32_bf16(
                    ah[i], bh[j], acc[i][j], 0, 0, 0);
                acc[i][j] = __builtin_amdgcn_mfma_f32_16x16x32_bf16(
                    ah[i], bl[j], acc[i][j], 0, 0, 0);
                acc[i][j] = __builtin_amdgcn_mfma_f32_16x16x32_bf16(
                    al[i], bh[j], acc[i][j], 0, 0, 0);
            }
        __syncthreads();
    }

    #pragma unroll
    for (int i = 0; i < WM / 16; ++i) {
        int o = m0 + wm * WM + i * 16 + quad * 4;
        float4 ra;
        if (HAS_ROWADD)
            ra = *(const float4*)(rowAdd + (size_t)blockIdx.z * O + o);
        #pragma unroll
        for (int j = 0; j < WN / 16; ++j) {
            long row = r0 + wn * WN + j * 16 + l16;
            size_t off = (size_t)row * O + o;
            f4_t v = acc[i][j];
            if (HAS_ROWADD) { v[0] += ra.x; v[1] += ra.y; v[2] += ra.z; v[3] += ra.w; }
            if (HAS_ADD) {
                float4 a4 = *(const float4*)(addF + off);
                v[0] += a4.x; v[1] += a4.y; v[2] += a4.z; v[3] += a4.w;
            }
            if (OUT_F32)
                *(float4*)(outF + off) = make_float4(v[0], v[1], v[2], v[3]);
            if (OUT_SPLIT)
                st4s(outHi, outLo, off, v);
        }
    }
}

// ---------------------------------------------------------------------------
// Exact pooled-half injection (fp32 original weights + fp32 P).
// ---------------------------------------------------------------------------
__global__ __launch_bounds__(256) void rowadd_kernel(const float* __restrict__ Wd0i,
                                                     const float* __restrict__ Wsi,
                                                     const float* __restrict__ P,
                                                     float* __restrict__ addD0,
                                                     float* __restrict__ addWs) {
    int s = blockIdx.x;               // b*3 + v
    int b = s / 3, v = s % 3;
    __shared__ float Pl[128];
    int t = threadIdx.x;
    if (t < 128) Pl[t] = P[(size_t)(b * 128 + t) * 3 + v];
    __syncthreads();
    float sum = 0.f;
    const float* wr = Wd0i + (size_t)t * 256 + 128;
    #pragma unroll 8
    for (int c = 0; c < 128; ++c) sum += wr[c] * Pl[c];
    addD0[(size_t)s * 256 + t] = sum;
    if (t < 128) {
        const float* wr2 = Wsi + (size_t)t * 256 + 128;
        float s2 = 0.f;
        #pragma unroll 8
        for (int c = 0; c < 128; ++c) s2 += wr2[c] * Pl[c];
        addWs[(size_t)s * 128 + t] = s2;
    }
}

// ---------------------------------------------------------------------------
// VN relu (slope 0), hi/lo planes, (B,3,N,C); out may alias d.
// ---------------------------------------------------------------------------
__global__ __launch_bounds__(256) void vnrelu4(const ushort* __restrict__ ph,
                                               const ushort* __restrict__ pl,
                                               const ushort* __restrict__ dh,
                                               const ushort* __restrict__ dl,
                                               ushort* __restrict__ oh,
                                               ushort* __restrict__ ol,
                                               int C, int total4) {
    int i = blockIdx.x * 256 + threadIdx.x;
    if (i >= total4) return;
    int cq = C >> 2;
    int c4 = i % cq, bn = i / cq;
    int b = bn >> 10, n = bn & 1023;
    size_t vs = (size_t)N_ * C;
    size_t base = ((size_t)b * 3 * N_ + n) * C + (c4 << 2);

    f4_t p0 = ld4s(ph, pl, base);
    f4_t p1 = ld4s(ph, pl, base + vs);
    f4_t p2 = ld4s(ph, pl, base + 2 * vs);
    f4_t d0 = ld4s(dh, dl, base);
    f4_t d1 = ld4s(dh, dl, base + vs);
    f4_t d2 = ld4s(dh, dl, base + 2 * vs);
    f4_t o0, o1, o2;
    #pragma unroll
    for (int e = 0; e < 4; ++e) {
        float P0 = p0[e], P1 = p1[e], P2 = p2[e];
        float D0 = d0[e], D1 = d1[e], D2 = d2[e];
        float dot = P0 * D0 + P1 * D1 + P2 * D2;
        float dsq = D0 * D0 + D1 * D1 + D2 * D2 + EPS_;
        float cf = dot / dsq;
        if (dot >= 0.f) { o0[e] = P0; o1[e] = P1; o2[e] = P2; }
        else { o0[e] = P0 - cf * D0; o1[e] = P1 - cf * D1; o2[e] = P2 - cf * D2; }
    }
    st4s(oh, ol, base, o0);
    st4s(oh, ol, base + vs, o1);
    st4s(oh, ol, base + 2 * vs, o2);
}

// ---------------------------------------------------------------------------
// VN relu (slope 0) for blocks 1..3: p = [h planes (c<128) | P fp32 bcast],
// d = d0 planes (256 ch), out 256 ch (aliases d).
// ---------------------------------------------------------------------------
__global__ __launch_bounds__(256) void vnrelu_cat4(const ushort* __restrict__ hh,
                                                   const ushort* __restrict__ hl,
                                                   const float* __restrict__ P,
                                                   const ushort* __restrict__ dh,
                                                   const ushort* __restrict__ dl,
                                                   ushort* __restrict__ oh,
                                                   ushort* __restrict__ ol) {
    int i = blockIdx.x * 256 + threadIdx.x;   // total = B*N*64
    int c4 = i & 63, bn = i >> 6;
    int b = bn >> 10, n = bn & 1023;
    size_t vs = (size_t)N_ * 256;
    size_t rowb = ((size_t)b * 3 * N_ + n);
    size_t base = rowb * 256 + (c4 << 2);

    f4_t p0, p1, p2;
    if (c4 < 32) {
        size_t hbase = rowb * 128 + (c4 << 2);
        size_t hvs = (size_t)N_ * 128;
        p0 = ld4s(hh, hl, hbase);
        p1 = ld4s(hh, hl, hbase + hvs);
        p2 = ld4s(hh, hl, hbase + 2 * hvs);
    } else {
        int c = (c4 << 2) - 128;
        #pragma unroll
        for (int e = 0; e < 4; ++e) {
            const float* Pc = P + (size_t)(b * 128 + c + e) * 3;
            p0[e] = Pc[0]; p1[e] = Pc[1]; p2[e] = Pc[2];
        }
    }
    f4_t d0 = ld4s(dh, dl, base);
    f4_t d1 = ld4s(dh, dl, base + vs);
    f4_t d2 = ld4s(dh, dl, base + 2 * vs);
    f4_t o0, o1, o2;
    #pragma unroll
    for (int e = 0; e < 4; ++e) {
        float P0 = p0[e], P1 = p1[e], P2 = p2[e];
        float D0 = d0[e], D1 = d1[e], D2 = d2[e];
        float dot = P0 * D0 + P1 * D1 + P2 * D2;
        float dsq = D0 * D0 + D1 * D1 + D2 * D2 + EPS_;
        float cf = dot / dsq;
        if (dot >= 0.f) { o0[e] = P0; o1[e] = P1; o2[e] = P2; }
        else { o0[e] = P0 - cf * D0; o1[e] = P1 - cf * D1; o2[e] = P2 - cf * D2; }
    }
    st4s(oh, ol, base, o0);
    st4s(oh, ol, base + vs, o1);
    st4s(oh, ol, base + 2 * vs, o2);
}

// ---------------------------------------------------------------------------
// Pool over N, stage 1: block (s, ch) sums 128 n-rows of h (hi/lo planes).
// ---------------------------------------------------------------------------
__global__ __launch_bounds__(128) void pool1_kernel(const ushort* __restrict__ hh,
                                                    const ushort* __restrict__ hl,
                                                    float* __restrict__ Pp) {
    int s = blockIdx.x >> 3, ch = blockIdx.x & 7;
    int t = threadIdx.x;
    int c2 = t & 63, nh = t >> 6;                    // 2 channels, 2 n-halves
    size_t base = ((size_t)s * N_ + ch * 128 + nh * 64) * H_ + c2 * 2;
    float s0 = 0.f, s1 = 0.f;
    for (int n = 0; n < 64; ++n) {
        uint uh = *(const uint*)(hh + base + (size_t)n * H_);
        uint ul = *(const uint*)(hl + base + (size_t)n * H_);
        s0 += bf2f((ushort)uh) + bf2f((ushort)ul);
        s1 += bf2f((ushort)(uh >> 16)) + bf2f((ushort)(ul >> 16));
    }
    __shared__ float red[2][128];
    red[nh][c2 * 2] = s0;
    red[nh][c2 * 2 + 1] = s1;
    __syncthreads();
    if (t < 128) Pp[(size_t)blockIdx.x * H_ + t] = red[0][t] + red[1][t];
}
__global__ __launch_bounds__(128) void pool2_kernel(const float* __restrict__ Pp,
                                                    float* __restrict__ P) {
    int s = blockIdx.x;
    int b = s / 3, v = s % 3;
    int c = threadIdx.x;
    float sum = 0.f;
    #pragma unroll
    for (int ch = 0; ch < 8; ++ch) sum += Pp[((size_t)s * 8 + ch) * H_ + c];
    P[((size_t)b * H_ + c) * 3 + v] = sum * (1.0f / (float)N_);
}

// ---------------------------------------------------------------------------
// Final stage (fp32, exact)
// ---------------------------------------------------------------------------
__global__ __launch_bounds__(128) void final_kernel(const float* __restrict__ P,
                                                    const float* __restrict__ Wd,
                                                    const float* __restrict__ Wc,
                                                    float* __restrict__ out) {
    int b = blockIdx.x;
    int t = threadIdx.x;
    __shared__ float hid[H_][3];
    __shared__ float act[H_][3];
    const float* Pb = P + (size_t)b * H_ * 3;
    hid[t][0] = Pb[t * 3 + 0];
    hid[t][1] = Pb[t * 3 + 1];
    hid[t][2] = Pb[t * 3 + 2];
    __syncthreads();

    float d0 = 0.f, d1 = 0.f, d2 = 0.f;
    const float* wd = Wd + (size_t)t * H_;
    for (int c = 0; c < H_; ++c) {
        float w = wd[c];
        d0 += w * hid[c][0]; d1 += w * hid[c][1]; d2 += w * hid[c][2];
    }
    float p0 = hid[t][0], p1 = hid[t][1], p2 = hid[t][2];
    float dot = p0 * d0 + p1 * d1 + p2 * d2;
    float dsq = d0 * d0 + d1 * d1 + d2 * d2 + EPS_;
    float cf = dot / dsq;
    float q0, q1, q2;
    if (dot >= 0.f) { q0 = p0; q1 = p1; q2 = p2; }
    else            { q0 = p0 - cf * d0; q1 = p1 - cf * d1; q2 = p2 - cf * d2; }
    act[t][0] = 0.2f * p0 + 0.8f * q0;
    act[t][1] = 0.2f * p1 + 0.8f * q1;
    act[t][2] = 0.2f * p2 + 0.8f * q2;
    __syncthreads();

    float o0 = 0.f, o1 = 0.f, o2 = 0.f;
    const float* wc = Wc + (size_t)t * H_;
    for (int c = 0; c < H_; ++c) {
        float w = wc[c];
        o0 += w * act[c][0]; o1 += w * act[c][1]; o2 += w * act[c][2];
    }
    size_t ob = ((size_t)b * H_ + t) * 3;
    out[ob + 0] = o0; out[ob + 1] = o1; out[ob + 2] = o2;
}

// ---------------------------------------------------------------------------
extern "C" void kernel_launch(void* const* d_in, const int* in_sizes, int n_in,
                              void* d_out, int out_size, void* d_ws, size_t ws_size,
                              hipStream_t stream) {
    const float* x   = (const float*)d_in[0];
    const float* Wf  = (const float*)d_in[1];
    const float* Wdp = (const float*)d_in[2];
    const float* Wfc = (const float*)d_in[3];
    const float* Wd0 = (const float*)d_in[4];
    const float* W0  = (const float*)d_in[5];
    const float* Wd1 = (const float*)d_in[6];
    const float* W1  = (const float*)d_in[7];
    const float* Wsc = (const float*)d_in[8];
    const float* Wda = (const float*)d_in[9];
    const float* Wc  = (const float*)d_in[10];
    float* out = (float*)d_out;
    (void)in_sizes; (void)n_in; (void)out_size; (void)ws_size;

    char* ws = (char*)d_ws;
    size_t off = 0;
    auto alloc = [&](size_t bytes) {
        void* p = ws + off;
        off = (off + bytes + 255) & ~(size_t)255;
        return p;
    };
    const size_t e128 = (size_t)R_ * 128;   // elems per 128-ch plane
    const size_t e256 = (size_t)R_ * 256;
    int*    idx   = (int*)   alloc((size_t)B_ * N_ * K_ * sizeof(int));
    ushort* wAllH = (ushort*)alloc((size_t)W_TOT * 2);
    ushort* wAllL = (ushort*)alloc((size_t)W_TOT * 2);
    ushort* h1H   = (ushort*)alloc(e128 * 2);
    ushort* h1L   = (ushort*)alloc(e128 * 2);
    ushort* HdH   = (ushort*)alloc(e256 * 2);
    ushort* HdL   = (ushort*)alloc(e256 * 2);
    ushort* d0H   = (ushort*)alloc(e256 * 2);   // also a0 (in-place)
    ushort* d0L   = (ushort*)alloc(e256 * 2);
    ushort* netH  = (ushort*)alloc(e128 * 2);
    ushort* netL  = (ushort*)alloc(e128 * 2);
    ushort* d1H   = (ushort*)alloc(e128 * 2);   // also a1 (in-place)
    ushort* d1L   = (ushort*)alloc(e128 * 2);
    float*  dx    = (float*) alloc(e128 * 4);
    ushort* hH[2] = { (ushort*)alloc(e128 * 2), (ushort*)alloc(e128 * 2) };
    ushort* hL[2] = { (ushort*)alloc(e128 * 2), (ushort*)alloc(e128 * 2) };
    float*  addD0 = (float*) alloc(24 * 256 * 4);
    float*  addWs = (float*) alloc(24 * 128 * 4);
    float*  Pp    = (float*) alloc((size_t)24 * 8 * 128 * 4);
    float*  P     = (float*) alloc((size_t)B_ * 128 * 3 * 4);

    const ushort* whFc = wAllH + OFF_FC; const ushort* wlFc = wAllL + OFF_FC;
    const ushort* whD0 = wAllH + OFF_D0; const ushort* wlD0 = wAllL + OFF_D0;
    const ushort* whW0 = wAllH + OFF_W0; const ushort* wlW0 = wAllL + OFF_W0;
    const ushort* whD1 = wAllH + OFF_D1; const ushort* wlD1 = wAllL + OFF_D1;
    const ushort* whW1 = wAllH + OFF_W1; const ushort* wlW1 = wAllL + OFF_W1;
    const ushort* whWs = wAllH + OFF_WS; const ushort* wlWs = wAllL + OFF_WS;

    hipLaunchKernelGGL(cvt_all, dim3((W_TOT + 255) / 256), dim3(256), 0, stream,
                       Wfc, Wd0, W0, Wd1, W1, Wsc, wAllH, wAllL);
    hipLaunchKernelGGL(knn_radix, dim3(B_ * N_), dim3(256), 0, stream, x, idx);
    hipLaunchKernelGGL(convpos_kernel, dim3(B_ * N_), dim3(128), 0, stream,
                       x, idx, Wf, Wdp, h1H, h1L);

    // fc_pos: (256,128) x h1 -> Hd
    gemm_mfma<64, 64, false, false, true, false><<<dim3(8, 2, 24), 256, 0, stream>>>(
        whFc, wlFc, h1H, h1L, nullptr, nullptr, HdH, HdL, nullptr, 256, 128, 128);

    for (int i = 0; i < 4; ++i) {
        int cur = i & 1, prv = cur ^ 1;
        if (i == 0) {
            gemm_mfma<64, 64, false, false, true, false><<<dim3(8, 2, 24), 256, 0, stream>>>(
                whD0, wlD0, HdH, HdL, nullptr, nullptr, d0H, d0L, nullptr, 256, 256, 256);
            hipLaunchKernelGGL(vnrelu4, dim3(B_ * N_ * 64 / 256), dim3(256), 0, stream,
                               HdH, HdL, d0H, d0L, d0H, d0L, 256, B_ * N_ * 64);
        } else {
            hipLaunchKernelGGL(rowadd_kernel, dim3(24), dim3(256), 0, stream,
                               Wd0 + (size_t)i * 65536, Wsc + (size_t)i * 32768,
                               P, addD0, addWs);
            gemm_mfma<64, 64, false, true, true, false><<<dim3(8, 2, 24), 256, 0, stream>>>(
                whD0 + (size_t)i * 65536, wlD0 + (size_t)i * 65536, hH[prv], hL[prv],
                nullptr, addD0, d0H, d0L, nullptr, 256, 128, 256);
            hipLaunchKernelGGL(vnrelu_cat4, dim3(B_ * N_ * 64 / 256), dim3(256), 0, stream,
                               hH[prv], hL[prv], P, d0H, d0L, d0H, d0L);
        }
        // net = W0 * a0  (128,256)
        gemm_mfma<64, 32, false, false, true, false><<<dim3(16, 1, 24), 256, 0, stream>>>(
            whW0 + (size_t)i * 32768, wlW0 + (size_t)i * 32768, d0H, d0L,
            nullptr, nullptr, netH, netL, nullptr, 128, 256, 256);
        // d1 = Wd1 * net  (128,128)
        gemm_mfma<64, 32, false, false, true, false><<<dim3(16, 1, 24), 256, 0, stream>>>(
            whD1 + (size_t)i * 16384, wlD1 + (size_t)i * 16384, netH, netL,
            nullptr, nullptr, d1H, d1L, nullptr, 128, 128, 128);
        hipLaunchKernelGGL(vnrelu4, dim3(B_ * N_ * 32 / 256), dim3(256), 0, stream,
                           netH, netL, d1H, d1L, d1H, d1L, 128, B_ * N_ * 32);
        // dx = W1 * a1 -> fp32
        gemm_mfma<64, 32, false, false, false, true><<<dim3(16, 1, 24), 256, 0, stream>>>(
            whW1 + (size_t)i * 16384, wlW1 + (size_t)i * 16384, d1H, d1L,
            nullptr, nullptr, nullptr, nullptr, dx, 128, 128, 128);
        // h = Ws * hidden + dx
        if (i == 0) {
            gemm_mfma<64, 32, true, false, true, false><<<dim3(16, 1, 24), 256, 0, stream>>>(
                whWs, wlWs, HdH, HdL, dx, nullptr, hH[cur], hL[cur], nullptr, 128, 256, 256);
        } else {
            gemm_mfma<64, 32, true, true, true, false><<<dim3(16, 1, 24), 256, 0, stream>>>(
                whWs + (size_t)i * 32768, wlWs + (size_t)i * 32768, hH[prv], hL[prv],
                dx, addWs, hH[cur], hL[cur], nullptr, 128, 128, 256);
        }
        hipLaunchKernelGGL(pool1_kernel, dim3(24 * 8), dim3(128), 0, stream,
                           hH[cur], hL[cur], Pp);
        hipLaunchKernelGGL(pool2_kernel, dim3(24), dim3(128), 0, stream, Pp, P);
    }

    hipLaunchKernelGGL(final_kernel, dim3(B_), dim3(128), 0, stream, P, Wda, Wc, out);
}

// Round 6
// 540.765 us; speedup vs baseline: 1.7356x; 1.1200x over previous
//
#include <hip/hip_runtime.h>
#include <cfloat>
#include <cstdint>

#define B_   8
#define N_   1024
#define H_   128
#define K_   20
#define EPS_ 1e-6f
#define R_   (B_ * 3 * N_)   // 24576 activation rows (b, v, n)

typedef __attribute__((ext_vector_type(8))) short bf8_t;   // 8 bf16 = 4 VGPRs
typedef __attribute__((ext_vector_type(4))) float f4_t;

__device__ inline ushort f2bf(float f) {
    uint u = __float_as_uint(f);
    u += 0x7FFFu + ((u >> 16) & 1u);      // RNE
    return (ushort)(u >> 16);
}
__device__ inline float bf2f(ushort u) { return __uint_as_float((uint)u << 16); }
__device__ inline void split_bf(float w, ushort& hi, ushort& lo) {
    hi = f2bf(w);
    lo = f2bf(w - bf2f(hi));
}
__device__ inline f4_t ld4s(const ushort* __restrict__ hi,
                            const ushort* __restrict__ lo, size_t off) {
    ushort4 h = *(const ushort4*)(hi + off);
    ushort4 l = *(const ushort4*)(lo + off);
    f4_t r;
    r[0] = bf2f(h.x) + bf2f(l.x); r[1] = bf2f(h.y) + bf2f(l.y);
    r[2] = bf2f(h.z) + bf2f(l.z); r[3] = bf2f(h.w) + bf2f(l.w);
    return r;
}
__device__ inline void st4s(ushort* __restrict__ hi, ushort* __restrict__ lo,
                            size_t off, f4_t v) {
    ushort4 h, l;
    split_bf(v[0], h.x, l.x); split_bf(v[1], h.y, l.y);
    split_bf(v[2], h.z, l.z); split_bf(v[3], h.w, l.w);
    *(ushort4*)(hi + off) = h;
    *(ushort4*)(lo + off) = l;
}

// ---------------------------------------------------------------------------
// All-weights fp32 -> hi/lo bf16 split. Offsets (elems):
// Fc 0 | D0 32768 | W0 294912 | D1 425984 | W1 491520 | Ws 557056 | end 688128
// ---------------------------------------------------------------------------
#define OFF_FC 0
#define OFF_D0 32768
#define OFF_W0 294912
#define OFF_D1 425984
#define OFF_W1 491520
#define OFF_WS 557056
#define W_TOT  688128
__global__ __launch_bounds__(256) void cvt_all(const float* __restrict__ Wfc,
                                               const float* __restrict__ Wd0,
                                               const float* __restrict__ W0,
                                               const float* __restrict__ Wd1,
                                               const float* __restrict__ W1,
                                               const float* __restrict__ Wsc,
                                               ushort* __restrict__ hi,
                                               ushort* __restrict__ lo) {
    int i = blockIdx.x * 256 + threadIdx.x;
    if (i >= W_TOT) return;
    const float* src; int off;
    if (i < OFF_W0)      { if (i < OFF_D0) { src = Wfc; off = OFF_FC; }
                           else            { src = Wd0; off = OFF_D0; } }
    else if (i < OFF_W1) { if (i < OFF_D1) { src = W0;  off = OFF_W0; }
                           else            { src = Wd1; off = OFF_D1; } }
    else                 { if (i < OFF_WS) { src = W1;  off = OFF_W1; }
                           else            { src = Wsc; off = OFF_WS; } }
    ushort h, l;
    split_bf(src[i - off], h, l);
    hi[i] = h; lo[i] = l;
}

// ---------------------------------------------------------------------------
// kNN: wave-per-query radix select. 4 waves/block, each wave independent.
// Per-wave 256-bin LDS histogram; wave shfl-scan + ballot select; shfl-prefix
// compaction (no atomics outside the histogram).
// ---------------------------------------------------------------------------
__device__ inline uint wave_iscan(uint v, int lane) {
    #pragma unroll
    for (int o = 1; o < 64; o <<= 1) {
        uint pv = __shfl_up(v, o);
        if (lane >= o) v += pv;
    }
    return v;
}

__global__ __launch_bounds__(256) void knn_wave(const float* __restrict__ x,
                                                int* __restrict__ idx) {
    int wv = threadIdx.x >> 6, lane = threadIdx.x & 63;
    int bn = blockIdx.x * 4 + wv;
    int b = bn >> 10, n = bn & 1023;
    const float* xb = x + (size_t)b * N_ * 3;
    __shared__ uint hist[4][256];
    uint* h = hist[wv];

    float cx = xb[n * 3 + 0], cy = xb[n * 3 + 1], cz = xb[n * 3 + 2];
    uint ku[16];
    #pragma unroll
    for (int k = 0; k < 16; ++k) {
        int j = lane + (k << 6);
        float dx = xb[j * 3 + 0] - cx;
        float dy = xb[j * 3 + 1] - cy;
        float dz = xb[j * 3 + 2] - cz;
        ku[k] = __float_as_uint(dx * dx + dy * dy + dz * dz);
    }

    uint rem = K_, prefix = 0;
    for (int s = 24; s >= 0; s -= 8) {
        #pragma unroll
        for (int q = 0; q < 4; ++q) h[lane + (q << 6)] = 0;
        __syncthreads();
        #pragma unroll
        for (int k = 0; k < 16; ++k) {
            uint u = ku[k];
            if ((s == 24) || ((u >> (s + 8)) == prefix))
                atomicAdd(&h[(u >> s) & 255u], 1u);
        }
        __syncthreads();
        uint s4 = h[4 * lane] + h[4 * lane + 1] + h[4 * lane + 2] + h[4 * lane + 3];
        uint incl = wave_iscan(s4, lane);
        unsigned long long mask = __ballot(incl >= rem);
        int L = __ffsll(mask) - 1;
        uint inclL = __shfl(incl, L);
        uint sL = __shfl(s4, L);
        uint run = inclL - sL;
        uint sel_bin = 0, sel_before = 0;
        bool found = false;
        #pragma unroll
        for (int q = 0; q < 4; ++q) {
            uint hv = h[4 * L + q];
            if (!found && run + hv >= rem) { sel_bin = 4 * L + q; sel_before = run; found = true; }
            run += hv;
        }
        prefix = (prefix << 8) | sel_bin;
        rem -= sel_before;
        __syncthreads();
    }

    uint T = prefix;
    uint nlt = K_ - rem;
    int cl = 0, ce = 0;
    #pragma unroll
    for (int k = 0; k < 16; ++k) { cl += (ku[k] < T); ce += (ku[k] == T); }
    uint il = wave_iscan((uint)cl, lane);
    uint ie = wave_iscan((uint)ce, lane);
    uint pl_ = il - (uint)cl;
    uint pe  = nlt + ie - (uint)ce;
    int* op = idx + (size_t)bn * K_;
    #pragma unroll
    for (int k = 0; k < 16; ++k) {
        int j = lane + (k << 6);
        if (ku[k] < T) { op[pl_++] = j; }
        else if (ku[k] == T) { if (pe < K_) op[pe] = j; pe++; }
    }
}

// ---------------------------------------------------------------------------
// conv_pos fused -> h1 hi/lo planes, layout (B,3,N,128) channel-contiguous.
// ---------------------------------------------------------------------------
__global__ __launch_bounds__(128) void convpos_kernel(const float* __restrict__ x,
                                                      const int* __restrict__ idx,
                                                      const float* __restrict__ Wf,
                                                      const float* __restrict__ Wd,
                                                      ushort* __restrict__ h1h,
                                                      ushort* __restrict__ h1l) {
    int bn = blockIdx.x;
    int b = bn >> 10, n = bn & 1023;
    const float* xb = x + (size_t)b * N_ * 3;

    __shared__ float nb[K_][3];
    __shared__ float ctr[3];
    int t = threadIdx.x;
    if (t < K_) {
        int j = idx[(size_t)bn * K_ + t];
        nb[t][0] = xb[j * 3 + 0];
        nb[t][1] = xb[j * 3 + 1];
        nb[t][2] = xb[j * 3 + 2];
    }
    if (t == K_) {
        ctr[0] = xb[n * 3 + 0]; ctr[1] = xb[n * 3 + 1]; ctr[2] = xb[n * 3 + 2];
    }
    __syncthreads();

    float cx = ctr[0], cy = ctr[1], cz = ctr[2];
    float wf0 = Wf[t * 3 + 0], wf1 = Wf[t * 3 + 1], wf2 = Wf[t * 3 + 2];
    float wd0 = Wd[t * 3 + 0], wd1 = Wd[t * 3 + 1], wd2 = Wd[t * 3 + 2];

    float ax = 0.f, ay = 0.f, az = 0.f;
    #pragma unroll 4
    for (int kk = 0; kk < K_; ++kk) {
        float nx = nb[kk][0], ny = nb[kk][1], nz = nb[kk][2];
        float ex = nx - cx, ey = ny - cy, ez = nz - cz;
        float rx = ny * cz - nz * cy;
        float ry = nz * cx - nx * cz;
        float rz = nx * cy - ny * cx;
        float fx = wf0 * ex + wf1 * cx + wf2 * rx;
        float fy = wf0 * ey + wf1 * cy + wf2 * ry;
        float fz = wf0 * ez + wf1 * cz + wf2 * rz;
        float gx = wd0 * ex + wd1 * cx + wd2 * rx;
        float gy = wd0 * ey + wd1 * cy + wd2 * ry;
        float gz = wd0 * ez + wd1 * cz + wd2 * rz;
        float dot = fx * gx + fy * gy + fz * gz;
        float dsq = gx * gx + gy * gy + gz * gz + EPS_;
        float coef = dot / dsq;
        float qx, qy, qz;
        if (dot >= 0.f) { qx = fx; qy = fy; qz = fz; }
        else            { qx = fx - coef * gx; qy = fy - coef * gy; qz = fz - coef * gz; }
        ax += 0.2f * fx + 0.8f * qx;
        ay += 0.2f * fy + 0.8f * qy;
        az += 0.2f * fz + 0.8f * qz;
    }
    const float inv = 1.0f / (float)K_;
    size_t r0 = ((size_t)b * 3) * N_ + n;
    ushort hh, ll;
    split_bf(ax * inv, hh, ll);
    h1h[(r0) * H_ + t] = hh;            h1l[(r0) * H_ + t] = ll;
    split_bf(ay * inv, hh, ll);
    h1h[(r0 + N_) * H_ + t] = hh;       h1l[(r0 + N_) * H_ + t] = ll;
    split_bf(az * inv, hh, ll);
    h1h[(r0 + 2 * N_) * H_ + t] = hh;   h1l[(r0 + 2 * N_) * H_ + t] = ll;
}

// ---------------------------------------------------------------------------
// Pre-split MFMA GEMM (unchanged structure from R5): XOR-swizzled LDS,
// 3 MFMAs per frag pair; epilogue fp32 and/or hi/lo split output.
// ---------------------------------------------------------------------------
template<int WM, int WN, bool HAS_ROWADD, bool OUT_SPLIT, bool OUT_F32>
__global__ __launch_bounds__(256) void gemm_mfma(const ushort* __restrict__ Whi,
                                                 const ushort* __restrict__ Wlo,
                                                 const ushort* __restrict__ Bhi_g,
                                                 const ushort* __restrict__ Blo_g,
                                                 const float* __restrict__ rowAdd,
                                                 ushort* __restrict__ outHi,
                                                 ushort* __restrict__ outLo,
                                                 float* __restrict__ outF,
                                                 int O, int C, int lda) {
    constexpr int BM = 2 * WM, BN = 2 * WN;   // BK = 32
    __shared__ __align__(16) ushort Ah[BM * 32];
    __shared__ __align__(16) ushort Al[BM * 32];
    __shared__ __align__(16) ushort Bh[BN * 32];
    __shared__ __align__(16) ushort Bl[BN * 32];

    const int t = threadIdx.x;
    const int lane = t & 63, wave = t >> 6;
    const int wm = wave >> 1, wn = wave & 1;
    const int l16 = lane & 15, quad = lane >> 4;
    const int sw = (quad ^ (l16 & 3)) * 8;
    const int m0 = blockIdx.y * BM;
    const long r0 = (long)blockIdx.z * N_ + blockIdx.x * BN;

    f4_t acc[WM / 16][WN / 16];
    #pragma unroll
    for (int i = 0; i < WM / 16; ++i)
        #pragma unroll
        for (int j = 0; j < WN / 16; ++j)
            #pragma unroll
            for (int e = 0; e < 4; ++e) acc[i][j][e] = 0.f;

    for (int k0 = 0; k0 < C; k0 += 32) {
        #pragma unroll
        for (int c = t; c < BM * 4; c += 256) {
            int row = c >> 2, ch = c & 3;
            size_t g = (size_t)(m0 + row) * lda + k0 + ch * 8;
            int ld = row * 32 + ((ch ^ (row & 3)) * 8);
            *(uint4*)(Ah + ld) = *(const uint4*)(Whi + g);
            *(uint4*)(Al + ld) = *(const uint4*)(Wlo + g);
        }
        #pragma unroll
        for (int c = t; c < BN * 4; c += 256) {
            int row = c >> 2, ch = c & 3;
            size_t g = (size_t)(r0 + row) * C + k0 + ch * 8;
            int ld = row * 32 + ((ch ^ (row & 3)) * 8);
            *(uint4*)(Bh + ld) = *(const uint4*)(Bhi_g + g);
            *(uint4*)(Bl + ld) = *(const uint4*)(Blo_g + g);
        }
        __syncthreads();
        bf8_t ah[WM / 16], al[WM / 16], bh[WN / 16], bl[WN / 16];
        #pragma unroll
        for (int i = 0; i < WM / 16; ++i) {
            int ar = wm * WM + i * 16 + l16;
            ah[i] = *(const bf8_t*)(Ah + ar * 32 + sw);
            al[i] = *(const bf8_t*)(Al + ar * 32 + sw);
        }
        #pragma unroll
        for (int j = 0; j < WN / 16; ++j) {
            int br = wn * WN + j * 16 + l16;
            bh[j] = *(const bf8_t*)(Bh + br * 32 + sw);
            bl[j] = *(const bf8_t*)(Bl + br * 32 + sw);
        }
        #pragma unroll
        for (int i = 0; i < WM / 16; ++i)
            #pragma unroll
            for (int j = 0; j < WN / 16; ++j) {
                acc[i][j] = __builtin_amdgcn_mfma_f32_16x16x32_bf16(
                    ah[i], bh[j], acc[i][j], 0, 0, 0);
                acc[i][j] = __builtin_amdgcn_mfma_f32_16x16x32_bf16(
                    ah[i], bl[j], acc[i][j], 0, 0, 0);
                acc[i][j] = __builtin_amdgcn_mfma_f32_16x16x32_bf16(
                    al[i], bh[j], acc[i][j], 0, 0, 0);
            }
        __syncthreads();
    }

    #pragma unroll
    for (int i = 0; i < WM / 16; ++i) {
        int o = m0 + wm * WM + i * 16 + quad * 4;
        float4 ra;
        if (HAS_ROWADD)
            ra = *(const float4*)(rowAdd + (size_t)blockIdx.z * O + o);
        #pragma unroll
        for (int j = 0; j < WN / 16; ++j) {
            long row = r0 + wn * WN + j * 16 + l16;
            size_t off = (size_t)row * O + o;
            f4_t v = acc[i][j];
            if (HAS_ROWADD) { v[0] += ra.x; v[1] += ra.y; v[2] += ra.z; v[3] += ra.w; }
            if (OUT_F32)
                *(float4*)(outF + off) = make_float4(v[0], v[1], v[2], v[3]);
            if (OUT_SPLIT)
                st4s(outHi, outLo, off, v);
        }
    }
}

// ---------------------------------------------------------------------------
// Dual-segment GEMM: out = W0seg*A0seg + W1seg*A1seg (+rowAdd), i.e. the
// concat-K GEMM h = [Ws | W1] * [hidden ; a1]. Segment switch on k0 (uniform).
// ---------------------------------------------------------------------------
template<int WM, int WN, bool HAS_ROWADD>
__global__ __launch_bounds__(256) void gemm_dual(const ushort* __restrict__ W0h,
                                                 const ushort* __restrict__ W0l,
                                                 int lda0, int C0,
                                                 const ushort* __restrict__ A0h,
                                                 const ushort* __restrict__ A0l,
                                                 const ushort* __restrict__ W1h,
                                                 const ushort* __restrict__ W1l,
                                                 int lda1, int C1,
                                                 const ushort* __restrict__ A1h,
                                                 const ushort* __restrict__ A1l,
                                                 const float* __restrict__ rowAdd,
                                                 ushort* __restrict__ outHi,
                                                 ushort* __restrict__ outLo,
                                                 int O) {
    constexpr int BM = 2 * WM, BN = 2 * WN;
    __shared__ __align__(16) ushort Ah[BM * 32];
    __shared__ __align__(16) ushort Al[BM * 32];
    __shared__ __align__(16) ushort Bh[BN * 32];
    __shared__ __align__(16) ushort Bl[BN * 32];

    const int t = threadIdx.x;
    const int lane = t & 63, wave = t >> 6;
    const int wm = wave >> 1, wn = wave & 1;
    const int l16 = lane & 15, quad = lane >> 4;
    const int sw = (quad ^ (l16 & 3)) * 8;
    const int m0 = blockIdx.y * BM;
    const long r0 = (long)blockIdx.z * N_ + blockIdx.x * BN;

    f4_t acc[WM / 16][WN / 16];
    #pragma unroll
    for (int i = 0; i < WM / 16; ++i)
        #pragma unroll
        for (int j = 0; j < WN / 16; ++j)
            #pragma unroll
            for (int e = 0; e < 4; ++e) acc[i][j][e] = 0.f;

    const int Ct = C0 + C1;
    for (int k0 = 0; k0 < Ct; k0 += 32) {
        const bool seg = (k0 >= C0);
        const ushort* wh = seg ? W1h : W0h;
        const ushort* wl = seg ? W1l : W0l;
        const ushort* ah_g = seg ? A1h : A0h;
        const ushort* al_g = seg ? A1l : A0l;
        const int lda = seg ? lda1 : lda0;
        const int cs  = seg ? C1 : C0;        // act row length
        const int kk  = seg ? (k0 - C0) : k0;
        #pragma unroll
        for (int c = t; c < BM * 4; c += 256) {
            int row = c >> 2, ch = c & 3;
            size_t g = (size_t)(m0 + row) * lda + kk + ch * 8;
            int ld = row * 32 + ((ch ^ (row & 3)) * 8);
            *(uint4*)(Ah + ld) = *(const uint4*)(wh + g);
            *(uint4*)(Al + ld) = *(const uint4*)(wl + g);
        }
        #pragma unroll
        for (int c = t; c < BN * 4; c += 256) {
            int row = c >> 2, ch = c & 3;
            size_t g = (size_t)(r0 + row) * cs + kk + ch * 8;
            int ld = row * 32 + ((ch ^ (row & 3)) * 8);
            *(uint4*)(Bh + ld) = *(const uint4*)(ah_g + g);
            *(uint4*)(Bl + ld) = *(const uint4*)(al_g + g);
        }
        __syncthreads();
        bf8_t ah[WM / 16], al[WM / 16], bh[WN / 16], bl[WN / 16];
        #pragma unroll
        for (int i = 0; i < WM / 16; ++i) {
            int ar = wm * WM + i * 16 + l16;
            ah[i] = *(const bf8_t*)(Ah + ar * 32 + sw);
            al[i] = *(const bf8_t*)(Al + ar * 32 + sw);
        }
        #pragma unroll
        for (int j = 0; j < WN / 16; ++j) {
            int br = wn * WN + j * 16 + l16;
            bh[j] = *(const bf8_t*)(Bh + br * 32 + sw);
            bl[j] = *(const bf8_t*)(Bl + br * 32 + sw);
        }
        #pragma unroll
        for (int i = 0; i < WM / 16; ++i)
            #pragma unroll
            for (int j = 0; j < WN / 16; ++j) {
                acc[i][j] = __builtin_amdgcn_mfma_f32_16x16x32_bf16(
                    ah[i], bh[j], acc[i][j], 0, 0, 0);
                acc[i][j] = __builtin_amdgcn_mfma_f32_16x16x32_bf16(
                    ah[i], bl[j], acc[i][j], 0, 0, 0);
                acc[i][j] = __builtin_amdgcn_mfma_f32_16x16x32_bf16(
                    al[i], bh[j], acc[i][j], 0, 0, 0);
            }
        __syncthreads();
    }

    #pragma unroll
    for (int i = 0; i < WM / 16; ++i) {
        int o = m0 + wm * WM + i * 16 + quad * 4;
        float4 ra;
        if (HAS_ROWADD)
            ra = *(const float4*)(rowAdd + (size_t)blockIdx.z * O + o);
        #pragma unroll
        for (int j = 0; j < WN / 16; ++j) {
            long row = r0 + wn * WN + j * 16 + l16;
            size_t off = (size_t)row * O + o;
            f4_t v = acc[i][j];
            if (HAS_ROWADD) { v[0] += ra.x; v[1] += ra.y; v[2] += ra.z; v[3] += ra.w; }
            st4s(outHi, outLo, off, v);
        }
    }
}

// ---------------------------------------------------------------------------
// Exact pooled-half injection (fp32 original weights + fp32 P).
// ---------------------------------------------------------------------------
__global__ __launch_bounds__(256) void rowadd_kernel(const float* __restrict__ Wd0i,
                                                     const float* __restrict__ Wsi,
                                                     const float* __restrict__ P,
                                                     float* __restrict__ addD0,
                                                     float* __restrict__ addWs) {
    int s = blockIdx.x;               // b*3 + v
    int b = s / 3, v = s % 3;
    __shared__ float Pl[128];
    int t = threadIdx.x;
    if (t < 128) Pl[t] = P[(size_t)(b * 128 + t) * 3 + v];
    __syncthreads();
    float sum = 0.f;
    const float* wr = Wd0i + (size_t)t * 256 + 128;
    #pragma unroll 8
    for (int c = 0; c < 128; ++c) sum += wr[c] * Pl[c];
    addD0[(size_t)s * 256 + t] = sum;
    if (t < 128) {
        const float* wr2 = Wsi + (size_t)t * 256 + 128;
        float s2 = 0.f;
        #pragma unroll 8
        for (int c = 0; c < 128; ++c) s2 += wr2[c] * Pl[c];
        addWs[(size_t)s * 128 + t] = s2;
    }
}

// ---------------------------------------------------------------------------
// VN relu (slope 0): p from hi/lo planes, d fp32, out hi/lo planes.
// ---------------------------------------------------------------------------
__global__ __launch_bounds__(256) void vnrelu_f(const ushort* __restrict__ ph,
                                                const ushort* __restrict__ pl,
                                                const float* __restrict__ d,
                                                ushort* __restrict__ oh,
                                                ushort* __restrict__ ol,
                                                int C, int total4) {
    int i = blockIdx.x * 256 + threadIdx.x;
    if (i >= total4) return;
    int cq = C >> 2;
    int c4 = i % cq, bn = i / cq;
    int b = bn >> 10, n = bn & 1023;
    size_t vs = (size_t)N_ * C;
    size_t base = ((size_t)b * 3 * N_ + n) * C + (c4 << 2);

    f4_t p0 = ld4s(ph, pl, base);
    f4_t p1 = ld4s(ph, pl, base + vs);
    f4_t p2 = ld4s(ph, pl, base + 2 * vs);
    f4_t d0 = *(const f4_t*)(d + base);
    f4_t d1 = *(const f4_t*)(d + base + vs);
    f4_t d2 = *(const f4_t*)(d + base + 2 * vs);
    f4_t o0, o1, o2;
    #pragma unroll
    for (int e = 0; e < 4; ++e) {
        float P0 = p0[e], P1 = p1[e], P2 = p2[e];
        float D0 = d0[e], D1 = d1[e], D2 = d2[e];
        float dot = P0 * D0 + P1 * D1 + P2 * D2;
        float dsq = D0 * D0 + D1 * D1 + D2 * D2 + EPS_;
        float cf = dot / dsq;
        if (dot >= 0.f) { o0[e] = P0; o1[e] = P1; o2[e] = P2; }
        else { o0[e] = P0 - cf * D0; o1[e] = P1 - cf * D1; o2[e] = P2 - cf * D2; }
    }
    st4s(oh, ol, base, o0);
    st4s(oh, ol, base + vs, o1);
    st4s(oh, ol, base + 2 * vs, o2);
}

// ---------------------------------------------------------------------------
// VN relu (slope 0), blocks 1..3: p = [h planes (c<128) | P fp32 bcast],
// d fp32 (256 ch), out hi/lo planes (256 ch).
// ---------------------------------------------------------------------------
__global__ __launch_bounds__(256) void vnrelu_cat_f(const ushort* __restrict__ hh,
                                                    const ushort* __restrict__ hl,
                                                    const float* __restrict__ P,
                                                    const float* __restrict__ d,
                                                    ushort* __restrict__ oh,
                                                    ushort* __restrict__ ol) {
    int i = blockIdx.x * 256 + threadIdx.x;   // total = B*N*64
    int c4 = i & 63, bn = i >> 6;
    int b = bn >> 10, n = bn & 1023;
    size_t vs = (size_t)N_ * 256;
    size_t rowb = ((size_t)b * 3 * N_ + n);
    size_t base = rowb * 256 + (c4 << 2);

    f4_t p0, p1, p2;
    if (c4 < 32) {
        size_t hbase = rowb * 128 + (c4 << 2);
        size_t hvs = (size_t)N_ * 128;
        p0 = ld4s(hh, hl, hbase);
        p1 = ld4s(hh, hl, hbase + hvs);
        p2 = ld4s(hh, hl, hbase + 2 * hvs);
    } else {
        int c = (c4 << 2) - 128;
        #pragma unroll
        for (int e = 0; e < 4; ++e) {
            const float* Pc = P + (size_t)(b * 128 + c + e) * 3;
            p0[e] = Pc[0]; p1[e] = Pc[1]; p2[e] = Pc[2];
        }
    }
    f4_t d0 = *(const f4_t*)(d + base);
    f4_t d1 = *(const f4_t*)(d + base + vs);
    f4_t d2 = *(const f4_t*)(d + base + 2 * vs);
    f4_t o0, o1, o2;
    #pragma unroll
    for (int e = 0; e < 4; ++e) {
        float P0 = p0[e], P1 = p1[e], P2 = p2[e];
        float D0 = d0[e], D1 = d1[e], D2 = d2[e];
        float dot = P0 * D0 + P1 * D1 + P2 * D2;
        float dsq = D0 * D0 + D1 * D1 + D2 * D2 + EPS_;
        float cf = dot / dsq;
        if (dot >= 0.f) { o0[e] = P0; o1[e] = P1; o2[e] = P2; }
        else { o0[e] = P0 - cf * D0; o1[e] = P1 - cf * D1; o2[e] = P2 - cf * D2; }
    }
    st4s(oh, ol, base, o0);
    st4s(oh, ol, base + vs, o1);
    st4s(oh, ol, base + 2 * vs, o2);
}

// ---------------------------------------------------------------------------
// Pool over N (2 stages), h hi/lo planes (B,3,N,128) -> P fp32 (B,128,3)
// ---------------------------------------------------------------------------
__global__ __launch_bounds__(128) void pool1_kernel(const ushort* __restrict__ hh,
                                                    const ushort* __restrict__ hl,
                                                    float* __restrict__ Pp) {
    int s = blockIdx.x >> 4, ch = blockIdx.x & 15;
    int t = threadIdx.x;
    int c2 = t & 63, nh = t >> 6;
    size_t base = ((size_t)s * N_ + ch * 64 + nh * 32) * H_ + c2 * 2;
    float s0 = 0.f, s1 = 0.f;
    for (int n = 0; n < 32; ++n) {
        uint uh = *(const uint*)(hh + base + (size_t)n * H_);
        uint ul = *(const uint*)(hl + base + (size_t)n * H_);
        s0 += bf2f((ushort)uh) + bf2f((ushort)ul);
        s1 += bf2f((ushort)(uh >> 16)) + bf2f((ushort)(ul >> 16));
    }
    __shared__ float red[2][128];
    red[nh][c2 * 2] = s0;
    red[nh][c2 * 2 + 1] = s1;
    __syncthreads();
    if (t < 128) Pp[(size_t)blockIdx.x * H_ + t] = red[0][t] + red[1][t];
}
__global__ __launch_bounds__(128) void pool2_kernel(const float* __restrict__ Pp,
                                                    float* __restrict__ P) {
    int s = blockIdx.x;
    int b = s / 3, v = s % 3;
    int c = threadIdx.x;
    float sum = 0.f;
    #pragma unroll
    for (int ch = 0; ch < 16; ++ch) sum += Pp[((size_t)s * 16 + ch) * H_ + c];
    P[((size_t)b * H_ + c) * 3 + v] = sum * (1.0f / (float)N_);
}

// ---------------------------------------------------------------------------
// Final stage (fp32, exact)
// ---------------------------------------------------------------------------
__global__ __launch_bounds__(128) void final_kernel(const float* __restrict__ P,
                                                    const float* __restrict__ Wd,
                                                    const float* __restrict__ Wc,
                                                    float* __restrict__ out) {
    int b = blockIdx.x;
    int t = threadIdx.x;
    __shared__ float hid[H_][3];
    __shared__ float act[H_][3];
    const float* Pb = P + (size_t)b * H_ * 3;
    hid[t][0] = Pb[t * 3 + 0];
    hid[t][1] = Pb[t * 3 + 1];
    hid[t][2] = Pb[t * 3 + 2];
    __syncthreads();

    float d0 = 0.f, d1 = 0.f, d2 = 0.f;
    const float* wd = Wd + (size_t)t * H_;
    for (int c = 0; c < H_; ++c) {
        float w = wd[c];
        d0 += w * hid[c][0]; d1 += w * hid[c][1]; d2 += w * hid[c][2];
    }
    float p0 = hid[t][0], p1 = hid[t][1], p2 = hid[t][2];
    float dot = p0 * d0 + p1 * d1 + p2 * d2;
    float dsq = d0 * d0 + d1 * d1 + d2 * d2 + EPS_;
    float cf = dot / dsq;
    float q0, q1, q2;
    if (dot >= 0.f) { q0 = p0; q1 = p1; q2 = p2; }
    else            { q0 = p0 - cf * d0; q1 = p1 - cf * d1; q2 = p2 - cf * d2; }
    act[t][0] = 0.2f * p0 + 0.8f * q0;
    act[t][1] = 0.2f * p1 + 0.8f * q1;
    act[t][2] = 0.2f * p2 + 0.8f * q2;
    __syncthreads();

    float o0 = 0.f, o1 = 0.f, o2 = 0.f;
    const float* wc = Wc + (size_t)t * H_;
    for (int c = 0; c < H_; ++c) {
        float w = wc[c];
        o0 += w * act[c][0]; o1 += w * act[c][1]; o2 += w * act[c][2];
    }
    size_t ob = ((size_t)b * H_ + t) * 3;
    out[ob + 0] = o0; out[ob + 1] = o1; out[ob + 2] = o2;
}

// ---------------------------------------------------------------------------
extern "C" void kernel_launch(void* const* d_in, const int* in_sizes, int n_in,
                              void* d_out, int out_size, void* d_ws, size_t ws_size,
                              hipStream_t stream) {
    const float* x   = (const float*)d_in[0];
    const float* Wf  = (const float*)d_in[1];
    const float* Wdp = (const float*)d_in[2];
    const float* Wfc = (const float*)d_in[3];
    const float* Wd0 = (const float*)d_in[4];
    const float* W0  = (const float*)d_in[5];
    const float* Wd1 = (const float*)d_in[6];
    const float* W1  = (const float*)d_in[7];
    const float* Wsc = (const float*)d_in[8];
    const float* Wda = (const float*)d_in[9];
    const float* Wc  = (const float*)d_in[10];
    float* out = (float*)d_out;
    (void)in_sizes; (void)n_in; (void)out_size; (void)ws_size;

    char* ws = (char*)d_ws;
    size_t off = 0;
    auto alloc = [&](size_t bytes) {
        void* p = ws + off;
        off = (off + bytes + 255) & ~(size_t)255;
        return p;
    };
    const size_t e128 = (size_t)R_ * 128;
    const size_t e256 = (size_t)R_ * 256;
    int*    idx   = (int*)   alloc((size_t)B_ * N_ * K_ * sizeof(int));
    ushort* wAllH = (ushort*)alloc((size_t)W_TOT * 2);
    ushort* wAllL = (ushort*)alloc((size_t)W_TOT * 2);
    ushort* h1H   = (ushort*)alloc(e128 * 2);
    ushort* h1L   = (ushort*)alloc(e128 * 2);
    ushort* HdH   = (ushort*)alloc(e256 * 2);
    ushort* HdL   = (ushort*)alloc(e256 * 2);
    float*  d0F   = (float*) alloc(e256 * 4);
    ushort* a0H   = (ushort*)alloc(e256 * 2);
    ushort* a0L   = (ushort*)alloc(e256 * 2);
    ushort* netH  = (ushort*)alloc(e128 * 2);
    ushort* netL  = (ushort*)alloc(e128 * 2);
    float*  d1F   = (float*) alloc(e128 * 4);
    ushort* a1H   = (ushort*)alloc(e128 * 2);
    ushort* a1L   = (ushort*)alloc(e128 * 2);
    ushort* hH[2] = { (ushort*)alloc(e128 * 2), (ushort*)alloc(e128 * 2) };
    ushort* hL[2] = { (ushort*)alloc(e128 * 2), (ushort*)alloc(e128 * 2) };
    float*  addD0 = (float*) alloc(24 * 256 * 4);
    float*  addWs = (float*) alloc(24 * 128 * 4);
    float*  Pp    = (float*) alloc((size_t)24 * 16 * 128 * 4);
    float*  P     = (float*) alloc((size_t)B_ * 128 * 3 * 4);

    const ushort* whFc = wAllH + OFF_FC; const ushort* wlFc = wAllL + OFF_FC;
    const ushort* whD0 = wAllH + OFF_D0; const ushort* wlD0 = wAllL + OFF_D0;
    const ushort* whW0 = wAllH + OFF_W0; const ushort* wlW0 = wAllL + OFF_W0;
    const ushort* whD1 = wAllH + OFF_D1; const ushort* wlD1 = wAllL + OFF_D1;
    const ushort* whW1 = wAllH + OFF_W1; const ushort* wlW1 = wAllL + OFF_W1;
    const ushort* whWs = wAllH + OFF_WS; const ushort* wlWs = wAllL + OFF_WS;

    hipLaunchKernelGGL(cvt_all, dim3((W_TOT + 255) / 256), dim3(256), 0, stream,
                       Wfc, Wd0, W0, Wd1, W1, Wsc, wAllH, wAllL);
    hipLaunchKernelGGL(knn_wave, dim3(B_ * N_ / 4), dim3(256), 0, stream, x, idx);
    hipLaunchKernelGGL(convpos_kernel, dim3(B_ * N_), dim3(128), 0, stream,
                       x, idx, Wf, Wdp, h1H, h1L);

    // fc_pos: (256,128) x h1 -> Hd planes
    gemm_mfma<64, 64, false, true, false><<<dim3(8, 2, 24), 256, 0, stream>>>(
        whFc, wlFc, h1H, h1L, nullptr, HdH, HdL, nullptr, 256, 128, 128);

    for (int i = 0; i < 4; ++i) {
        int cur = i & 1, prv = cur ^ 1;
        if (i == 0) {
            gemm_mfma<64, 64, false, false, true><<<dim3(8, 2, 24), 256, 0, stream>>>(
                whD0, wlD0, HdH, HdL, nullptr, nullptr, nullptr, d0F, 256, 256, 256);
            hipLaunchKernelGGL(vnrelu_f, dim3(B_ * N_ * 64 / 256), dim3(256), 0, stream,
                               HdH, HdL, d0F, a0H, a0L, 256, B_ * N_ * 64);
        } else {
            hipLaunchKernelGGL(rowadd_kernel, dim3(24), dim3(256), 0, stream,
                               Wd0 + (size_t)i * 65536, Wsc + (size_t)i * 32768,
                               P, addD0, addWs);
            gemm_mfma<64, 64, true, false, true><<<dim3(8, 2, 24), 256, 0, stream>>>(
                whD0 + (size_t)i * 65536, wlD0 + (size_t)i * 65536, hH[prv], hL[prv],
                addD0, nullptr, nullptr, d0F, 256, 128, 256);
            hipLaunchKernelGGL(vnrelu_cat_f, dim3(B_ * N_ * 64 / 256), dim3(256), 0, stream,
                               hH[prv], hL[prv], P, d0F, a0H, a0L);
        }
        // net = W0 * a0  (128,256)
        gemm_mfma<64, 32, false, true, false><<<dim3(16, 1, 24), 256, 0, stream>>>(
            whW0 + (size_t)i * 32768, wlW0 + (size_t)i * 32768, a0H, a0L,
            nullptr, netH, netL, nullptr, 128, 256, 256);
        // d1 = Wd1 * net  (128,128) -> fp32
        gemm_mfma<64, 32, false, false, true><<<dim3(16, 1, 24), 256, 0, stream>>>(
            whD1 + (size_t)i * 16384, wlD1 + (size_t)i * 16384, netH, netL,
            nullptr, nullptr, nullptr, d1F, 128, 128, 128);
        hipLaunchKernelGGL(vnrelu_f, dim3(B_ * N_ * 32 / 256), dim3(256), 0, stream,
                           netH, netL, d1F, a1H, a1L, 128, B_ * N_ * 32);
        // h = [Ws | W1] * [hidden ; a1]  (+rowAdd for i>0)
        if (i == 0) {
            gemm_dual<64, 32, false><<<dim3(16, 1, 24), 256, 0, stream>>>(
                whWs, wlWs, 256, 256, HdH, HdL,
                whW1, wlW1, 128, 128, a1H, a1L,
                nullptr, hH[cur], hL[cur], 128);
        } else {
            gemm_dual<64, 32, true><<<dim3(16, 1, 24), 256, 0, stream>>>(
                whWs + (size_t)i * 32768, wlWs + (size_t)i * 32768, 256, 128,
                hH[prv], hL[prv],
                whW1 + (size_t)i * 16384, wlW1 + (size_t)i * 16384, 128, 128,
                a1H, a1L,
                addWs, hH[cur], hL[cur], 128);
        }
        hipLaunchKernelGGL(pool1_kernel, dim3(24 * 16), dim3(128), 0, stream,
                           hH[cur], hL[cur], Pp);
        hipLaunchKernelGGL(pool2_kernel, dim3(24), dim3(128), 0, stream, Pp, P);
    }

    hipLaunchKernelGGL(final_kernel, dim3(B_), dim3(128), 0, stream, P, Wda, Wc, out);
}

// Round 7
// 509.370 us; speedup vs baseline: 1.8426x; 1.0616x over previous
//
#include <hip/hip_runtime.h>
#include <cfloat>
#include <cstdint>

#define B_   8
#define N_   1024
#define H_   128
#define K_   20
#define EPS_ 1e-6f
#define R_   (B_ * 3 * N_)

typedef __attribute__((ext_vector_type(8))) short bf8_t;
typedef __attribute__((ext_vector_type(4))) float f4_t;

__device__ inline ushort f2bf(float f) {
    uint u = __float_as_uint(f);
    u += 0x7FFFu + ((u >> 16) & 1u);
    return (ushort)(u >> 16);
}
__device__ inline float bf2f(ushort u) { return __uint_as_float((uint)u << 16); }
__device__ inline void split_bf(float w, ushort& hi, ushort& lo) {
    hi = f2bf(w);
    lo = f2bf(w - bf2f(hi));
}
__device__ inline f4_t ld4s(const ushort* __restrict__ hi,
                            const ushort* __restrict__ lo, size_t off) {
    ushort4 h = *(const ushort4*)(hi + off);
    ushort4 l = *(const ushort4*)(lo + off);
    f4_t r;
    r[0] = bf2f(h.x) + bf2f(l.x); r[1] = bf2f(h.y) + bf2f(l.y);
    r[2] = bf2f(h.z) + bf2f(l.z); r[3] = bf2f(h.w) + bf2f(l.w);
    return r;
}
__device__ inline void st4s(ushort* __restrict__ hi, ushort* __restrict__ lo,
                            size_t off, f4_t v) {
    ushort4 h, l;
    split_bf(v[0], h.x, l.x); split_bf(v[1], h.y, l.y);
    split_bf(v[2], h.z, l.z); split_bf(v[3], h.w, l.w);
    *(ushort4*)(hi + off) = h;
    *(ushort4*)(lo + off) = l;
}

// ---------------------------------------------------------------------------
// All-weights fp32 -> hi/lo bf16 split.
// ---------------------------------------------------------------------------
#define OFF_FC 0
#define OFF_D0 32768
#define OFF_W0 294912
#define OFF_D1 425984
#define OFF_W1 491520
#define OFF_WS 557056
#define W_TOT  688128
__global__ __launch_bounds__(256) void cvt_all(const float* __restrict__ Wfc,
                                               const float* __restrict__ Wd0,
                                               const float* __restrict__ W0,
                                               const float* __restrict__ Wd1,
                                               const float* __restrict__ W1,
                                               const float* __restrict__ Wsc,
                                               ushort* __restrict__ hi,
                                               ushort* __restrict__ lo) {
    int i = blockIdx.x * 256 + threadIdx.x;
    if (i >= W_TOT) return;
    const float* src; int off;
    if (i < OFF_W0)      { if (i < OFF_D0) { src = Wfc; off = OFF_FC; }
                           else            { src = Wd0; off = OFF_D0; } }
    else if (i < OFF_W1) { if (i < OFF_D1) { src = W0;  off = OFF_W0; }
                           else            { src = Wd1; off = OFF_D1; } }
    else                 { if (i < OFF_WS) { src = W1;  off = OFF_W1; }
                           else            { src = Wsc; off = OFF_WS; } }
    ushort h, l;
    split_bf(src[i - off], h, l);
    hi[i] = h; lo[i] = l;
}

// ---------------------------------------------------------------------------
// kNN: wave-per-query radix select (unchanged from R6 — verified).
// ---------------------------------------------------------------------------
__device__ inline uint wave_iscan(uint v, int lane) {
    #pragma unroll
    for (int o = 1; o < 64; o <<= 1) {
        uint pv = __shfl_up(v, o);
        if (lane >= o) v += pv;
    }
    return v;
}

__global__ __launch_bounds__(256) void knn_wave(const float* __restrict__ x,
                                                int* __restrict__ idx) {
    int wv = threadIdx.x >> 6, lane = threadIdx.x & 63;
    int bn = blockIdx.x * 4 + wv;
    int b = bn >> 10, n = bn & 1023;
    const float* xb = x + (size_t)b * N_ * 3;
    __shared__ uint hist[4][256];
    uint* h = hist[wv];

    float cx = xb[n * 3 + 0], cy = xb[n * 3 + 1], cz = xb[n * 3 + 2];
    uint ku[16];
    #pragma unroll
    for (int k = 0; k < 16; ++k) {
        int j = lane + (k << 6);
        float dx = xb[j * 3 + 0] - cx;
        float dy = xb[j * 3 + 1] - cy;
        float dz = xb[j * 3 + 2] - cz;
        ku[k] = __float_as_uint(dx * dx + dy * dy + dz * dz);
    }

    uint rem = K_, prefix = 0;
    for (int s = 24; s >= 0; s -= 8) {
        #pragma unroll
        for (int q = 0; q < 4; ++q) h[lane + (q << 6)] = 0;
        __syncthreads();
        #pragma unroll
        for (int k = 0; k < 16; ++k) {
            uint u = ku[k];
            if ((s == 24) || ((u >> (s + 8)) == prefix))
                atomicAdd(&h[(u >> s) & 255u], 1u);
        }
        __syncthreads();
        uint s4 = h[4 * lane] + h[4 * lane + 1] + h[4 * lane + 2] + h[4 * lane + 3];
        uint incl = wave_iscan(s4, lane);
        unsigned long long mask = __ballot(incl >= rem);
        int L = __ffsll(mask) - 1;
        uint inclL = __shfl(incl, L);
        uint sL = __shfl(s4, L);
        uint run = inclL - sL;
        uint sel_bin = 0, sel_before = 0;
        bool found = false;
        #pragma unroll
        for (int q = 0; q < 4; ++q) {
            uint hv = h[4 * L + q];
            if (!found && run + hv >= rem) { sel_bin = 4 * L + q; sel_before = run; found = true; }
            run += hv;
        }
        prefix = (prefix << 8) | sel_bin;
        rem -= sel_before;
        __syncthreads();
    }

    uint T = prefix;
    uint nlt = K_ - rem;
    int cl = 0, ce = 0;
    #pragma unroll
    for (int k = 0; k < 16; ++k) { cl += (ku[k] < T); ce += (ku[k] == T); }
    uint il = wave_iscan((uint)cl, lane);
    uint ie = wave_iscan((uint)ce, lane);
    uint pl_ = il - (uint)cl;
    uint pe  = nlt + ie - (uint)ce;
    int* op = idx + (size_t)bn * K_;
    #pragma unroll
    for (int k = 0; k < 16; ++k) {
        int j = lane + (k << 6);
        if (ku[k] < T) { op[pl_++] = j; }
        else if (ku[k] == T) { if (pe < K_) op[pe] = j; pe++; }
    }
}

// ---------------------------------------------------------------------------
// conv_pos fused -> h1 hi/lo planes (B,3,N,128).
// ---------------------------------------------------------------------------
__global__ __launch_bounds__(128) void convpos_kernel(const float* __restrict__ x,
                                                      const int* __restrict__ idx,
                                                      const float* __restrict__ Wf,
                                                      const float* __restrict__ Wd,
                                                      ushort* __restrict__ h1h,
                                                      ushort* __restrict__ h1l) {
    int bn = blockIdx.x;
    int b = bn >> 10, n = bn & 1023;
    const float* xb = x + (size_t)b * N_ * 3;

    __shared__ float nb[K_][3];
    __shared__ float ctr[3];
    int t = threadIdx.x;
    if (t < K_) {
        int j = idx[(size_t)bn * K_ + t];
        nb[t][0] = xb[j * 3 + 0];
        nb[t][1] = xb[j * 3 + 1];
        nb[t][2] = xb[j * 3 + 2];
    }
    if (t == K_) {
        ctr[0] = xb[n * 3 + 0]; ctr[1] = xb[n * 3 + 1]; ctr[2] = xb[n * 3 + 2];
    }
    __syncthreads();

    float cx = ctr[0], cy = ctr[1], cz = ctr[2];
    float wf0 = Wf[t * 3 + 0], wf1 = Wf[t * 3 + 1], wf2 = Wf[t * 3 + 2];
    float wd0 = Wd[t * 3 + 0], wd1 = Wd[t * 3 + 1], wd2 = Wd[t * 3 + 2];

    float ax = 0.f, ay = 0.f, az = 0.f;
    #pragma unroll 4
    for (int kk = 0; kk < K_; ++kk) {
        float nx = nb[kk][0], ny = nb[kk][1], nz = nb[kk][2];
        float ex = nx - cx, ey = ny - cy, ez = nz - cz;
        float rx = ny * cz - nz * cy;
        float ry = nz * cx - nx * cz;
        float rz = nx * cy - ny * cx;
        float fx = wf0 * ex + wf1 * cx + wf2 * rx;
        float fy = wf0 * ey + wf1 * cy + wf2 * ry;
        float fz = wf0 * ez + wf1 * cz + wf2 * rz;
        float gx = wd0 * ex + wd1 * cx + wd2 * rx;
        float gy = wd0 * ey + wd1 * cy + wd2 * ry;
        float gz = wd0 * ez + wd1 * cz + wd2 * rz;
        float dot = fx * gx + fy * gy + fz * gz;
        float dsq = gx * gx + gy * gy + gz * gz + EPS_;
        float coef = dot / dsq;
        float qx, qy, qz;
        if (dot >= 0.f) { qx = fx; qy = fy; qz = fz; }
        else            { qx = fx - coef * gx; qy = fy - coef * gy; qz = fz - coef * gz; }
        ax += 0.2f * fx + 0.8f * qx;
        ay += 0.2f * fy + 0.8f * qy;
        az += 0.2f * fz + 0.8f * qz;
    }
    const float inv = 1.0f / (float)K_;
    size_t r0 = ((size_t)b * 3) * N_ + n;
    ushort hh, ll;
    split_bf(ax * inv, hh, ll);
    h1h[(r0) * H_ + t] = hh;            h1l[(r0) * H_ + t] = ll;
    split_bf(ay * inv, hh, ll);
    h1h[(r0 + N_) * H_ + t] = hh;       h1l[(r0 + N_) * H_ + t] = ll;
    split_bf(az * inv, hh, ll);
    h1h[(r0 + 2 * N_) * H_ + t] = hh;   h1l[(r0 + 2 * N_) * H_ + t] = ll;
}

// ---------------------------------------------------------------------------
// 3-v fused split MFMA GEMM. One block computes a 64(o) x 64(n) tile for ALL
// 3 v-slabs of batch b = blockIdx.z (weights staged once; acc[3] per lane).
// RELU_MODE: 0=none (write GEMM result), 1=VN-relu with p from pPlanes
// (stride O), 2=VN-relu with p = [pPlanes (o<128, stride 128) | P bcast].
// Optional per-(b,v,o) rowAdd before relu/write.
// ---------------------------------------------------------------------------
template<int RELU_MODE, bool HAS_ROWADD>
__global__ __launch_bounds__(256) void gemm3v(const ushort* __restrict__ Whi,
                                              const ushort* __restrict__ Wlo,
                                              int lda,
                                              const ushort* __restrict__ Ahi,
                                              const ushort* __restrict__ Alo,
                                              int C,
                                              const ushort* __restrict__ pHi,
                                              const ushort* __restrict__ pLo,
                                              const float* __restrict__ P,
                                              const float* __restrict__ rowAdd,
                                              ushort* __restrict__ outHi,
                                              ushort* __restrict__ outLo,
                                              int O) {
    __shared__ __align__(16) ushort Ah[64 * 32];
    __shared__ __align__(16) ushort Al[64 * 32];
    __shared__ __align__(16) ushort Bh[3][64 * 32];
    __shared__ __align__(16) ushort Bl[3][64 * 32];

    const int t = threadIdx.x;
    const int lane = t & 63, wave = t >> 6;
    const int wm = wave >> 1, wn = wave & 1;
    const int l16 = lane & 15, quad = lane >> 4;
    const int sw = (quad ^ (l16 & 3)) * 8;
    const int m0 = blockIdx.y * 64;
    const int b  = blockIdx.z;
    const int n0 = blockIdx.x * 64;

    f4_t acc[3][2][2];
    #pragma unroll
    for (int v = 0; v < 3; ++v)
        #pragma unroll
        for (int i = 0; i < 2; ++i)
            #pragma unroll
            for (int j = 0; j < 2; ++j)
                #pragma unroll
                for (int e = 0; e < 4; ++e) acc[v][i][j][e] = 0.f;

    for (int k0 = 0; k0 < C; k0 += 32) {
        // A: weights 64 x 32
        if (t < 256) {
            int row = t >> 2, ch = t & 3;
            size_t g = (size_t)(m0 + row) * lda + k0 + ch * 8;
            int ld = row * 32 + ((ch ^ (row & 3)) * 8);
            *(uint4*)(Ah + ld) = *(const uint4*)(Whi + g);
            *(uint4*)(Al + ld) = *(const uint4*)(Wlo + g);
        }
        // B: acts 3 x 64 x 32
        #pragma unroll
        for (int c = t; c < 768; c += 256) {
            int v = c >> 8, rem = c & 255;
            int row = rem >> 2, ch = rem & 3;
            size_t g = (size_t)((b * 3 + v) * N_ + n0 + row) * C + k0 + ch * 8;
            int ld = row * 32 + ((ch ^ (row & 3)) * 8);
            *(uint4*)(Bh[v] + ld) = *(const uint4*)(Ahi + g);
            *(uint4*)(Bl[v] + ld) = *(const uint4*)(Alo + g);
        }
        __syncthreads();
        bf8_t ah[2], al[2];
        #pragma unroll
        for (int i = 0; i < 2; ++i) {
            int ar = wm * 32 + i * 16 + l16;
            ah[i] = *(const bf8_t*)(Ah + ar * 32 + sw);
            al[i] = *(const bf8_t*)(Al + ar * 32 + sw);
        }
        #pragma unroll
        for (int v = 0; v < 3; ++v) {
            bf8_t bh[2], bl[2];
            #pragma unroll
            for (int j = 0; j < 2; ++j) {
                int br = wn * 32 + j * 16 + l16;
                bh[j] = *(const bf8_t*)(Bh[v] + br * 32 + sw);
                bl[j] = *(const bf8_t*)(Bl[v] + br * 32 + sw);
            }
            #pragma unroll
            for (int i = 0; i < 2; ++i)
                #pragma unroll
                for (int j = 0; j < 2; ++j) {
                    acc[v][i][j] = __builtin_amdgcn_mfma_f32_16x16x32_bf16(
                        ah[i], bh[j], acc[v][i][j], 0, 0, 0);
                    acc[v][i][j] = __builtin_amdgcn_mfma_f32_16x16x32_bf16(
                        ah[i], bl[j], acc[v][i][j], 0, 0, 0);
                    acc[v][i][j] = __builtin_amdgcn_mfma_f32_16x16x32_bf16(
                        al[i], bh[j], acc[v][i][j], 0, 0, 0);
                }
        }
        __syncthreads();
    }

    #pragma unroll
    for (int i = 0; i < 2; ++i) {
        int o = m0 + wm * 32 + i * 16 + quad * 4;
        float4 ra[3];
        if (HAS_ROWADD)
            #pragma unroll
            for (int v = 0; v < 3; ++v)
                ra[v] = *(const float4*)(rowAdd + (size_t)(b * 3 + v) * O + o);
        #pragma unroll
        for (int j = 0; j < 2; ++j) {
            int n = n0 + wn * 32 + j * 16 + l16;
            size_t row0 = (size_t)(b * 3) * N_ + n;     // v=0 row
            f4_t d[3];
            #pragma unroll
            for (int v = 0; v < 3; ++v) {
                d[v] = acc[v][i][j];
                if (HAS_ROWADD) {
                    d[v][0] += ra[v].x; d[v][1] += ra[v].y;
                    d[v][2] += ra[v].z; d[v][3] += ra[v].w;
                }
            }
            if (RELU_MODE == 0) {
                #pragma unroll
                for (int v = 0; v < 3; ++v)
                    st4s(outHi, outLo, (row0 + (size_t)v * N_) * O + o, d[v]);
            } else {
                f4_t p[3];
                if (RELU_MODE == 1) {
                    #pragma unroll
                    for (int v = 0; v < 3; ++v)
                        p[v] = ld4s(pHi, pLo, (row0 + (size_t)v * N_) * O + o);
                } else {
                    if (o < 128) {
                        #pragma unroll
                        for (int v = 0; v < 3; ++v)
                            p[v] = ld4s(pHi, pLo, (row0 + (size_t)v * N_) * 128 + o);
                    } else {
                        #pragma unroll
                        for (int e = 0; e < 4; ++e) {
                            const float* Pc = P + (size_t)(b * 128 + o - 128 + e) * 3;
                            p[0][e] = Pc[0]; p[1][e] = Pc[1]; p[2][e] = Pc[2];
                        }
                    }
                }
                f4_t q[3];
                #pragma unroll
                for (int e = 0; e < 4; ++e) {
                    float dot = p[0][e] * d[0][e] + p[1][e] * d[1][e] + p[2][e] * d[2][e];
                    float dsq = d[0][e] * d[0][e] + d[1][e] * d[1][e] + d[2][e] * d[2][e] + EPS_;
                    float cf = dot / dsq;
                    if (dot >= 0.f) { q[0][e] = p[0][e]; q[1][e] = p[1][e]; q[2][e] = p[2][e]; }
                    else {
                        q[0][e] = p[0][e] - cf * d[0][e];
                        q[1][e] = p[1][e] - cf * d[1][e];
                        q[2][e] = p[2][e] - cf * d[2][e];
                    }
                }
                #pragma unroll
                for (int v = 0; v < 3; ++v)
                    st4s(outHi, outLo, (row0 + (size_t)v * N_) * O + o, q[v]);
            }
        }
    }
}

// ---------------------------------------------------------------------------
// 3-v dual-segment GEMM (h = Ws*hidden + W1*a1 + rowAdd) with fused pool
// partials; optional h-plane writes (skipped at last block). O = 128.
// Pp layout: [((b*16 + ntile)*2 + wn) * 384 + o*3 + v]
// ---------------------------------------------------------------------------
template<bool HAS_ROWADD, bool WRITE_OUT>
__global__ __launch_bounds__(256) void gemm3v_dual(const ushort* __restrict__ W0h,
                                                   const ushort* __restrict__ W0l,
                                                   int lda0, int C0,
                                                   const ushort* __restrict__ A0h,
                                                   const ushort* __restrict__ A0l,
                                                   const ushort* __restrict__ W1h,
                                                   const ushort* __restrict__ W1l,
                                                   int lda1, int C1,
                                                   const ushort* __restrict__ A1h,
                                                   const ushort* __restrict__ A1l,
                                                   const float* __restrict__ rowAdd,
                                                   ushort* __restrict__ outHi,
                                                   ushort* __restrict__ outLo,
                                                   float* __restrict__ Pp) {
    constexpr int O = 128;
    __shared__ __align__(16) ushort Ah[64 * 32];
    __shared__ __align__(16) ushort Al[64 * 32];
    __shared__ __align__(16) ushort Bh[3][64 * 32];
    __shared__ __align__(16) ushort Bl[3][64 * 32];

    const int t = threadIdx.x;
    const int lane = t & 63, wave = t >> 6;
    const int wm = wave >> 1, wn = wave & 1;
    const int l16 = lane & 15, quad = lane >> 4;
    const int sw = (quad ^ (l16 & 3)) * 8;
    const int m0 = blockIdx.y * 64;
    const int b  = blockIdx.z;
    const int n0 = blockIdx.x * 64;

    f4_t acc[3][2][2];
    #pragma unroll
    for (int v = 0; v < 3; ++v)
        #pragma unroll
        for (int i = 0; i < 2; ++i)
            #pragma unroll
            for (int j = 0; j < 2; ++j)
                #pragma unroll
                for (int e = 0; e < 4; ++e) acc[v][i][j][e] = 0.f;

    const int Ct = C0 + C1;
    for (int k0 = 0; k0 < Ct; k0 += 32) {
        const bool seg = (k0 >= C0);
        const ushort* wh = seg ? W1h : W0h;
        const ushort* wl = seg ? W1l : W0l;
        const ushort* bhg = seg ? A1h : A0h;
        const ushort* blg = seg ? A1l : A0l;
        const int lda = seg ? lda1 : lda0;
        const int cs  = seg ? C1 : C0;
        const int kk  = seg ? (k0 - C0) : k0;
        if (t < 256) {
            int row = t >> 2, ch = t & 3;
            size_t g = (size_t)(m0 + row) * lda + kk + ch * 8;
            int ld = row * 32 + ((ch ^ (row & 3)) * 8);
            *(uint4*)(Ah + ld) = *(const uint4*)(wh + g);
            *(uint4*)(Al + ld) = *(const uint4*)(wl + g);
        }
        #pragma unroll
        for (int c = t; c < 768; c += 256) {
            int v = c >> 8, rem = c & 255;
            int row = rem >> 2, ch = rem & 3;
            size_t g = (size_t)((b * 3 + v) * N_ + n0 + row) * cs + kk + ch * 8;
            int ld = row * 32 + ((ch ^ (row & 3)) * 8);
            *(uint4*)(Bh[v] + ld) = *(const uint4*)(bhg + g);
            *(uint4*)(Bl[v] + ld) = *(const uint4*)(blg + g);
        }
        __syncthreads();
        bf8_t ah[2], al[2];
        #pragma unroll
        for (int i = 0; i < 2; ++i) {
            int ar = wm * 32 + i * 16 + l16;
            ah[i] = *(const bf8_t*)(Ah + ar * 32 + sw);
            al[i] = *(const bf8_t*)(Al + ar * 32 + sw);
        }
        #pragma unroll
        for (int v = 0; v < 3; ++v) {
            bf8_t bh[2], bl[2];
            #pragma unroll
            for (int j = 0; j < 2; ++j) {
                int br = wn * 32 + j * 16 + l16;
                bh[j] = *(const bf8_t*)(Bh[v] + br * 32 + sw);
                bl[j] = *(const bf8_t*)(Bl[v] + br * 32 + sw);
            }
            #pragma unroll
            for (int i = 0; i < 2; ++i)
                #pragma unroll
                for (int j = 0; j < 2; ++j) {
                    acc[v][i][j] = __builtin_amdgcn_mfma_f32_16x16x32_bf16(
                        ah[i], bh[j], acc[v][i][j], 0, 0, 0);
                    acc[v][i][j] = __builtin_amdgcn_mfma_f32_16x16x32_bf16(
                        ah[i], bl[j], acc[v][i][j], 0, 0, 0);
                    acc[v][i][j] = __builtin_amdgcn_mfma_f32_16x16x32_bf16(
                        al[i], bh[j], acc[v][i][j], 0, 0, 0);
                }
        }
        __syncthreads();
    }

    const size_t slot = ((size_t)b * 16 + blockIdx.x) * 2 + wn;
    #pragma unroll
    for (int i = 0; i < 2; ++i) {
        int o = m0 + wm * 32 + i * 16 + quad * 4;
        float4 ra[3];
        if (HAS_ROWADD)
            #pragma unroll
            for (int v = 0; v < 3; ++v)
                ra[v] = *(const float4*)(rowAdd + (size_t)(b * 3 + v) * O + o);
        f4_t psum[3];
        #pragma unroll
        for (int v = 0; v < 3; ++v)
            #pragma unroll
            for (int e = 0; e < 4; ++e) psum[v][e] = 0.f;

        #pragma unroll
        for (int j = 0; j < 2; ++j) {
            int n = n0 + wn * 32 + j * 16 + l16;
            size_t row0 = (size_t)(b * 3) * N_ + n;
            #pragma unroll
            for (int v = 0; v < 3; ++v) {
                f4_t d = acc[v][i][j];
                if (HAS_ROWADD) {
                    d[0] += ra[v].x; d[1] += ra[v].y; d[2] += ra[v].z; d[3] += ra[v].w;
                }
                #pragma unroll
                for (int e = 0; e < 4; ++e) psum[v][e] += d[e];
                if (WRITE_OUT)
                    st4s(outHi, outLo, (row0 + (size_t)v * N_) * O + o, d);
            }
        }
        // reduce over the 16-lane n-group (xor butterfly over bits 0..3)
        #pragma unroll
        for (int v = 0; v < 3; ++v)
            #pragma unroll
            for (int e = 0; e < 4; ++e) {
                float s = psum[v][e];
                s += __shfl_xor(s, 1);
                s += __shfl_xor(s, 2);
                s += __shfl_xor(s, 4);
                s += __shfl_xor(s, 8);
                psum[v][e] = s;
            }
        if (l16 == 0) {
            #pragma unroll
            for (int v = 0; v < 3; ++v)
                #pragma unroll
                for (int e = 0; e < 4; ++e)
                    Pp[slot * 384 + (size_t)(o + e) * 3 + v] = psum[v][e];
        }
    }
}

// ---------------------------------------------------------------------------
// Exact pooled-half injection (fp32 original weights + fp32 P).
// ---------------------------------------------------------------------------
__global__ __launch_bounds__(256) void rowadd_kernel(const float* __restrict__ Wd0i,
                                                     const float* __restrict__ Wsi,
                                                     const float* __restrict__ P,
                                                     float* __restrict__ addD0,
                                                     float* __restrict__ addWs) {
    int s = blockIdx.x;               // b*3 + v
    int b = s / 3, v = s % 3;
    __shared__ float Pl[128];
    int t = threadIdx.x;
    if (t < 128) Pl[t] = P[(size_t)(b * 128 + t) * 3 + v];
    __syncthreads();
    float sum = 0.f;
    const float* wr = Wd0i + (size_t)t * 256 + 128;
    #pragma unroll 8
    for (int c = 0; c < 128; ++c) sum += wr[c] * Pl[c];
    addD0[(size_t)s * 256 + t] = sum;
    if (t < 128) {
        const float* wr2 = Wsi + (size_t)t * 256 + 128;
        float s2 = 0.f;
        #pragma unroll 8
        for (int c = 0; c < 128; ++c) s2 += wr2[c] * Pl[c];
        addWs[(size_t)s * 128 + t] = s2;
    }
}

// ---------------------------------------------------------------------------
// Pool stage 2: reduce 32 partial slots -> P (B,128,3), scaled by 1/N.
// ---------------------------------------------------------------------------
__global__ __launch_bounds__(128) void pool2_kernel(const float* __restrict__ Pp,
                                                    float* __restrict__ P) {
    int b = blockIdx.x;
    int c = threadIdx.x;
    float s0 = 0.f, s1 = 0.f, s2 = 0.f;
    for (int sl = 0; sl < 32; ++sl) {
        const float* p = Pp + ((size_t)b * 32 + sl) * 384 + (size_t)c * 3;
        s0 += p[0]; s1 += p[1]; s2 += p[2];
    }
    float* o = P + (size_t)(b * 128 + c) * 3;
    const float inv = 1.0f / (float)N_;
    o[0] = s0 * inv; o[1] = s1 * inv; o[2] = s2 * inv;
}

// ---------------------------------------------------------------------------
// Final stage (fp32, exact)
// ---------------------------------------------------------------------------
__global__ __launch_bounds__(128) void final_kernel(const float* __restrict__ P,
                                                    const float* __restrict__ Wd,
                                                    const float* __restrict__ Wc,
                                                    float* __restrict__ out) {
    int b = blockIdx.x;
    int t = threadIdx.x;
    __shared__ float hid[H_][3];
    __shared__ float act[H_][3];
    const float* Pb = P + (size_t)b * H_ * 3;
    hid[t][0] = Pb[t * 3 + 0];
    hid[t][1] = Pb[t * 3 + 1];
    hid[t][2] = Pb[t * 3 + 2];
    __syncthreads();

    float d0 = 0.f, d1 = 0.f, d2 = 0.f;
    const float* wd = Wd + (size_t)t * H_;
    for (int c = 0; c < H_; ++c) {
        float w = wd[c];
        d0 += w * hid[c][0]; d1 += w * hid[c][1]; d2 += w * hid[c][2];
    }
    float p0 = hid[t][0], p1 = hid[t][1], p2 = hid[t][2];
    float dot = p0 * d0 + p1 * d1 + p2 * d2;
    float dsq = d0 * d0 + d1 * d1 + d2 * d2 + EPS_;
    float cf = dot / dsq;
    float q0, q1, q2;
    if (dot >= 0.f) { q0 = p0; q1 = p1; q2 = p2; }
    else            { q0 = p0 - cf * d0; q1 = p1 - cf * d1; q2 = p2 - cf * d2; }
    act[t][0] = 0.2f * p0 + 0.8f * q0;
    act[t][1] = 0.2f * p1 + 0.8f * q1;
    act[t][2] = 0.2f * p2 + 0.8f * q2;
    __syncthreads();

    float o0 = 0.f, o1 = 0.f, o2 = 0.f;
    const float* wc = Wc + (size_t)t * H_;
    for (int c = 0; c < H_; ++c) {
        float w = wc[c];
        o0 += w * act[c][0]; o1 += w * act[c][1]; o2 += w * act[c][2];
    }
    size_t ob = ((size_t)b * H_ + t) * 3;
    out[ob + 0] = o0; out[ob + 1] = o1; out[ob + 2] = o2;
}

// ---------------------------------------------------------------------------
extern "C" void kernel_launch(void* const* d_in, const int* in_sizes, int n_in,
                              void* d_out, int out_size, void* d_ws, size_t ws_size,
                              hipStream_t stream) {
    const float* x   = (const float*)d_in[0];
    const float* Wf  = (const float*)d_in[1];
    const float* Wdp = (const float*)d_in[2];
    const float* Wfc = (const float*)d_in[3];
    const float* Wd0 = (const float*)d_in[4];
    const float* W0  = (const float*)d_in[5];
    const float* Wd1 = (const float*)d_in[6];
    const float* W1  = (const float*)d_in[7];
    const float* Wsc = (const float*)d_in[8];
    const float* Wda = (const float*)d_in[9];
    const float* Wc  = (const float*)d_in[10];
    float* out = (float*)d_out;
    (void)in_sizes; (void)n_in; (void)out_size; (void)ws_size;

    char* ws = (char*)d_ws;
    size_t off = 0;
    auto alloc = [&](size_t bytes) {
        void* p = ws + off;
        off = (off + bytes + 255) & ~(size_t)255;
        return p;
    };
    const size_t e128 = (size_t)R_ * 128;
    const size_t e256 = (size_t)R_ * 256;
    int*    idx   = (int*)   alloc((size_t)B_ * N_ * K_ * sizeof(int));
    ushort* wAllH = (ushort*)alloc((size_t)W_TOT * 2);
    ushort* wAllL = (ushort*)alloc((size_t)W_TOT * 2);
    ushort* h1H   = (ushort*)alloc(e128 * 2);
    ushort* h1L   = (ushort*)alloc(e128 * 2);
    ushort* HdH   = (ushort*)alloc(e256 * 2);
    ushort* HdL   = (ushort*)alloc(e256 * 2);
    ushort* a0H   = (ushort*)alloc(e256 * 2);
    ushort* a0L   = (ushort*)alloc(e256 * 2);
    ushort* netH  = (ushort*)alloc(e128 * 2);
    ushort* netL  = (ushort*)alloc(e128 * 2);
    ushort* a1H   = (ushort*)alloc(e128 * 2);
    ushort* a1L   = (ushort*)alloc(e128 * 2);
    ushort* hH[2] = { (ushort*)alloc(e128 * 2), (ushort*)alloc(e128 * 2) };
    ushort* hL[2] = { (ushort*)alloc(e128 * 2), (ushort*)alloc(e128 * 2) };
    float*  addD0 = (float*) alloc(24 * 256 * 4);
    float*  addWs = (float*) alloc(24 * 128 * 4);
    float*  Pp    = (float*) alloc((size_t)B_ * 32 * 384 * 4);
    float*  P     = (float*) alloc((size_t)B_ * 128 * 3 * 4);

    const ushort* whFc = wAllH + OFF_FC; const ushort* wlFc = wAllL + OFF_FC;
    const ushort* whD0 = wAllH + OFF_D0; const ushort* wlD0 = wAllL + OFF_D0;
    const ushort* whW0 = wAllH + OFF_W0; const ushort* wlW0 = wAllL + OFF_W0;
    const ushort* whD1 = wAllH + OFF_D1; const ushort* wlD1 = wAllL + OFF_D1;
    const ushort* whW1 = wAllH + OFF_W1; const ushort* wlW1 = wAllL + OFF_W1;
    const ushort* whWs = wAllH + OFF_WS; const ushort* wlWs = wAllL + OFF_WS;

    hipLaunchKernelGGL(cvt_all, dim3((W_TOT + 255) / 256), dim3(256), 0, stream,
                       Wfc, Wd0, W0, Wd1, W1, Wsc, wAllH, wAllL);
    hipLaunchKernelGGL(knn_wave, dim3(B_ * N_ / 4), dim3(256), 0, stream, x, idx);
    hipLaunchKernelGGL(convpos_kernel, dim3(B_ * N_), dim3(128), 0, stream,
                       x, idx, Wf, Wdp, h1H, h1L);

    // fc_pos: Hd = Wfc (256x128) * h1
    gemm3v<0, false><<<dim3(16, 4, 8), 256, 0, stream>>>(
        whFc, wlFc, 128, h1H, h1L, 128,
        nullptr, nullptr, nullptr, nullptr, HdH, HdL, 256);

    for (int i = 0; i < 4; ++i) {
        int cur = i & 1, prv = cur ^ 1;
        if (i == 0) {
            // a0 = vnrelu(Hd, Wd0*Hd)
            gemm3v<1, false><<<dim3(16, 4, 8), 256, 0, stream>>>(
                whD0, wlD0, 256, HdH, HdL, 256,
                HdH, HdL, nullptr, nullptr, a0H, a0L, 256);
        } else {
            hipLaunchKernelGGL(rowadd_kernel, dim3(24), dim3(256), 0, stream,
                               Wd0 + (size_t)i * 65536, Wsc + (size_t)i * 32768,
                               P, addD0, addWs);
            // a0 = vnrelu([h|P], Wd0_left*h + rowAdd)
            gemm3v<2, true><<<dim3(16, 4, 8), 256, 0, stream>>>(
                whD0 + (size_t)i * 65536, wlD0 + (size_t)i * 65536, 256,
                hH[prv], hL[prv], 128,
                hH[prv], hL[prv], P, addD0, a0H, a0L, 256);
        }
        // net = W0 * a0
        gemm3v<0, false><<<dim3(16, 2, 8), 256, 0, stream>>>(
            whW0 + (size_t)i * 32768, wlW0 + (size_t)i * 32768, 256,
            a0H, a0L, 256, nullptr, nullptr, nullptr, nullptr, netH, netL, 128);
        // a1 = vnrelu(net, Wd1*net)
        gemm3v<1, false><<<dim3(16, 2, 8), 256, 0, stream>>>(
            whD1 + (size_t)i * 16384, wlD1 + (size_t)i * 16384, 128,
            netH, netL, 128, netH, netL, nullptr, nullptr, a1H, a1L, 128);
        // h = [Ws | W1] * [hidden ; a1] (+rowAdd) ; fused pool partials
        if (i == 0) {
            gemm3v_dual<false, true><<<dim3(16, 2, 8), 256, 0, stream>>>(
                whWs, wlWs, 256, 256, HdH, HdL,
                whW1, wlW1, 128, 128, a1H, a1L,
                nullptr, hH[cur], hL[cur], Pp);
        } else if (i < 3) {
            gemm3v_dual<true, true><<<dim3(16, 2, 8), 256, 0, stream>>>(
                whWs + (size_t)i * 32768, wlWs + (size_t)i * 32768, 256, 128,
                hH[prv], hL[prv],
                whW1 + (size_t)i * 16384, wlW1 + (size_t)i * 16384, 128, 128,
                a1H, a1L, addWs, hH[cur], hL[cur], Pp);
        } else {
            gemm3v_dual<true, false><<<dim3(16, 2, 8), 256, 0, stream>>>(
                whWs + (size_t)i * 32768, wlWs + (size_t)i * 32768, 256, 128,
                hH[prv], hL[prv],
                whW1 + (size_t)i * 16384, wlW1 + (size_t)i * 16384, 128, 128,
                a1H, a1L, addWs, nullptr, nullptr, Pp);
        }
        hipLaunchKernelGGL(pool2_kernel, dim3(B_), dim3(128), 0, stream, Pp, P);
    }

    hipLaunchKernelGGL(final_kernel, dim3(B_), dim3(128), 0, stream, P, Wda, Wc, out);
}

// Round 8
// 455.570 us; speedup vs baseline: 2.0602x; 1.1181x over previous
//
#include <hip/hip_runtime.h>
#include <cfloat>
#include <cstdint>

#define B_   8
#define N_   1024
#define H_   128
#define K_   20
#define EPS_ 1e-6f
#define R_   (B_ * 3 * N_)

typedef _Float16 half_t;
typedef _Float16 h8_t __attribute__((ext_vector_type(8)));
typedef _Float16 h4_t __attribute__((ext_vector_type(4)));
typedef __attribute__((ext_vector_type(4))) float f4_t;

__device__ inline f4_t ld4h(const half_t* __restrict__ p, size_t off) {
    h4_t x = *(const h4_t*)(p + off);
    f4_t r;
    r[0] = (float)x[0]; r[1] = (float)x[1]; r[2] = (float)x[2]; r[3] = (float)x[3];
    return r;
}
__device__ inline void st4h(half_t* __restrict__ p, size_t off, f4_t v) {
    h4_t o;
    o[0] = (half_t)v[0]; o[1] = (half_t)v[1]; o[2] = (half_t)v[2]; o[3] = (half_t)v[3];
    *(h4_t*)(p + off) = o;
}

// ---------------------------------------------------------------------------
// All-weights fp32 -> fp16 hi + fp16 lo split (lo captures residual).
// ---------------------------------------------------------------------------
#define OFF_FC 0
#define OFF_D0 32768
#define OFF_W0 294912
#define OFF_D1 425984
#define OFF_W1 491520
#define OFF_WS 557056
#define W_TOT  688128
__global__ __launch_bounds__(256) void cvt_all(const float* __restrict__ Wfc,
                                               const float* __restrict__ Wd0,
                                               const float* __restrict__ W0,
                                               const float* __restrict__ Wd1,
                                               const float* __restrict__ W1,
                                               const float* __restrict__ Wsc,
                                               half_t* __restrict__ hi,
                                               half_t* __restrict__ lo) {
    int i = blockIdx.x * 256 + threadIdx.x;
    if (i >= W_TOT) return;
    const float* src; int off;
    if (i < OFF_W0)      { if (i < OFF_D0) { src = Wfc; off = OFF_FC; }
                           else            { src = Wd0; off = OFF_D0; } }
    else if (i < OFF_W1) { if (i < OFF_D1) { src = W0;  off = OFF_W0; }
                           else            { src = Wd1; off = OFF_D1; } }
    else                 { if (i < OFF_WS) { src = W1;  off = OFF_W1; }
                           else            { src = Wsc; off = OFF_WS; } }
    float w = src[i - off];
    half_t h = (half_t)w;
    half_t l = (half_t)(w - (float)h);
    hi[i] = h; lo[i] = l;
}

// ---------------------------------------------------------------------------
// kNN: wave-per-query radix select (verified R6/R7).
// ---------------------------------------------------------------------------
__device__ inline uint wave_iscan(uint v, int lane) {
    #pragma unroll
    for (int o = 1; o < 64; o <<= 1) {
        uint pv = __shfl_up(v, o);
        if (lane >= o) v += pv;
    }
    return v;
}

__global__ __launch_bounds__(256) void knn_wave(const float* __restrict__ x,
                                                int* __restrict__ idx) {
    int wv = threadIdx.x >> 6, lane = threadIdx.x & 63;
    int bn = blockIdx.x * 4 + wv;
    int b = bn >> 10, n = bn & 1023;
    const float* xb = x + (size_t)b * N_ * 3;
    __shared__ uint hist[4][256];
    uint* h = hist[wv];

    float cx = xb[n * 3 + 0], cy = xb[n * 3 + 1], cz = xb[n * 3 + 2];
    uint ku[16];
    #pragma unroll
    for (int k = 0; k < 16; ++k) {
        int j = lane + (k << 6);
        float dx = xb[j * 3 + 0] - cx;
        float dy = xb[j * 3 + 1] - cy;
        float dz = xb[j * 3 + 2] - cz;
        ku[k] = __float_as_uint(dx * dx + dy * dy + dz * dz);
    }

    uint rem = K_, prefix = 0;
    for (int s = 24; s >= 0; s -= 8) {
        #pragma unroll
        for (int q = 0; q < 4; ++q) h[lane + (q << 6)] = 0;
        __syncthreads();
        #pragma unroll
        for (int k = 0; k < 16; ++k) {
            uint u = ku[k];
            if ((s == 24) || ((u >> (s + 8)) == prefix))
                atomicAdd(&h[(u >> s) & 255u], 1u);
        }
        __syncthreads();
        uint s4 = h[4 * lane] + h[4 * lane + 1] + h[4 * lane + 2] + h[4 * lane + 3];
        uint incl = wave_iscan(s4, lane);
        unsigned long long mask = __ballot(incl >= rem);
        int L = __ffsll(mask) - 1;
        uint inclL = __shfl(incl, L);
        uint sL = __shfl(s4, L);
        uint run = inclL - sL;
        uint sel_bin = 0, sel_before = 0;
        bool found = false;
        #pragma unroll
        for (int q = 0; q < 4; ++q) {
            uint hv = h[4 * L + q];
            if (!found && run + hv >= rem) { sel_bin = 4 * L + q; sel_before = run; found = true; }
            run += hv;
        }
        prefix = (prefix << 8) | sel_bin;
        rem -= sel_before;
        __syncthreads();
    }

    uint T = prefix;
    uint nlt = K_ - rem;
    int cl = 0, ce = 0;
    #pragma unroll
    for (int k = 0; k < 16; ++k) { cl += (ku[k] < T); ce += (ku[k] == T); }
    uint il = wave_iscan((uint)cl, lane);
    uint ie = wave_iscan((uint)ce, lane);
    uint pl_ = il - (uint)cl;
    uint pe  = nlt + ie - (uint)ce;
    int* op = idx + (size_t)bn * K_;
    #pragma unroll
    for (int k = 0; k < 16; ++k) {
        int j = lane + (k << 6);
        if (ku[k] < T) { op[pl_++] = j; }
        else if (ku[k] == T) { if (pe < K_) op[pe] = j; pe++; }
    }
}

// ---------------------------------------------------------------------------
// conv_pos fused -> h1 fp16 plane (B,3,N,128).
// ---------------------------------------------------------------------------
__global__ __launch_bounds__(128) void convpos_kernel(const float* __restrict__ x,
                                                      const int* __restrict__ idx,
                                                      const float* __restrict__ Wf,
                                                      const float* __restrict__ Wd,
                                                      half_t* __restrict__ h1) {
    int bn = blockIdx.x;
    int b = bn >> 10, n = bn & 1023;
    const float* xb = x + (size_t)b * N_ * 3;

    __shared__ float nb[K_][3];
    __shared__ float ctr[3];
    int t = threadIdx.x;
    if (t < K_) {
        int j = idx[(size_t)bn * K_ + t];
        nb[t][0] = xb[j * 3 + 0];
        nb[t][1] = xb[j * 3 + 1];
        nb[t][2] = xb[j * 3 + 2];
    }
    if (t == K_) {
        ctr[0] = xb[n * 3 + 0]; ctr[1] = xb[n * 3 + 1]; ctr[2] = xb[n * 3 + 2];
    }
    __syncthreads();

    float cx = ctr[0], cy = ctr[1], cz = ctr[2];
    float wf0 = Wf[t * 3 + 0], wf1 = Wf[t * 3 + 1], wf2 = Wf[t * 3 + 2];
    float wd0 = Wd[t * 3 + 0], wd1 = Wd[t * 3 + 1], wd2 = Wd[t * 3 + 2];

    float ax = 0.f, ay = 0.f, az = 0.f;
    #pragma unroll 4
    for (int kk = 0; kk < K_; ++kk) {
        float nx = nb[kk][0], ny = nb[kk][1], nz = nb[kk][2];
        float ex = nx - cx, ey = ny - cy, ez = nz - cz;
        float rx = ny * cz - nz * cy;
        float ry = nz * cx - nx * cz;
        float rz = nx * cy - ny * cx;
        float fx = wf0 * ex + wf1 * cx + wf2 * rx;
        float fy = wf0 * ey + wf1 * cy + wf2 * ry;
        float fz = wf0 * ez + wf1 * cz + wf2 * rz;
        float gx = wd0 * ex + wd1 * cx + wd2 * rx;
        float gy = wd0 * ey + wd1 * cy + wd2 * ry;
        float gz = wd0 * ez + wd1 * cz + wd2 * rz;
        float dot = fx * gx + fy * gy + fz * gz;
        float dsq = gx * gx + gy * gy + gz * gz + EPS_;
        float coef = dot / dsq;
        float qx, qy, qz;
        if (dot >= 0.f) { qx = fx; qy = fy; qz = fz; }
        else            { qx = fx - coef * gx; qy = fy - coef * gy; qz = fz - coef * gz; }
        ax += 0.2f * fx + 0.8f * qx;
        ay += 0.2f * fy + 0.8f * qy;
        az += 0.2f * fz + 0.8f * qz;
    }
    const float inv = 1.0f / (float)K_;
    size_t r0 = ((size_t)b * 3) * N_ + n;
    h1[(r0) * H_ + t]          = (half_t)(ax * inv);
    h1[(r0 + N_) * H_ + t]     = (half_t)(ay * inv);
    h1[(r0 + 2 * N_) * H_ + t] = (half_t)(az * inv);
}

// ---------------------------------------------------------------------------
// 3-v fused fp16 MFMA GEMM; weights as fp16 hi/lo (2 MFMAs), acts single
// fp16 plane. MT = m-tile (64 or 128). Block 256 thr, waves 2(m)x2(n),
// n-tile 64, all 3 v-slabs per block. XOR-swizzled LDS.
// RELU_MODE: 0=none, 1=VN-relu p from pA (stride O), 2=VN-relu p=[pA
// (o<128, stride 128) | P fp32 bcast].
// ---------------------------------------------------------------------------
template<int MT, int RELU_MODE, bool HAS_ROWADD>
__global__ __launch_bounds__(256) void gemm3v(const half_t* __restrict__ Whi,
                                              const half_t* __restrict__ Wlo,
                                              int lda,
                                              const half_t* __restrict__ A,
                                              int C,
                                              const half_t* __restrict__ pA,
                                              const float* __restrict__ P,
                                              const float* __restrict__ rowAdd,
                                              half_t* __restrict__ outA,
                                              int O) {
    constexpr int IF = MT / 32;                 // i-frags per wave
    __shared__ __align__(16) half_t Ah[MT * 32];
    __shared__ __align__(16) half_t Al[MT * 32];
    __shared__ __align__(16) half_t Bs[3][64 * 32];

    const int t = threadIdx.x;
    const int lane = t & 63, wave = t >> 6;
    const int wm = wave >> 1, wn = wave & 1;
    const int l16 = lane & 15, quad = lane >> 4;
    const int sw = (quad ^ (l16 & 3)) * 8;
    const int m0 = blockIdx.y * MT;
    const int b  = blockIdx.z;
    const int n0 = blockIdx.x * 64;

    f4_t acc[3][IF][2];
    #pragma unroll
    for (int v = 0; v < 3; ++v)
        #pragma unroll
        for (int i = 0; i < IF; ++i)
            #pragma unroll
            for (int j = 0; j < 2; ++j)
                #pragma unroll
                for (int e = 0; e < 4; ++e) acc[v][i][j][e] = 0.f;

    for (int k0 = 0; k0 < C; k0 += 32) {
        #pragma unroll
        for (int c = t; c < MT * 4; c += 256) {
            int row = c >> 2, ch = c & 3;
            size_t g = (size_t)(m0 + row) * lda + k0 + ch * 8;
            int ld = row * 32 + ((ch ^ (row & 3)) * 8);
            *(uint4*)(Ah + ld) = *(const uint4*)(Whi + g);
            *(uint4*)(Al + ld) = *(const uint4*)(Wlo + g);
        }
        #pragma unroll
        for (int c = t; c < 768; c += 256) {
            int v = c >> 8, rem = c & 255;
            int row = rem >> 2, ch = rem & 3;
            size_t g = (size_t)((b * 3 + v) * N_ + n0 + row) * C + k0 + ch * 8;
            int ld = row * 32 + ((ch ^ (row & 3)) * 8);
            *(uint4*)(Bs[v] + ld) = *(const uint4*)(A + g);
        }
        __syncthreads();
        h8_t ah[IF], al[IF];
        #pragma unroll
        for (int i = 0; i < IF; ++i) {
            int ar = wm * (MT / 2) + i * 16 + l16;
            ah[i] = *(const h8_t*)(Ah + ar * 32 + sw);
            al[i] = *(const h8_t*)(Al + ar * 32 + sw);
        }
        #pragma unroll
        for (int v = 0; v < 3; ++v) {
            h8_t bh[2];
            #pragma unroll
            for (int j = 0; j < 2; ++j) {
                int br = wn * 32 + j * 16 + l16;
                bh[j] = *(const h8_t*)(Bs[v] + br * 32 + sw);
            }
            #pragma unroll
            for (int i = 0; i < IF; ++i)
                #pragma unroll
                for (int j = 0; j < 2; ++j) {
                    acc[v][i][j] = __builtin_amdgcn_mfma_f32_16x16x32_f16(
                        ah[i], bh[j], acc[v][i][j], 0, 0, 0);
                    acc[v][i][j] = __builtin_amdgcn_mfma_f32_16x16x32_f16(
                        al[i], bh[j], acc[v][i][j], 0, 0, 0);
                }
        }
        __syncthreads();
    }

    #pragma unroll
    for (int i = 0; i < IF; ++i) {
        int o = m0 + wm * (MT / 2) + i * 16 + quad * 4;
        float4 ra[3];
        if (HAS_ROWADD)
            #pragma unroll
            for (int v = 0; v < 3; ++v)
                ra[v] = *(const float4*)(rowAdd + (size_t)(b * 3 + v) * O + o);
        #pragma unroll
        for (int j = 0; j < 2; ++j) {
            int n = n0 + wn * 32 + j * 16 + l16;
            size_t row0 = (size_t)(b * 3) * N_ + n;
            f4_t d[3];
            #pragma unroll
            for (int v = 0; v < 3; ++v) {
                d[v] = acc[v][i][j];
                if (HAS_ROWADD) {
                    d[v][0] += ra[v].x; d[v][1] += ra[v].y;
                    d[v][2] += ra[v].z; d[v][3] += ra[v].w;
                }
            }
            if (RELU_MODE == 0) {
                #pragma unroll
                for (int v = 0; v < 3; ++v)
                    st4h(outA, (row0 + (size_t)v * N_) * O + o, d[v]);
            } else {
                f4_t p[3];
                if (RELU_MODE == 1) {
                    #pragma unroll
                    for (int v = 0; v < 3; ++v)
                        p[v] = ld4h(pA, (row0 + (size_t)v * N_) * O + o);
                } else {
                    if (o < 128) {
                        #pragma unroll
                        for (int v = 0; v < 3; ++v)
                            p[v] = ld4h(pA, (row0 + (size_t)v * N_) * 128 + o);
                    } else {
                        #pragma unroll
                        for (int e = 0; e < 4; ++e) {
                            const float* Pc = P + (size_t)(b * 128 + o - 128 + e) * 3;
                            p[0][e] = Pc[0]; p[1][e] = Pc[1]; p[2][e] = Pc[2];
                        }
                    }
                }
                f4_t q[3];
                #pragma unroll
                for (int e = 0; e < 4; ++e) {
                    float dot = p[0][e] * d[0][e] + p[1][e] * d[1][e] + p[2][e] * d[2][e];
                    float dsq = d[0][e] * d[0][e] + d[1][e] * d[1][e] + d[2][e] * d[2][e] + EPS_;
                    float cf = dot / dsq;
                    if (dot >= 0.f) { q[0][e] = p[0][e]; q[1][e] = p[1][e]; q[2][e] = p[2][e]; }
                    else {
                        q[0][e] = p[0][e] - cf * d[0][e];
                        q[1][e] = p[1][e] - cf * d[1][e];
                        q[2][e] = p[2][e] - cf * d[2][e];
                    }
                }
                #pragma unroll
                for (int v = 0; v < 3; ++v)
                    st4h(outA, (row0 + (size_t)v * N_) * O + o, q[v]);
            }
        }
    }
}

// ---------------------------------------------------------------------------
// 3-v dual-segment GEMM (h = Ws*hidden + W1*a1 + rowAdd), fp16 acts, fused
// pool partials; optional h writes. O=128, tile 64x64.
// Pp layout: [((b*16 + ntile)*2 + wn) * 384 + o*3 + v]
// ---------------------------------------------------------------------------
template<bool HAS_ROWADD, bool WRITE_OUT>
__global__ __launch_bounds__(256) void gemm3v_dual(const half_t* __restrict__ W0h,
                                                   const half_t* __restrict__ W0l,
                                                   int lda0, int C0,
                                                   const half_t* __restrict__ A0,
                                                   const half_t* __restrict__ W1h,
                                                   const half_t* __restrict__ W1l,
                                                   int lda1, int C1,
                                                   const half_t* __restrict__ A1,
                                                   const float* __restrict__ rowAdd,
                                                   half_t* __restrict__ outA,
                                                   float* __restrict__ Pp) {
    constexpr int O = 128;
    __shared__ __align__(16) half_t Ah[64 * 32];
    __shared__ __align__(16) half_t Al[64 * 32];
    __shared__ __align__(16) half_t Bs[3][64 * 32];

    const int t = threadIdx.x;
    const int lane = t & 63, wave = t >> 6;
    const int wm = wave >> 1, wn = wave & 1;
    const int l16 = lane & 15, quad = lane >> 4;
    const int sw = (quad ^ (l16 & 3)) * 8;
    const int m0 = blockIdx.y * 64;
    const int b  = blockIdx.z;
    const int n0 = blockIdx.x * 64;

    f4_t acc[3][2][2];
    #pragma unroll
    for (int v = 0; v < 3; ++v)
        #pragma unroll
        for (int i = 0; i < 2; ++i)
            #pragma unroll
            for (int j = 0; j < 2; ++j)
                #pragma unroll
                for (int e = 0; e < 4; ++e) acc[v][i][j][e] = 0.f;

    const int Ct = C0 + C1;
    for (int k0 = 0; k0 < Ct; k0 += 32) {
        const bool seg = (k0 >= C0);
        const half_t* wh = seg ? W1h : W0h;
        const half_t* wl = seg ? W1l : W0l;
        const half_t* ag = seg ? A1 : A0;
        const int lda = seg ? lda1 : lda0;
        const int cs  = seg ? C1 : C0;
        const int kk  = seg ? (k0 - C0) : k0;
        if (t < 256) {
            int row = t >> 2, ch = t & 3;
            size_t g = (size_t)(m0 + row) * lda + kk + ch * 8;
            int ld = row * 32 + ((ch ^ (row & 3)) * 8);
            *(uint4*)(Ah + ld) = *(const uint4*)(wh + g);
            *(uint4*)(Al + ld) = *(const uint4*)(wl + g);
        }
        #pragma unroll
        for (int c = t; c < 768; c += 256) {
            int v = c >> 8, rem = c & 255;
            int row = rem >> 2, ch = rem & 3;
            size_t g = (size_t)((b * 3 + v) * N_ + n0 + row) * cs + kk + ch * 8;
            int ld = row * 32 + ((ch ^ (row & 3)) * 8);
            *(uint4*)(Bs[v] + ld) = *(const uint4*)(ag + g);
        }
        __syncthreads();
        h8_t ah[2], al[2];
        #pragma unroll
        for (int i = 0; i < 2; ++i) {
            int ar = wm * 32 + i * 16 + l16;
            ah[i] = *(const h8_t*)(Ah + ar * 32 + sw);
            al[i] = *(const h8_t*)(Al + ar * 32 + sw);
        }
        #pragma unroll
        for (int v = 0; v < 3; ++v) {
            h8_t bh[2];
            #pragma unroll
            for (int j = 0; j < 2; ++j) {
                int br = wn * 32 + j * 16 + l16;
                bh[j] = *(const h8_t*)(Bs[v] + br * 32 + sw);
            }
            #pragma unroll
            for (int i = 0; i < 2; ++i)
                #pragma unroll
                for (int j = 0; j < 2; ++j) {
                    acc[v][i][j] = __builtin_amdgcn_mfma_f32_16x16x32_f16(
                        ah[i], bh[j], acc[v][i][j], 0, 0, 0);
                    acc[v][i][j] = __builtin_amdgcn_mfma_f32_16x16x32_f16(
                        al[i], bh[j], acc[v][i][j], 0, 0, 0);
                }
        }
        __syncthreads();
    }

    const size_t slot = ((size_t)b * 16 + blockIdx.x) * 2 + wn;
    #pragma unroll
    for (int i = 0; i < 2; ++i) {
        int o = m0 + wm * 32 + i * 16 + quad * 4;
        float4 ra[3];
        if (HAS_ROWADD)
            #pragma unroll
            for (int v = 0; v < 3; ++v)
                ra[v] = *(const float4*)(rowAdd + (size_t)(b * 3 + v) * O + o);
        f4_t psum[3];
        #pragma unroll
        for (int v = 0; v < 3; ++v)
            #pragma unroll
            for (int e = 0; e < 4; ++e) psum[v][e] = 0.f;

        #pragma unroll
        for (int j = 0; j < 2; ++j) {
            int n = n0 + wn * 32 + j * 16 + l16;
            size_t row0 = (size_t)(b * 3) * N_ + n;
            #pragma unroll
            for (int v = 0; v < 3; ++v) {
                f4_t d = acc[v][i][j];
                if (HAS_ROWADD) {
                    d[0] += ra[v].x; d[1] += ra[v].y; d[2] += ra[v].z; d[3] += ra[v].w;
                }
                #pragma unroll
                for (int e = 0; e < 4; ++e) psum[v][e] += d[e];
                if (WRITE_OUT)
                    st4h(outA, (row0 + (size_t)v * N_) * O + o, d);
            }
        }
        #pragma unroll
        for (int v = 0; v < 3; ++v)
            #pragma unroll
            for (int e = 0; e < 4; ++e) {
                float s = psum[v][e];
                s += __shfl_xor(s, 1);
                s += __shfl_xor(s, 2);
                s += __shfl_xor(s, 4);
                s += __shfl_xor(s, 8);
                psum[v][e] = s;
            }
        if (l16 == 0) {
            #pragma unroll
            for (int v = 0; v < 3; ++v)
                #pragma unroll
                for (int e = 0; e < 4; ++e)
                    Pp[slot * 384 + (size_t)(o + e) * 3 + v] = psum[v][e];
        }
    }
}

// ---------------------------------------------------------------------------
// Exact pooled-half injection (fp32 original weights + fp32 P).
// ---------------------------------------------------------------------------
__global__ __launch_bounds__(256) void rowadd_kernel(const float* __restrict__ Wd0i,
                                                     const float* __restrict__ Wsi,
                                                     const float* __restrict__ P,
                                                     float* __restrict__ addD0,
                                                     float* __restrict__ addWs) {
    int s = blockIdx.x;               // b*3 + v
    int b = s / 3, v = s % 3;
    __shared__ float Pl[128];
    int t = threadIdx.x;
    if (t < 128) Pl[t] = P[(size_t)(b * 128 + t) * 3 + v];
    __syncthreads();
    float sum = 0.f;
    const float* wr = Wd0i + (size_t)t * 256 + 128;
    #pragma unroll 8
    for (int c = 0; c < 128; ++c) sum += wr[c] * Pl[c];
    addD0[(size_t)s * 256 + t] = sum;
    if (t < 128) {
        const float* wr2 = Wsi + (size_t)t * 256 + 128;
        float s2 = 0.f;
        #pragma unroll 8
        for (int c = 0; c < 128; ++c) s2 += wr2[c] * Pl[c];
        addWs[(size_t)s * 128 + t] = s2;
    }
}

// ---------------------------------------------------------------------------
// Pool stage 2: reduce 32 partial slots -> P (B,128,3), scaled by 1/N.
// ---------------------------------------------------------------------------
__global__ __launch_bounds__(128) void pool2_kernel(const float* __restrict__ Pp,
                                                    float* __restrict__ P) {
    int b = blockIdx.x;
    int c = threadIdx.x;
    float s0 = 0.f, s1 = 0.f, s2 = 0.f;
    for (int sl = 0; sl < 32; ++sl) {
        const float* p = Pp + ((size_t)b * 32 + sl) * 384 + (size_t)c * 3;
        s0 += p[0]; s1 += p[1]; s2 += p[2];
    }
    float* o = P + (size_t)(b * 128 + c) * 3;
    const float inv = 1.0f / (float)N_;
    o[0] = s0 * inv; o[1] = s1 * inv; o[2] = s2 * inv;
}

// ---------------------------------------------------------------------------
// Final stage (fp32, exact)
// ---------------------------------------------------------------------------
__global__ __launch_bounds__(128) void final_kernel(const float* __restrict__ P,
                                                    const float* __restrict__ Wd,
                                                    const float* __restrict__ Wc,
                                                    float* __restrict__ out) {
    int b = blockIdx.x;
    int t = threadIdx.x;
    __shared__ float hid[H_][3];
    __shared__ float act[H_][3];
    const float* Pb = P + (size_t)b * H_ * 3;
    hid[t][0] = Pb[t * 3 + 0];
    hid[t][1] = Pb[t * 3 + 1];
    hid[t][2] = Pb[t * 3 + 2];
    __syncthreads();

    float d0 = 0.f, d1 = 0.f, d2 = 0.f;
    const float* wd = Wd + (size_t)t * H_;
    for (int c = 0; c < H_; ++c) {
        float w = wd[c];
        d0 += w * hid[c][0]; d1 += w * hid[c][1]; d2 += w * hid[c][2];
    }
    float p0 = hid[t][0], p1 = hid[t][1], p2 = hid[t][2];
    float dot = p0 * d0 + p1 * d1 + p2 * d2;
    float dsq = d0 * d0 + d1 * d1 + d2 * d2 + EPS_;
    float cf = dot / dsq;
    float q0, q1, q2;
    if (dot >= 0.f) { q0 = p0; q1 = p1; q2 = p2; }
    else            { q0 = p0 - cf * d0; q1 = p1 - cf * d1; q2 = p2 - cf * d2; }
    act[t][0] = 0.2f * p0 + 0.8f * q0;
    act[t][1] = 0.2f * p1 + 0.8f * q1;
    act[t][2] = 0.2f * p2 + 0.8f * q2;
    __syncthreads();

    float o0 = 0.f, o1 = 0.f, o2 = 0.f;
    const float* wc = Wc + (size_t)t * H_;
    for (int c = 0; c < H_; ++c) {
        float w = wc[c];
        o0 += w * act[c][0]; o1 += w * act[c][1]; o2 += w * act[c][2];
    }
    size_t ob = ((size_t)b * H_ + t) * 3;
    out[ob + 0] = o0; out[ob + 1] = o1; out[ob + 2] = o2;
}

// ---------------------------------------------------------------------------
extern "C" void kernel_launch(void* const* d_in, const int* in_sizes, int n_in,
                              void* d_out, int out_size, void* d_ws, size_t ws_size,
                              hipStream_t stream) {
    const float* x   = (const float*)d_in[0];
    const float* Wf  = (const float*)d_in[1];
    const float* Wdp = (const float*)d_in[2];
    const float* Wfc = (const float*)d_in[3];
    const float* Wd0 = (const float*)d_in[4];
    const float* W0  = (const float*)d_in[5];
    const float* Wd1 = (const float*)d_in[6];
    const float* W1  = (const float*)d_in[7];
    const float* Wsc = (const float*)d_in[8];
    const float* Wda = (const float*)d_in[9];
    const float* Wc  = (const float*)d_in[10];
    float* out = (float*)d_out;
    (void)in_sizes; (void)n_in; (void)out_size; (void)ws_size;

    char* ws = (char*)d_ws;
    size_t off = 0;
    auto alloc = [&](size_t bytes) {
        void* p = ws + off;
        off = (off + bytes + 255) & ~(size_t)255;
        return p;
    };
    const size_t e128 = (size_t)R_ * 128;
    const size_t e256 = (size_t)R_ * 256;
    int*    idx   = (int*)   alloc((size_t)B_ * N_ * K_ * sizeof(int));
    half_t* wAllH = (half_t*)alloc((size_t)W_TOT * 2);
    half_t* wAllL = (half_t*)alloc((size_t)W_TOT * 2);
    half_t* h1F   = (half_t*)alloc(e128 * 2);
    half_t* HdF   = (half_t*)alloc(e256 * 2);
    half_t* a0F   = (half_t*)alloc(e256 * 2);
    half_t* netF  = (half_t*)alloc(e128 * 2);
    half_t* a1F   = (half_t*)alloc(e128 * 2);
    half_t* hF[2] = { (half_t*)alloc(e128 * 2), (half_t*)alloc(e128 * 2) };
    float*  addD0 = (float*) alloc(24 * 256 * 4);
    float*  addWs = (float*) alloc(24 * 128 * 4);
    float*  Pp    = (float*) alloc((size_t)B_ * 32 * 384 * 4);
    float*  P     = (float*) alloc((size_t)B_ * 128 * 3 * 4);

    const half_t* whFc = wAllH + OFF_FC; const half_t* wlFc = wAllL + OFF_FC;
    const half_t* whD0 = wAllH + OFF_D0; const half_t* wlD0 = wAllL + OFF_D0;
    const half_t* whW0 = wAllH + OFF_W0; const half_t* wlW0 = wAllL + OFF_W0;
    const half_t* whD1 = wAllH + OFF_D1; const half_t* wlD1 = wAllL + OFF_D1;
    const half_t* whW1 = wAllH + OFF_W1; const half_t* wlW1 = wAllL + OFF_W1;
    const half_t* whWs = wAllH + OFF_WS; const half_t* wlWs = wAllL + OFF_WS;

    hipLaunchKernelGGL(cvt_all, dim3((W_TOT + 255) / 256), dim3(256), 0, stream,
                       Wfc, Wd0, W0, Wd1, W1, Wsc, wAllH, wAllL);
    hipLaunchKernelGGL(knn_wave, dim3(B_ * N_ / 4), dim3(256), 0, stream, x, idx);
    hipLaunchKernelGGL(convpos_kernel, dim3(B_ * N_), dim3(128), 0, stream,
                       x, idx, Wf, Wdp, h1F);

    // fc_pos: Hd = Wfc (256x128) * h1   [m-tile 128]
    gemm3v<128, 0, false><<<dim3(16, 2, 8), 256, 0, stream>>>(
        whFc, wlFc, 128, h1F, 128, nullptr, nullptr, nullptr, HdF, 256);

    for (int i = 0; i < 4; ++i) {
        int cur = i & 1, prv = cur ^ 1;
        if (i == 0) {
            // a0 = vnrelu(Hd, Wd0*Hd)   [m-tile 128]
            gemm3v<128, 1, false><<<dim3(16, 2, 8), 256, 0, stream>>>(
                whD0, wlD0, 256, HdF, 256, HdF, nullptr, nullptr, a0F, 256);
        } else {
            hipLaunchKernelGGL(rowadd_kernel, dim3(24), dim3(256), 0, stream,
                               Wd0 + (size_t)i * 65536, Wsc + (size_t)i * 32768,
                               P, addD0, addWs);
            // a0 = vnrelu([h|P], Wd0_left*h + rowAdd)   [m-tile 128]
            gemm3v<128, 2, true><<<dim3(16, 2, 8), 256, 0, stream>>>(
                whD0 + (size_t)i * 65536, wlD0 + (size_t)i * 65536, 256,
                hF[prv], 128, hF[prv], P, addD0, a0F, 256);
        }
        // net = W0 * a0
        gemm3v<64, 0, false><<<dim3(16, 2, 8), 256, 0, stream>>>(
            whW0 + (size_t)i * 32768, wlW0 + (size_t)i * 32768, 256,
            a0F, 256, nullptr, nullptr, nullptr, netF, 128);
        // a1 = vnrelu(net, Wd1*net)
        gemm3v<64, 1, false><<<dim3(16, 2, 8), 256, 0, stream>>>(
            whD1 + (size_t)i * 16384, wlD1 + (size_t)i * 16384, 128,
            netF, 128, netF, nullptr, nullptr, a1F, 128);
        // h = [Ws | W1] * [hidden ; a1] (+rowAdd) ; fused pool partials
        if (i == 0) {
            gemm3v_dual<false, true><<<dim3(16, 2, 8), 256, 0, stream>>>(
                whWs, wlWs, 256, 256, HdF,
                whW1, wlW1, 128, 128, a1F,
                nullptr, hF[cur], Pp);
        } else if (i < 3) {
            gemm3v_dual<true, true><<<dim3(16, 2, 8), 256, 0, stream>>>(
                whWs + (size_t)i * 32768, wlWs + (size_t)i * 32768, 256, 128, hF[prv],
                whW1 + (size_t)i * 16384, wlW1 + (size_t)i * 16384, 128, 128, a1F,
                addWs, hF[cur], Pp);
        } else {
            gemm3v_dual<true, false><<<dim3(16, 2, 8), 256, 0, stream>>>(
                whWs + (size_t)i * 32768, wlWs + (size_t)i * 32768, 256, 128, hF[prv],
                whW1 + (size_t)i * 16384, wlW1 + (size_t)i * 16384, 128, 128, a1F,
                addWs, nullptr, Pp);
        }
        hipLaunchKernelGGL(pool2_kernel, dim3(B_), dim3(128), 0, stream, Pp, P);
    }

    hipLaunchKernelGGL(final_kernel, dim3(B_), dim3(128), 0, stream, P, Wda, Wc, out);
}

// Round 9
// 420.522 us; speedup vs baseline: 2.2319x; 1.0833x over previous
//
#include <hip/hip_runtime.h>
#include <cfloat>
#include <cstdint>

#define B_   8
#define N_   1024
#define H_   128
#define K_   20
#define EPS_ 1e-6f
#define R_   (B_ * 3 * N_)

typedef _Float16 half_t;
typedef _Float16 h8_t __attribute__((ext_vector_type(8)));
typedef _Float16 h4_t __attribute__((ext_vector_type(4)));
typedef __attribute__((ext_vector_type(4))) float f4_t;

__device__ inline f4_t ld4h(const half_t* __restrict__ p, size_t off) {
    h4_t x = *(const h4_t*)(p + off);
    f4_t r;
    r[0] = (float)x[0]; r[1] = (float)x[1]; r[2] = (float)x[2]; r[3] = (float)x[3];
    return r;
}
__device__ inline void st4h(half_t* __restrict__ p, size_t off, f4_t v) {
    h4_t o;
    o[0] = (half_t)v[0]; o[1] = (half_t)v[1]; o[2] = (half_t)v[2]; o[3] = (half_t)v[3];
    *(h4_t*)(p + off) = o;
}

// ---------------------------------------------------------------------------
// All-weights fp32 -> fp16 hi + fp16 lo split.
// ---------------------------------------------------------------------------
#define OFF_FC 0
#define OFF_D0 32768
#define OFF_W0 294912
#define OFF_D1 425984
#define OFF_W1 491520
#define OFF_WS 557056
#define W_TOT  688128
__global__ __launch_bounds__(256) void cvt_all(const float* __restrict__ Wfc,
                                               const float* __restrict__ Wd0,
                                               const float* __restrict__ W0,
                                               const float* __restrict__ Wd1,
                                               const float* __restrict__ W1,
                                               const float* __restrict__ Wsc,
                                               half_t* __restrict__ hi,
                                               half_t* __restrict__ lo) {
    int i = blockIdx.x * 256 + threadIdx.x;
    if (i >= W_TOT) return;
    const float* src; int off;
    if (i < OFF_W0)      { if (i < OFF_D0) { src = Wfc; off = OFF_FC; }
                           else            { src = Wd0; off = OFF_D0; } }
    else if (i < OFF_W1) { if (i < OFF_D1) { src = W0;  off = OFF_W0; }
                           else            { src = Wd1; off = OFF_D1; } }
    else                 { if (i < OFF_WS) { src = W1;  off = OFF_W1; }
                           else            { src = Wsc; off = OFF_WS; } }
    float w = src[i - off];
    half_t h = (half_t)w;
    half_t l = (half_t)(w - (float)h);
    hi[i] = h; lo[i] = l;
}

// ---------------------------------------------------------------------------
// kNN: LDS point cloud (SoA) + per-wave exact 20-round min-selection.
// Block = 4 queries (one per wave). No histograms / atomics / select barriers.
// ---------------------------------------------------------------------------
__global__ __launch_bounds__(256) void knn_wave(const float* __restrict__ x,
                                                int* __restrict__ idx) {
    __shared__ float xs[N_], ys[N_], zs[N_];
    int t = threadIdx.x;
    int wv = t >> 6, lane = t & 63;
    int b = blockIdx.x >> 8;               // 256 blocks per batch
    int n = (blockIdx.x & 255) * 4 + wv;   // this wave's query
    const float* xb = x + (size_t)b * N_ * 3;
    for (int j = t; j < N_; j += 256) {
        xs[j] = xb[j * 3 + 0];
        ys[j] = xb[j * 3 + 1];
        zs[j] = xb[j * 3 + 2];
    }
    __syncthreads();

    float cx = xs[n], cy = ys[n], cz = zs[n];
    float du[16];
    #pragma unroll
    for (int k = 0; k < 16; ++k) {
        int j = lane + (k << 6);
        float dx = xs[j] - cx, dy = ys[j] - cy, dz = zs[j] - cz;
        du[k] = dx * dx + dy * dy + dz * dz;
    }

    int* op = idx + (size_t)(b * N_ + n) * K_;
    for (int s = 0; s < K_; ++s) {
        float m = du[0];
        #pragma unroll
        for (int k = 1; k < 16; ++k) m = fminf(m, du[k]);
        #pragma unroll
        for (int o = 32; o; o >>= 1) m = fminf(m, __shfl_xor(m, o));
        bool has = false;
        #pragma unroll
        for (int k = 0; k < 16; ++k) has |= (du[k] == m);
        unsigned long long msk = __ballot(has);
        int first = __ffsll(msk) - 1;
        if (lane == first) {
            bool done = false;
            #pragma unroll
            for (int k = 0; k < 16; ++k) {
                if (!done && du[k] == m) {
                    op[s] = lane + (k << 6);
                    du[k] = FLT_MAX;
                    done = true;
                }
            }
        }
    }
}

// ---------------------------------------------------------------------------
// conv_pos fused -> h1 fp16 plane (B,3,N,128).
// ---------------------------------------------------------------------------
__global__ __launch_bounds__(128) void convpos_kernel(const float* __restrict__ x,
                                                      const int* __restrict__ idx,
                                                      const float* __restrict__ Wf,
                                                      const float* __restrict__ Wd,
                                                      half_t* __restrict__ h1) {
    int bn = blockIdx.x;
    int b = bn >> 10, n = bn & 1023;
    const float* xb = x + (size_t)b * N_ * 3;

    __shared__ float nb[K_][3];
    __shared__ float ctr[3];
    int t = threadIdx.x;
    if (t < K_) {
        int j = idx[(size_t)bn * K_ + t];
        nb[t][0] = xb[j * 3 + 0];
        nb[t][1] = xb[j * 3 + 1];
        nb[t][2] = xb[j * 3 + 2];
    }
    if (t == K_) {
        ctr[0] = xb[n * 3 + 0]; ctr[1] = xb[n * 3 + 1]; ctr[2] = xb[n * 3 + 2];
    }
    __syncthreads();

    float cx = ctr[0], cy = ctr[1], cz = ctr[2];
    float wf0 = Wf[t * 3 + 0], wf1 = Wf[t * 3 + 1], wf2 = Wf[t * 3 + 2];
    float wd0 = Wd[t * 3 + 0], wd1 = Wd[t * 3 + 1], wd2 = Wd[t * 3 + 2];

    float ax = 0.f, ay = 0.f, az = 0.f;
    #pragma unroll 4
    for (int kk = 0; kk < K_; ++kk) {
        float nx = nb[kk][0], ny = nb[kk][1], nz = nb[kk][2];
        float ex = nx - cx, ey = ny - cy, ez = nz - cz;
        float rx = ny * cz - nz * cy;
        float ry = nz * cx - nx * cz;
        float rz = nx * cy - ny * cx;
        float fx = wf0 * ex + wf1 * cx + wf2 * rx;
        float fy = wf0 * ey + wf1 * cy + wf2 * ry;
        float fz = wf0 * ez + wf1 * cz + wf2 * rz;
        float gx = wd0 * ex + wd1 * cx + wd2 * rx;
        float gy = wd0 * ey + wd1 * cy + wd2 * ry;
        float gz = wd0 * ez + wd1 * cz + wd2 * rz;
        float dot = fx * gx + fy * gy + fz * gz;
        float dsq = gx * gx + gy * gy + gz * gz + EPS_;
        float coef = dot / dsq;
        float qx, qy, qz;
        if (dot >= 0.f) { qx = fx; qy = fy; qz = fz; }
        else            { qx = fx - coef * gx; qy = fy - coef * gy; qz = fz - coef * gz; }
        ax += 0.2f * fx + 0.8f * qx;
        ay += 0.2f * fy + 0.8f * qy;
        az += 0.2f * fz + 0.8f * qz;
    }
    const float inv = 1.0f / (float)K_;
    size_t r0 = ((size_t)b * 3) * N_ + n;
    h1[(r0) * H_ + t]          = (half_t)(ax * inv);
    h1[(r0 + N_) * H_ + t]     = (half_t)(ay * inv);
    h1[(r0 + 2 * N_) * H_ + t] = (half_t)(az * inv);
}

// ---------------------------------------------------------------------------
// 3-v fused fp16 MFMA GEMM, tile 64(m) x 32(n), 4 waves (2m x 2n, 32x16
// per wave). Weights fp16 hi/lo (2 MFMAs/frag), acts single fp16 plane.
// RELU_MODE: 0=none, 1=VN-relu p from pA (stride O), 2=VN-relu p=[pA
// (o<128, stride 128) | P fp32 bcast]. Optional rowAdd.
// ---------------------------------------------------------------------------
template<int RELU_MODE, bool HAS_ROWADD>
__global__ __launch_bounds__(256) void gemm3v(const half_t* __restrict__ Whi,
                                              const half_t* __restrict__ Wlo,
                                              int lda,
                                              const half_t* __restrict__ A,
                                              int C,
                                              const half_t* __restrict__ pA,
                                              const float* __restrict__ P,
                                              const float* __restrict__ rowAdd,
                                              half_t* __restrict__ outA,
                                              int O) {
    __shared__ __align__(16) half_t Ah[64 * 32];
    __shared__ __align__(16) half_t Al[64 * 32];
    __shared__ __align__(16) half_t Bs[3][32 * 32];

    const int t = threadIdx.x;
    const int lane = t & 63, wave = t >> 6;
    const int wm = wave >> 1, wn = wave & 1;
    const int l16 = lane & 15, quad = lane >> 4;
    const int sw = (quad ^ (l16 & 3)) * 8;
    const int m0 = blockIdx.y * 64;
    const int b  = blockIdx.z;
    const int n0 = blockIdx.x * 32;

    f4_t acc[3][2];
    #pragma unroll
    for (int v = 0; v < 3; ++v)
        #pragma unroll
        for (int i = 0; i < 2; ++i)
            #pragma unroll
            for (int e = 0; e < 4; ++e) acc[v][i][e] = 0.f;

    for (int k0 = 0; k0 < C; k0 += 32) {
        {   // A: 64 rows x 4 chunks = 256 (one per thread)
            int row = t >> 2, ch = t & 3;
            size_t g = (size_t)(m0 + row) * lda + k0 + ch * 8;
            int ld = row * 32 + ((ch ^ (row & 3)) * 8);
            *(uint4*)(Ah + ld) = *(const uint4*)(Whi + g);
            *(uint4*)(Al + ld) = *(const uint4*)(Wlo + g);
        }
        #pragma unroll
        for (int c = t; c < 384; c += 256) {   // B: 3 x 32 rows x 4 chunks
            int v = c >> 7, rem = c & 127;
            int row = rem >> 2, ch = rem & 3;
            size_t g = (size_t)((b * 3 + v) * N_ + n0 + row) * C + k0 + ch * 8;
            int ld = row * 32 + ((ch ^ (row & 3)) * 8);
            *(uint4*)(Bs[v] + ld) = *(const uint4*)(A + g);
        }
        __syncthreads();
        h8_t ah[2], al[2], bh[3];
        #pragma unroll
        for (int i = 0; i < 2; ++i) {
            int ar = wm * 32 + i * 16 + l16;
            ah[i] = *(const h8_t*)(Ah + ar * 32 + sw);
            al[i] = *(const h8_t*)(Al + ar * 32 + sw);
        }
        #pragma unroll
        for (int v = 0; v < 3; ++v) {
            int br = wn * 16 + l16;
            bh[v] = *(const h8_t*)(Bs[v] + br * 32 + sw);
        }
        #pragma unroll
        for (int v = 0; v < 3; ++v)
            #pragma unroll
            for (int i = 0; i < 2; ++i) {
                acc[v][i] = __builtin_amdgcn_mfma_f32_16x16x32_f16(
                    ah[i], bh[v], acc[v][i], 0, 0, 0);
                acc[v][i] = __builtin_amdgcn_mfma_f32_16x16x32_f16(
                    al[i], bh[v], acc[v][i], 0, 0, 0);
            }
        __syncthreads();
    }

    const int n = n0 + wn * 16 + l16;
    const size_t row0 = (size_t)(b * 3) * N_ + n;
    #pragma unroll
    for (int i = 0; i < 2; ++i) {
        int o = m0 + wm * 32 + i * 16 + quad * 4;
        f4_t d[3];
        #pragma unroll
        for (int v = 0; v < 3; ++v) {
            d[v] = acc[v][i];
            if (HAS_ROWADD) {
                float4 ra = *(const float4*)(rowAdd + (size_t)(b * 3 + v) * O + o);
                d[v][0] += ra.x; d[v][1] += ra.y; d[v][2] += ra.z; d[v][3] += ra.w;
            }
        }
        if (RELU_MODE == 0) {
            #pragma unroll
            for (int v = 0; v < 3; ++v)
                st4h(outA, (row0 + (size_t)v * N_) * O + o, d[v]);
        } else {
            f4_t p[3];
            if (RELU_MODE == 1) {
                #pragma unroll
                for (int v = 0; v < 3; ++v)
                    p[v] = ld4h(pA, (row0 + (size_t)v * N_) * O + o);
            } else {
                if (o < 128) {
                    #pragma unroll
                    for (int v = 0; v < 3; ++v)
                        p[v] = ld4h(pA, (row0 + (size_t)v * N_) * 128 + o);
                } else {
                    #pragma unroll
                    for (int e = 0; e < 4; ++e) {
                        const float* Pc = P + (size_t)(b * 128 + o - 128 + e) * 3;
                        p[0][e] = Pc[0]; p[1][e] = Pc[1]; p[2][e] = Pc[2];
                    }
                }
            }
            f4_t q[3];
            #pragma unroll
            for (int e = 0; e < 4; ++e) {
                float dot = p[0][e] * d[0][e] + p[1][e] * d[1][e] + p[2][e] * d[2][e];
                float dsq = d[0][e] * d[0][e] + d[1][e] * d[1][e] + d[2][e] * d[2][e] + EPS_;
                float cf = dot / dsq;
                if (dot >= 0.f) { q[0][e] = p[0][e]; q[1][e] = p[1][e]; q[2][e] = p[2][e]; }
                else {
                    q[0][e] = p[0][e] - cf * d[0][e];
                    q[1][e] = p[1][e] - cf * d[1][e];
                    q[2][e] = p[2][e] - cf * d[2][e];
                }
            }
            #pragma unroll
            for (int v = 0; v < 3; ++v)
                st4h(outA, (row0 + (size_t)v * N_) * O + o, q[v]);
        }
    }
}

// ---------------------------------------------------------------------------
// 3-v dual-segment GEMM (h = Ws*hidden + W1*a1 + rowAdd), tile 64x32, fused
// pool partials; optional h writes. O=128.
// Pp layout: [((b*32 + ntile)*2 + wn) * 384 + o*3 + v]  (64 slots per b)
// ---------------------------------------------------------------------------
template<bool HAS_ROWADD, bool WRITE_OUT>
__global__ __launch_bounds__(256) void gemm3v_dual(const half_t* __restrict__ W0h,
                                                   const half_t* __restrict__ W0l,
                                                   int lda0, int C0,
                                                   const half_t* __restrict__ A0,
                                                   const half_t* __restrict__ W1h,
                                                   const half_t* __restrict__ W1l,
                                                   int lda1, int C1,
                                                   const half_t* __restrict__ A1,
                                                   const float* __restrict__ rowAdd,
                                                   half_t* __restrict__ outA,
                                                   float* __restrict__ Pp) {
    constexpr int O = 128;
    __shared__ __align__(16) half_t Ah[64 * 32];
    __shared__ __align__(16) half_t Al[64 * 32];
    __shared__ __align__(16) half_t Bs[3][32 * 32];

    const int t = threadIdx.x;
    const int lane = t & 63, wave = t >> 6;
    const int wm = wave >> 1, wn = wave & 1;
    const int l16 = lane & 15, quad = lane >> 4;
    const int sw = (quad ^ (l16 & 3)) * 8;
    const int m0 = blockIdx.y * 64;
    const int b  = blockIdx.z;
    const int n0 = blockIdx.x * 32;

    f4_t acc[3][2];
    #pragma unroll
    for (int v = 0; v < 3; ++v)
        #pragma unroll
        for (int i = 0; i < 2; ++i)
            #pragma unroll
            for (int e = 0; e < 4; ++e) acc[v][i][e] = 0.f;

    const int Ct = C0 + C1;
    for (int k0 = 0; k0 < Ct; k0 += 32) {
        const bool seg = (k0 >= C0);
        const half_t* wh = seg ? W1h : W0h;
        const half_t* wl = seg ? W1l : W0l;
        const half_t* ag = seg ? A1 : A0;
        const int lda = seg ? lda1 : lda0;
        const int cs  = seg ? C1 : C0;
        const int kk  = seg ? (k0 - C0) : k0;
        {
            int row = t >> 2, ch = t & 3;
            size_t g = (size_t)(m0 + row) * lda + kk + ch * 8;
            int ld = row * 32 + ((ch ^ (row & 3)) * 8);
            *(uint4*)(Ah + ld) = *(const uint4*)(wh + g);
            *(uint4*)(Al + ld) = *(const uint4*)(wl + g);
        }
        #pragma unroll
        for (int c = t; c < 384; c += 256) {
            int v = c >> 7, rem = c & 127;
            int row = rem >> 2, ch = rem & 3;
            size_t g = (size_t)((b * 3 + v) * N_ + n0 + row) * cs + kk + ch * 8;
            int ld = row * 32 + ((ch ^ (row & 3)) * 8);
            *(uint4*)(Bs[v] + ld) = *(const uint4*)(ag + g);
        }
        __syncthreads();
        h8_t ah[2], al[2], bh[3];
        #pragma unroll
        for (int i = 0; i < 2; ++i) {
            int ar = wm * 32 + i * 16 + l16;
            ah[i] = *(const h8_t*)(Ah + ar * 32 + sw);
            al[i] = *(const h8_t*)(Al + ar * 32 + sw);
        }
        #pragma unroll
        for (int v = 0; v < 3; ++v) {
            int br = wn * 16 + l16;
            bh[v] = *(const h8_t*)(Bs[v] + br * 32 + sw);
        }
        #pragma unroll
        for (int v = 0; v < 3; ++v)
            #pragma unroll
            for (int i = 0; i < 2; ++i) {
                acc[v][i] = __builtin_amdgcn_mfma_f32_16x16x32_f16(
                    ah[i], bh[v], acc[v][i], 0, 0, 0);
                acc[v][i] = __builtin_amdgcn_mfma_f32_16x16x32_f16(
                    al[i], bh[v], acc[v][i], 0, 0, 0);
            }
        __syncthreads();
    }

    const int n = n0 + wn * 16 + l16;
    const size_t row0 = (size_t)(b * 3) * N_ + n;
    const size_t slot = ((size_t)b * 32 + blockIdx.x) * 2 + wn;
    #pragma unroll
    for (int i = 0; i < 2; ++i) {
        int o = m0 + wm * 32 + i * 16 + quad * 4;
        f4_t d[3];
        #pragma unroll
        for (int v = 0; v < 3; ++v) {
            d[v] = acc[v][i];
            if (HAS_ROWADD) {
                float4 ra = *(const float4*)(rowAdd + (size_t)(b * 3 + v) * O + o);
                d[v][0] += ra.x; d[v][1] += ra.y; d[v][2] += ra.z; d[v][3] += ra.w;
            }
            if (WRITE_OUT)
                st4h(outA, (row0 + (size_t)v * N_) * O + o, d[v]);
        }
        // reduce over 16-lane n-group
        #pragma unroll
        for (int v = 0; v < 3; ++v)
            #pragma unroll
            for (int e = 0; e < 4; ++e) {
                float s = d[v][e];
                s += __shfl_xor(s, 1);
                s += __shfl_xor(s, 2);
                s += __shfl_xor(s, 4);
                s += __shfl_xor(s, 8);
                d[v][e] = s;
            }
        if (l16 == 0) {
            #pragma unroll
            for (int v = 0; v < 3; ++v)
                #pragma unroll
                for (int e = 0; e < 4; ++e)
                    Pp[slot * 384 + (size_t)(o + e) * 3 + v] = d[v][e];
        }
    }
}

// ---------------------------------------------------------------------------
// Exact pooled-half injection (fp32 original weights + fp32 P).
// ---------------------------------------------------------------------------
__global__ __launch_bounds__(256) void rowadd_kernel(const float* __restrict__ Wd0i,
                                                     const float* __restrict__ Wsi,
                                                     const float* __restrict__ P,
                                                     float* __restrict__ addD0,
                                                     float* __restrict__ addWs) {
    int s = blockIdx.x;               // b*3 + v
    int b = s / 3, v = s % 3;
    __shared__ float Pl[128];
    int t = threadIdx.x;
    if (t < 128) Pl[t] = P[(size_t)(b * 128 + t) * 3 + v];
    __syncthreads();
    float sum = 0.f;
    const float* wr = Wd0i + (size_t)t * 256 + 128;
    #pragma unroll 8
    for (int c = 0; c < 128; ++c) sum += wr[c] * Pl[c];
    addD0[(size_t)s * 256 + t] = sum;
    if (t < 128) {
        const float* wr2 = Wsi + (size_t)t * 256 + 128;
        float s2 = 0.f;
        #pragma unroll 8
        for (int c = 0; c < 128; ++c) s2 += wr2[c] * Pl[c];
        addWs[(size_t)s * 128 + t] = s2;
    }
}

// ---------------------------------------------------------------------------
// Pool stage 2: reduce 64 partial slots -> P (B,128,3), scaled by 1/N.
// ---------------------------------------------------------------------------
__global__ __launch_bounds__(128) void pool2_kernel(const float* __restrict__ Pp,
                                                    float* __restrict__ P) {
    int b = blockIdx.x;
    int c = threadIdx.x;
    float s0 = 0.f, s1 = 0.f, s2 = 0.f;
    for (int sl = 0; sl < 64; ++sl) {
        const float* p = Pp + ((size_t)b * 64 + sl) * 384 + (size_t)c * 3;
        s0 += p[0]; s1 += p[1]; s2 += p[2];
    }
    float* o = P + (size_t)(b * 128 + c) * 3;
    const float inv = 1.0f / (float)N_;
    o[0] = s0 * inv; o[1] = s1 * inv; o[2] = s2 * inv;
}

// ---------------------------------------------------------------------------
// Final stage (fp32, exact)
// ---------------------------------------------------------------------------
__global__ __launch_bounds__(128) void final_kernel(const float* __restrict__ P,
                                                    const float* __restrict__ Wd,
                                                    const float* __restrict__ Wc,
                                                    float* __restrict__ out) {
    int b = blockIdx.x;
    int t = threadIdx.x;
    __shared__ float hid[H_][3];
    __shared__ float act[H_][3];
    const float* Pb = P + (size_t)b * H_ * 3;
    hid[t][0] = Pb[t * 3 + 0];
    hid[t][1] = Pb[t * 3 + 1];
    hid[t][2] = Pb[t * 3 + 2];
    __syncthreads();

    float d0 = 0.f, d1 = 0.f, d2 = 0.f;
    const float* wd = Wd + (size_t)t * H_;
    for (int c = 0; c < H_; ++c) {
        float w = wd[c];
        d0 += w * hid[c][0]; d1 += w * hid[c][1]; d2 += w * hid[c][2];
    }
    float p0 = hid[t][0], p1 = hid[t][1], p2 = hid[t][2];
    float dot = p0 * d0 + p1 * d1 + p2 * d2;
    float dsq = d0 * d0 + d1 * d1 + d2 * d2 + EPS_;
    float cf = dot / dsq;
    float q0, q1, q2;
    if (dot >= 0.f) { q0 = p0; q1 = p1; q2 = p2; }
    else            { q0 = p0 - cf * d0; q1 = p1 - cf * d1; q2 = p2 - cf * d2; }
    act[t][0] = 0.2f * p0 + 0.8f * q0;
    act[t][1] = 0.2f * p1 + 0.8f * q1;
    act[t][2] = 0.2f * p2 + 0.8f * q2;
    __syncthreads();

    float o0 = 0.f, o1 = 0.f, o2 = 0.f;
    const float* wc = Wc + (size_t)t * H_;
    for (int c = 0; c < H_; ++c) {
        float w = wc[c];
        o0 += w * act[c][0]; o1 += w * act[c][1]; o2 += w * act[c][2];
    }
    size_t ob = ((size_t)b * H_ + t) * 3;
    out[ob + 0] = o0; out[ob + 1] = o1; out[ob + 2] = o2;
}

// ---------------------------------------------------------------------------
extern "C" void kernel_launch(void* const* d_in, const int* in_sizes, int n_in,
                              void* d_out, int out_size, void* d_ws, size_t ws_size,
                              hipStream_t stream) {
    const float* x   = (const float*)d_in[0];
    const float* Wf  = (const float*)d_in[1];
    const float* Wdp = (const float*)d_in[2];
    const float* Wfc = (const float*)d_in[3];
    const float* Wd0 = (const float*)d_in[4];
    const float* W0  = (const float*)d_in[5];
    const float* Wd1 = (const float*)d_in[6];
    const float* W1  = (const float*)d_in[7];
    const float* Wsc = (const float*)d_in[8];
    const float* Wda = (const float*)d_in[9];
    const float* Wc  = (const float*)d_in[10];
    float* out = (float*)d_out;
    (void)in_sizes; (void)n_in; (void)out_size; (void)ws_size;

    char* ws = (char*)d_ws;
    size_t off = 0;
    auto alloc = [&](size_t bytes) {
        void* p = ws + off;
        off = (off + bytes + 255) & ~(size_t)255;
        return p;
    };
    const size_t e128 = (size_t)R_ * 128;
    const size_t e256 = (size_t)R_ * 256;
    int*    idx   = (int*)   alloc((size_t)B_ * N_ * K_ * sizeof(int));
    half_t* wAllH = (half_t*)alloc((size_t)W_TOT * 2);
    half_t* wAllL = (half_t*)alloc((size_t)W_TOT * 2);
    half_t* h1F   = (half_t*)alloc(e128 * 2);
    half_t* HdF   = (half_t*)alloc(e256 * 2);
    half_t* a0F   = (half_t*)alloc(e256 * 2);
    half_t* netF  = (half_t*)alloc(e128 * 2);
    half_t* a1F   = (half_t*)alloc(e128 * 2);
    half_t* hF[2] = { (half_t*)alloc(e128 * 2), (half_t*)alloc(e128 * 2) };
    float*  addD0 = (float*) alloc(24 * 256 * 4);
    float*  addWs = (float*) alloc(24 * 128 * 4);
    float*  Pp    = (float*) alloc((size_t)B_ * 64 * 384 * 4);
    float*  P     = (float*) alloc((size_t)B_ * 128 * 3 * 4);

    const half_t* whFc = wAllH + OFF_FC; const half_t* wlFc = wAllL + OFF_FC;
    const half_t* whD0 = wAllH + OFF_D0; const half_t* wlD0 = wAllL + OFF_D0;
    const half_t* whW0 = wAllH + OFF_W0; const half_t* wlW0 = wAllL + OFF_W0;
    const half_t* whD1 = wAllH + OFF_D1; const half_t* wlD1 = wAllL + OFF_D1;
    const half_t* whW1 = wAllH + OFF_W1; const half_t* wlW1 = wAllL + OFF_W1;
    const half_t* whWs = wAllH + OFF_WS; const half_t* wlWs = wAllL + OFF_WS;

    hipLaunchKernelGGL(cvt_all, dim3((W_TOT + 255) / 256), dim3(256), 0, stream,
                       Wfc, Wd0, W0, Wd1, W1, Wsc, wAllH, wAllL);
    hipLaunchKernelGGL(knn_wave, dim3(B_ * N_ / 4), dim3(256), 0, stream, x, idx);
    hipLaunchKernelGGL(convpos_kernel, dim3(B_ * N_), dim3(128), 0, stream,
                       x, idx, Wf, Wdp, h1F);

    // fc_pos: Hd = Wfc (256x128) * h1
    gemm3v<0, false><<<dim3(32, 4, 8), 256, 0, stream>>>(
        whFc, wlFc, 128, h1F, 128, nullptr, nullptr, nullptr, HdF, 256);

    for (int i = 0; i < 4; ++i) {
        int cur = i & 1, prv = cur ^ 1;
        if (i == 0) {
            // a0 = vnrelu(Hd, Wd0*Hd)
            gemm3v<1, false><<<dim3(32, 4, 8), 256, 0, stream>>>(
                whD0, wlD0, 256, HdF, 256, HdF, nullptr, nullptr, a0F, 256);
        } else {
            hipLaunchKernelGGL(rowadd_kernel, dim3(24), dim3(256), 0, stream,
                               Wd0 + (size_t)i * 65536, Wsc + (size_t)i * 32768,
                               P, addD0, addWs);
            // a0 = vnrelu([h|P], Wd0_left*h + rowAdd)
            gemm3v<2, true><<<dim3(32, 4, 8), 256, 0, stream>>>(
                whD0 + (size_t)i * 65536, wlD0 + (size_t)i * 65536, 256,
                hF[prv], 128, hF[prv], P, addD0, a0F, 256);
        }
        // net = W0 * a0
        gemm3v<0, false><<<dim3(32, 2, 8), 256, 0, stream>>>(
            whW0 + (size_t)i * 32768, wlW0 + (size_t)i * 32768, 256,
            a0F, 256, nullptr, nullptr, nullptr, netF, 128);
        // a1 = vnrelu(net, Wd1*net)
        gemm3v<1, false><<<dim3(32, 2, 8), 256, 0, stream>>>(
            whD1 + (size_t)i * 16384, wlD1 + (size_t)i * 16384, 128,
            netF, 128, netF, nullptr, nullptr, a1F, 128);
        // h = [Ws | W1] * [hidden ; a1] (+rowAdd) ; fused pool partials
        if (i == 0) {
            gemm3v_dual<false, true><<<dim3(32, 2, 8), 256, 0, stream>>>(
                whWs, wlWs, 256, 256, HdF,
                whW1, wlW1, 128, 128, a1F,
                nullptr, hF[cur], Pp);
        } else if (i < 3) {
            gemm3v_dual<true, true><<<dim3(32, 2, 8), 256, 0, stream>>>(
                whWs + (size_t)i * 32768, wlWs + (size_t)i * 32768, 256, 128, hF[prv],
                whW1 + (size_t)i * 16384, wlW1 + (size_t)i * 16384, 128, 128, a1F,
                addWs, hF[cur], Pp);
        } else {
            gemm3v_dual<true, false><<<dim3(32, 2, 8), 256, 0, stream>>>(
                whWs + (size_t)i * 32768, wlWs + (size_t)i * 32768, 256, 128, hF[prv],
                whW1 + (size_t)i * 16384, wlW1 + (size_t)i * 16384, 128, 128, a1F,
                addWs, nullptr, Pp);
        }
        hipLaunchKernelGGL(pool2_kernel, dim3(B_), dim3(128), 0, stream, Pp, P);
    }

    hipLaunchKernelGGL(final_kernel, dim3(B_), dim3(128), 0, stream, P, Wda, Wc, out);
}